// Round 10
// baseline (3247.528 us; speedup 1.0000x reference)
//
#include <hip/hip_runtime.h>
#include <hip/hip_fp16.h>
#include <math.h>

#define N_NODES 30000
#define N_EDGES 480000
#define N_GRAPHS 16
#define HID 128
#define HEADS 8
#define HEAD_DIM 16
#define NODE_IN 64
#define EDGE_IN 32
#define COND 8
#define NODE_OUT 64
#define NLAYERS 4
#define EF (N_EDGES + N_NODES) /* 510000 */
#define LN_EPS 1e-5f
#define SH_STRIDE 132  /* padded LDS row stride: rg0/rg1 broadcast addrs land 16 banks apart */

__device__ __forceinline__ float gelu_f(float x) {
    return 0.5f * x * (1.0f + erff(x * 0.70710678118654752440f));
}

__device__ __forceinline__ void atomicMaxF(float* addr, float val) {
    if (val >= 0.0f) {
        atomicMax((int*)addr, __float_as_int(val));
    } else {
        atomicMin((unsigned int*)addr, __float_as_uint(val));
    }
}

// ---------- generic zero ----------
__global__ void zero_kernel(float* __restrict__ p, long n) {
    long i = (long)blockIdx.x * blockDim.x + threadIdx.x;
    long stride = (long)gridDim.x * blockDim.x;
    for (; i < n; i += stride) p[i] = 0.0f;
}

// ---------- time MLP: t[16] -> t_emb[16,128] ----------
__global__ void time_mlp_kernel(const float* __restrict__ t,
                                const float* __restrict__ tW1, const float* __restrict__ tb1,
                                const float* __restrict__ tW2, const float* __restrict__ tb2,
                                float* __restrict__ t_emb) {
    __shared__ float hsh[HID];
    int b = blockIdx.x, j = threadIdx.x;
    float tv = t[b];
    hsh[j] = gelu_f(tv * tW1[j] + tb1[j]);
    __syncthreads();
    float acc = tb2[j];
    for (int k = 0; k < HID; ++k) acc += hsh[k] * tW2[k * HID + j];
    t_emb[b * HID + j] = acc;
}

// ---------- concat x(64) + conditions[batch](8) -> xc[N,72] ----------
__global__ void concat_kernel(const float* __restrict__ x, const float* __restrict__ cond,
                              const int* __restrict__ batch, float* __restrict__ xc) {
    int idx = blockIdx.x * blockDim.x + threadIdx.x;
    if (idx >= N_NODES * 72) return;
    int n = idx / 72, c = idx % 72;
    xc[idx] = (c < NODE_IN) ? x[n * NODE_IN + c] : cond[batch[n] * COND + (c - NODE_IN)];
}

// ---------- generic GEMM: C[M,NCOL] = A[M,K] @ B[K,NCOL] + bias ----------
template <int NCOL, int R>
__global__ void gemm_kernel(const float* __restrict__ A, const float* __restrict__ B,
                            const float* __restrict__ bias, float* __restrict__ C,
                            int M, int K) {
    __shared__ __align__(16) float sh[R * HID];
    int j = threadIdx.x;
    int row0 = blockIdx.x * R;
    int total = R * K;
    for (int i = j; i < total; i += NCOL) {
        int r = i / K, k = i - r * K;
        int row = row0 + r;
        sh[r * K + k] = (row < M) ? A[(long)row * K + k] : 0.0f;
    }
    __syncthreads();
    float acc[R];
    float bv = bias ? bias[j] : 0.0f;
#pragma unroll
    for (int r = 0; r < R; ++r) acc[r] = bv;
    int KB = K >> 2;
    for (int kb = 0; kb < KB; ++kb) {
        float w0 = B[(kb * 4 + 0) * NCOL + j];
        float w1 = B[(kb * 4 + 1) * NCOL + j];
        float w2 = B[(kb * 4 + 2) * NCOL + j];
        float w3 = B[(kb * 4 + 3) * NCOL + j];
#pragma unroll
        for (int r = 0; r < R; ++r) {
            float4 a = *(const float4*)&sh[r * K + kb * 4];
            acc[r] += a.x * w0 + a.y * w1 + a.z * w2 + a.w * w3;
        }
    }
#pragma unroll
    for (int r = 0; r < R; ++r) {
        int row = row0 + r;
        if (row < M) C[(long)row * NCOL + j] = acc[r];
    }
}

// ---------- fused dual GEMM: Cl = A@Bl + bl, Cr = A@Br + br (K = HID) ----------
template <int R>
__global__ void gemm2_kernel(const float* __restrict__ A,
                             const float* __restrict__ Bl, const float* __restrict__ bl,
                             const float* __restrict__ Br, const float* __restrict__ br,
                             float* __restrict__ Cl, float* __restrict__ Cr, int M) {
    __shared__ __align__(16) float sh[R * HID];
    int j = threadIdx.x;
    int row0 = blockIdx.x * R;
    for (int i = j; i < R * HID; i += HID) {
        int r = i >> 7, k = i & 127;
        int row = row0 + r;
        sh[i] = (row < M) ? A[(long)row * HID + k] : 0.0f;
    }
    __syncthreads();
    float accl[R], accr[R];
    float blv = bl[j], brv = br[j];
#pragma unroll
    for (int r = 0; r < R; ++r) { accl[r] = blv; accr[r] = brv; }
    for (int kb = 0; kb < HID / 4; ++kb) {
        float l0 = Bl[(kb * 4 + 0) * HID + j];
        float l1 = Bl[(kb * 4 + 1) * HID + j];
        float l2 = Bl[(kb * 4 + 2) * HID + j];
        float l3 = Bl[(kb * 4 + 3) * HID + j];
        float r0 = Br[(kb * 4 + 0) * HID + j];
        float r1 = Br[(kb * 4 + 1) * HID + j];
        float r2 = Br[(kb * 4 + 2) * HID + j];
        float r3 = Br[(kb * 4 + 3) * HID + j];
#pragma unroll
        for (int r = 0; r < R; ++r) {
            float4 a = *(const float4*)&sh[r * HID + kb * 4];
            accl[r] += a.x * l0 + a.y * l1 + a.z * l2 + a.w * l3;
            accr[r] += a.x * r0 + a.y * r1 + a.z * r2 + a.w * r3;
        }
    }
#pragma unroll
    for (int r = 0; r < R; ++r) {
        int row = row0 + r;
        if (row < M) {
            Cl[(long)row * HID + j] = accl[r];
            Cr[(long)row * HID + j] = accr[r];
        }
    }
}

// ---------- in-place LayerNorm + GELU (+ optional t_emb[batch[row]]) ----------
__global__ void ln_gelu_kernel(float* __restrict__ X, const float* __restrict__ g,
                               const float* __restrict__ bta,
                               const float* __restrict__ t_emb, const int* __restrict__ batch) {
    int row = blockIdx.x, j = threadIdx.x;
    __shared__ float red[HID];
    float v = X[(long)row * HID + j];
    red[j] = v;
    __syncthreads();
    for (int s = 64; s > 0; s >>= 1) { if (j < s) red[j] += red[j + s]; __syncthreads(); }
    float mean = red[0] * (1.0f / HID);
    __syncthreads();
    float d = v - mean;
    red[j] = d * d;
    __syncthreads();
    for (int s = 64; s > 0; s >>= 1) { if (j < s) red[j] += red[j + s]; __syncthreads(); }
    float var = red[0] * (1.0f / HID);
    float y = gelu_f(d * rsqrtf(var + LN_EPS) * g[j] + bta[j]);
    if (t_emb) y += t_emb[batch[row] * HID + j];
    X[(long)row * HID + j] = y;
}

// ---------- fallback (modes 0/2): edge-encode + segment-sum, LDS-tree LN ----------
template <int R, int MODE>
__global__ void edge_enc_loop_kernel(const float* __restrict__ edge_attr,
                                     const float* __restrict__ eW, const float* __restrict__ eb,
                                     const float* __restrict__ eg, const float* __restrict__ ebe,
                                     const int* __restrict__ ei_dst,
                                     float* __restrict__ loop_sum, float* __restrict__ cnt,
                                     float* __restrict__ stat,
                                     float* __restrict__ ea32, __half* __restrict__ ea16) {
    __shared__ float red[R * HID];
    __shared__ __align__(16) float sattr[R * EDGE_IN];
    __shared__ int sdst[R];
    int j = threadIdx.x;
    long e0 = (long)blockIdx.x * R;
    if (j < R * EDGE_IN / 4)
        ((float4*)sattr)[j] = ((const float4*)(edge_attr + e0 * EDGE_IN))[j];
    if (j < R) sdst[j] = ei_dst[e0 + j];
    __syncthreads();
    float val[R];
    float ebv = eb[j];
#pragma unroll
    for (int r = 0; r < R; ++r) val[r] = ebv;
#pragma unroll
    for (int kb = 0; kb < EDGE_IN / 4; ++kb) {
        float w0 = eW[(kb * 4 + 0) * HID + j];
        float w1 = eW[(kb * 4 + 1) * HID + j];
        float w2 = eW[(kb * 4 + 2) * HID + j];
        float w3 = eW[(kb * 4 + 3) * HID + j];
#pragma unroll
        for (int r = 0; r < R; ++r) {
            float4 a = *(const float4*)&sattr[r * EDGE_IN + kb * 4];
            val[r] += a.x * w0 + a.y * w1 + a.z * w2 + a.w * w3;
        }
    }
#pragma unroll
    for (int r = 0; r < R; ++r) red[r * HID + j] = val[r];
    __syncthreads();
    for (int s = 64; s > 0; s >>= 1) {
        if (j < s) {
#pragma unroll
            for (int r = 0; r < R; ++r) red[r * HID + j] += red[r * HID + j + s];
        }
        __syncthreads();
    }
    float mean[R];
#pragma unroll
    for (int r = 0; r < R; ++r) mean[r] = red[r * HID] * (1.0f / HID);
    __syncthreads();
#pragma unroll
    for (int r = 0; r < R; ++r) { float d = val[r] - mean[r]; red[r * HID + j] = d * d; }
    __syncthreads();
    for (int s = 64; s > 0; s >>= 1) {
        if (j < s) {
#pragma unroll
            for (int r = 0; r < R; ++r) red[r * HID + j] += red[r * HID + j + s];
        }
        __syncthreads();
    }
    float egv = eg[j], bev = ebe[j];
#pragma unroll
    for (int r = 0; r < R; ++r) {
        float var = red[r * HID] * (1.0f / HID);
        float rstd = rsqrtf(var + LN_EPS);
        float y = gelu_f((val[r] - mean[r]) * rstd * egv + bev);
        int d = sdst[r];
        long e = e0 + r;
        if (j == 0) { stat[e * 2] = mean[r]; stat[e * 2 + 1] = rstd; }
        if (MODE == 2) ea32[e * HID + j] = y;
        if (MODE == 1) ea16[e * HID + j] = __float2half(y);
        atomicAdd(&loop_sum[(long)d * HID + j], y);
        if (j == 0) atomicAdd(&cnt[d], 1.0f);
    }
}

// ---------- mode-1 MAIN enc: wave-owns-rows, shfl LN (no barriers), fp16 ea ----------
__global__ __launch_bounds__(128) void edge_enc_loop_w_kernel(
        const float* __restrict__ edge_attr,
        const float* __restrict__ eW, const float* __restrict__ eb,
        const float* __restrict__ eg, const float* __restrict__ ebe,
        const int* __restrict__ ei_dst,
        float* __restrict__ loop_sum, float* __restrict__ cnt,
        __half* __restrict__ ea16) {
    const int R = 8;
    __shared__ __align__(16) float sattr[R * EDGE_IN];
    __shared__ int sdst[R];
    int t = threadIdx.x;
    long e0 = (long)blockIdx.x * R;
    if (t < R * EDGE_IN / 4)
        ((float4*)sattr)[t] = ((const float4*)(edge_attr + e0 * EDGE_IN))[t];
    if (t < R) sdst[t] = ei_dst[e0 + t];
    __syncthreads();
    int lane = t & 63, w = t >> 6;
    int r0 = w * 4;
    int j1 = lane, j2 = lane + 64;
    float eb1 = eb[j1], eb2 = eb[j2];
    float v0[4], v1[4];
#pragma unroll
    for (int q = 0; q < 4; ++q) { v0[q] = eb1; v1[q] = eb2; }
#pragma unroll
    for (int kb = 0; kb < EDGE_IN / 4; ++kb) {
        float w10 = eW[(kb * 4 + 0) * HID + j1];
        float w11 = eW[(kb * 4 + 1) * HID + j1];
        float w12 = eW[(kb * 4 + 2) * HID + j1];
        float w13 = eW[(kb * 4 + 3) * HID + j1];
        float w20 = eW[(kb * 4 + 0) * HID + j2];
        float w21 = eW[(kb * 4 + 1) * HID + j2];
        float w22 = eW[(kb * 4 + 2) * HID + j2];
        float w23 = eW[(kb * 4 + 3) * HID + j2];
#pragma unroll
        for (int q = 0; q < 4; ++q) {
            float4 a = *(const float4*)&sattr[(r0 + q) * EDGE_IN + kb * 4];
            v0[q] += a.x * w10 + a.y * w11 + a.z * w12 + a.w * w13;
            v1[q] += a.x * w20 + a.y * w21 + a.z * w22 + a.w * w23;
        }
    }
    float eg1 = eg[j1], eg2 = eg[j2];
    float be1 = ebe[j1], be2 = ebe[j2];
#pragma unroll
    for (int q = 0; q < 4; ++q) {
        float s1 = v0[q] + v1[q];
        float s2 = v0[q] * v0[q] + v1[q] * v1[q];
#pragma unroll
        for (int m = 1; m < 64; m <<= 1) {
            s1 += __shfl_xor(s1, m);
            s2 += __shfl_xor(s2, m);
        }
        float mean = s1 * (1.0f / 128.0f);
        float var = s2 * (1.0f / 128.0f) - mean * mean;
        float rstd = rsqrtf(var + LN_EPS);
        float y0 = gelu_f((v0[q] - mean) * rstd * eg1 + be1);
        float y1 = gelu_f((v1[q] - mean) * rstd * eg2 + be2);
        long e = e0 + r0 + q;
        int d = sdst[r0 + q];
        ea16[e * HID + j1] = __float2half(y0);
        ea16[e * HID + j2] = __float2half(y1);
        atomicAdd(&loop_sum[(long)d * HID + j1], y0);
        atomicAdd(&loop_sum[(long)d * HID + j2], y1);
        if (lane == 0) atomicAdd(&cnt[d], 1.0f);
    }
}

__global__ void loop_div_kernel(float* __restrict__ loop_attr, const float* __restrict__ cnt) {
    int idx = blockIdx.x * blockDim.x + threadIdx.x;
    if (idx >= N_NODES * HID) return;
    int n = idx >> 7;
    loop_attr[idx] = loop_attr[idx] / fmaxf(cnt[n], 1.0f);
}

// ---------- init mx=-inf, den=0 ----------
__global__ void init_mx_den_kernel(float* __restrict__ mx, float* __restrict__ den) {
    int idx = blockIdx.x * blockDim.x + threadIdx.x;
    if (idx >= N_NODES * HEADS) return;
    mx[idx] = -INFINITY;
    den[idx] = 0.0f;
}

// ---------- shared epilogue (1 col/thread fallback variants) ----------
template <int R>
__device__ __forceinline__ void em_logit_body(
        const float* __restrict__ sh, const int* __restrict__ ssrc, const int* __restrict__ sdst,
        const float* __restrict__ cWe_l, const float* __restrict__ catt_l,
        const float* __restrict__ xl, const float* __restrict__ xr,
        float* __restrict__ logit, float* __restrict__ mx, long e0, int j) {
    float acc[R];
#pragma unroll
    for (int r = 0; r < R; ++r) acc[r] = 0.0f;
    for (int kb = 0; kb < HID / 4; ++kb) {
        float w0 = cWe_l[(kb * 4 + 0) * HID + j];
        float w1 = cWe_l[(kb * 4 + 1) * HID + j];
        float w2 = cWe_l[(kb * 4 + 2) * HID + j];
        float w3 = cWe_l[(kb * 4 + 3) * HID + j];
#pragma unroll
        for (int r = 0; r < R; ++r) {
            float4 a = *(const float4*)&sh[r * HID + kb * 4];
            acc[r] += a.x * w0 + a.y * w1 + a.z * w2 + a.w * w3;
        }
    }
    float cj = catt_l[j];
    int head = j >> 4;
#pragma unroll
    for (int r = 0; r < R; ++r) {
        long e = e0 + r;
        int s = ssrc[r], d = sdst[r];
        float m = xl[(long)s * HID + j] + xr[(long)d * HID + j] + acc[r];
        m = (m > 0.0f) ? m : 0.2f * m;
        float p = m * cj;
        p += __shfl_down(p, 8, 16);
        p += __shfl_down(p, 4, 16);
        p += __shfl_down(p, 2, 16);
        p += __shfl_down(p, 1, 16);
        if ((j & 15) == 0) {
            logit[e * HEADS + head] = p;
            atomicMaxF(&mx[(long)d * HEADS + head], p);
        }
    }
}

// ---------- att kernel, mode 0 fallback: re-encode with CACHED LN stats ----------
template <int R>
__global__ void att_logit7_kernel(const float* __restrict__ edge_attr,
                                  const float* __restrict__ eW, const float* __restrict__ eb,
                                  const float* __restrict__ eg, const float* __restrict__ ebe,
                                  const float* __restrict__ stat,
                                  const float* __restrict__ loop_attr,
                                  const float* __restrict__ cWe_l, const float* __restrict__ catt_l,
                                  const float* __restrict__ xl, const float* __restrict__ xr,
                                  const int* __restrict__ ei_src, const int* __restrict__ ei_dst,
                                  float* __restrict__ logit, float* __restrict__ mx) {
    __shared__ __align__(16) float sh[R * HID];
    __shared__ __align__(16) float sattr[R * EDGE_IN];
    __shared__ float sstat[R * 2];
    __shared__ int ssrc[R], sdst[R];
    int j = threadIdx.x;
    long e0 = (long)blockIdx.x * R;
    bool realblk = (e0 < N_EDGES);

    if (realblk) {
        if (j < R * EDGE_IN / 4)
            ((float4*)sattr)[j] = ((const float4*)(edge_attr + e0 * EDGE_IN))[j];
        if (j < R * 2) sstat[j] = stat[e0 * 2 + j];
        if (j < R) { ssrc[j] = ei_src[e0 + j]; sdst[j] = ei_dst[e0 + j]; }
    } else {
        if (j < R) ssrc[j] = sdst[j] = (int)(e0 + j - N_EDGES);
    }
    __syncthreads();

    if (realblk) {
        float val[R];
        float ebv = eb[j];
#pragma unroll
        for (int r = 0; r < R; ++r) val[r] = ebv;
#pragma unroll
        for (int kb = 0; kb < EDGE_IN / 4; ++kb) {
            float w0 = eW[(kb * 4 + 0) * HID + j];
            float w1 = eW[(kb * 4 + 1) * HID + j];
            float w2 = eW[(kb * 4 + 2) * HID + j];
            float w3 = eW[(kb * 4 + 3) * HID + j];
#pragma unroll
            for (int r = 0; r < R; ++r) {
                float4 a = *(const float4*)&sattr[r * EDGE_IN + kb * 4];
                val[r] += a.x * w0 + a.y * w1 + a.z * w2 + a.w * w3;
            }
        }
        float egv = eg[j], bev = ebe[j];
#pragma unroll
        for (int r = 0; r < R; ++r) {
            float mean = sstat[r * 2], rstd = sstat[r * 2 + 1];
            sh[r * HID + j] = gelu_f((val[r] - mean) * rstd * egv + bev);
        }
    } else {
#pragma unroll
        for (int r = 0; r < R; ++r)
            sh[r * HID + j] = loop_attr[(long)(e0 + r - N_EDGES) * HID + j];
    }
    __syncthreads();
    em_logit_body<R>(sh, ssrc, sdst, cWe_l, catt_l, xl, xr, logit, mx, e0, j);
}

// ---------- att kernel, mode 2 fallback: stream fp32 ea ----------
template <int R>
__global__ void att_logit6_kernel(const float* __restrict__ ea,
                                  const float* __restrict__ loop_attr,
                                  const float* __restrict__ cWe_l, const float* __restrict__ catt_l,
                                  const float* __restrict__ xl, const float* __restrict__ xr,
                                  const int* __restrict__ ei_src, const int* __restrict__ ei_dst,
                                  float* __restrict__ logit, float* __restrict__ mx) {
    __shared__ __align__(16) float sh[R * HID];
    __shared__ int ssrc[R], sdst[R];
    int j = threadIdx.x;
    long e0 = (long)blockIdx.x * R;
    bool realblk = (e0 < N_EDGES);
    const float* srcp = realblk ? (ea + e0 * HID) : (loop_attr + (e0 - N_EDGES) * HID);
    const float4* s4 = (const float4*)srcp;
    ((float4*)sh)[j]       = s4[j];
    ((float4*)sh)[j + HID] = s4[j + HID];
    if (j < R) {
        long e = e0 + j;
        if (realblk) { ssrc[j] = ei_src[e]; sdst[j] = ei_dst[e]; }
        else         { ssrc[j] = sdst[j] = (int)(e - N_EDGES); }
    }
    __syncthreads();
    em_logit_body<R>(sh, ssrc, sdst, cWe_l, catt_l, xl, xr, logit, mx, e0, j);
}

// ---------- att kernel, mode 1 MAIN: fp16 ea, 16-edge tile, 4 cols/thread, PADDED LDS ----------
// Thread: cg=t&31 -> cols cg*4..+3 (float4 weight loads); rg=t>>5 -> rows rg*4..+3.
// sh stride 132: the rg=0 / rg=1 broadcast addresses differ by 528 floats -> banks 16 apart
// -> both ds_read_b128 broadcasts conflict-free (round-9's 1.92M conflicts eliminated).
__global__ __launch_bounds__(128) void att_logit9h_kernel(
        const __half* __restrict__ ea,
        const float* __restrict__ loop_attr,
        const float* __restrict__ cWe_l, const float* __restrict__ catt_l,
        const float* __restrict__ xl, const float* __restrict__ xr,
        const int* __restrict__ ei_src, const int* __restrict__ ei_dst,
        float* __restrict__ logit, float* __restrict__ mx) {
    const int R = 16;
    __shared__ __align__(16) float sh[R * SH_STRIDE];
    __shared__ int ssrc[R], sdst[R];
    int t = threadIdx.x;
    long e0 = (long)blockIdx.x * R;
    bool realblk = (e0 < N_EDGES);

    // stage 16 rows into padded LDS (row = linear>>7, col = linear&127)
    if (realblk) {
        const uint4* s16 = (const uint4*)(ea + e0 * HID);  // 256 uint4 of fp16
#pragma unroll
        for (int i = 0; i < 2; ++i) {
            uint4 u = s16[t + i * 128];
            int o = (t + i * 128) * 8;
            int row = o >> 7, col = o & 127;
            float* dst = &sh[row * SH_STRIDE + col];
            const __half2* hp = (const __half2*)&u;
            float2 f0 = __half22float2(hp[0]);
            float2 f1 = __half22float2(hp[1]);
            float2 f2 = __half22float2(hp[2]);
            float2 f3 = __half22float2(hp[3]);
            *(float4*)dst       = make_float4(f0.x, f0.y, f1.x, f1.y);
            *(float4*)(dst + 4) = make_float4(f2.x, f2.y, f3.x, f3.y);
        }
    } else {
        const float4* s4 = (const float4*)(loop_attr + (e0 - N_EDGES) * HID);
#pragma unroll
        for (int i = 0; i < 4; ++i) {
            int o = (t + i * 128) * 4;
            int row = o >> 7, col = o & 127;
            *(float4*)&sh[row * SH_STRIDE + col] = s4[t + i * 128];
        }
    }
    if (t < R) {
        long e = e0 + t;
        if (realblk) { ssrc[t] = ei_src[e]; sdst[t] = ei_dst[e]; }
        else         { ssrc[t] = sdst[t] = (int)(e - N_EDGES); }
    }
    __syncthreads();

    int cg = t & 31, rg = t >> 5;
    int c0 = cg * 4;
    float acc[4][4];
#pragma unroll
    for (int i = 0; i < 4; ++i)
#pragma unroll
        for (int c = 0; c < 4; ++c) acc[i][c] = 0.0f;
    for (int kb = 0; kb < HID / 4; ++kb) {
        float4 w0 = *(const float4*)&cWe_l[(kb * 4 + 0) * HID + c0];
        float4 w1 = *(const float4*)&cWe_l[(kb * 4 + 1) * HID + c0];
        float4 w2 = *(const float4*)&cWe_l[(kb * 4 + 2) * HID + c0];
        float4 w3 = *(const float4*)&cWe_l[(kb * 4 + 3) * HID + c0];
#pragma unroll
        for (int i = 0; i < 4; ++i) {
            float4 a = *(const float4*)&sh[(rg * 4 + i) * SH_STRIDE + kb * 4];
            acc[i][0] += a.x * w0.x + a.y * w1.x + a.z * w2.x + a.w * w3.x;
            acc[i][1] += a.x * w0.y + a.y * w1.y + a.z * w2.y + a.w * w3.y;
            acc[i][2] += a.x * w0.z + a.y * w1.z + a.z * w2.z + a.w * w3.z;
            acc[i][3] += a.x * w0.w + a.y * w1.w + a.z * w2.w + a.w * w3.w;
        }
    }

    float4 cat4 = *(const float4*)&catt_l[c0];
    int head = cg >> 2;
#pragma unroll
    for (int i = 0; i < 4; ++i) {
        int r = rg * 4 + i;
        long e = e0 + r;
        int s = ssrc[r], d = sdst[r];
        float4 xlv = *(const float4*)&xl[(long)s * HID + c0];
        float4 xrv = *(const float4*)&xr[(long)d * HID + c0];
        float m0 = xlv.x + xrv.x + acc[i][0]; m0 = (m0 > 0.0f) ? m0 : 0.2f * m0;
        float m1 = xlv.y + xrv.y + acc[i][1]; m1 = (m1 > 0.0f) ? m1 : 0.2f * m1;
        float m2 = xlv.z + xrv.z + acc[i][2]; m2 = (m2 > 0.0f) ? m2 : 0.2f * m2;
        float m3 = xlv.w + xrv.w + acc[i][3]; m3 = (m3 > 0.0f) ? m3 : 0.2f * m3;
        float p = m0 * cat4.x + m1 * cat4.y + m2 * cat4.z + m3 * cat4.w;
        p += __shfl_xor(p, 1);
        p += __shfl_xor(p, 2);
        if ((cg & 3) == 0) {
            logit[e * HEADS + head] = p;
            atomicMaxF(&mx[(long)d * HEADS + head], p);
        }
    }
}

// ---------- exp(logit-mx), accumulate denominator ----------
__global__ void softmax_norm_kernel(const int* __restrict__ ei_dst, const float* __restrict__ mx,
                                    float* __restrict__ logit, float* __restrict__ den) {
    long idx = (long)blockIdx.x * blockDim.x + threadIdx.x;
    if (idx >= (long)EF * HEADS) return;
    long e = idx >> 3;
    int hh = (int)(idx & 7);
    int d = (e < N_EDGES) ? ei_dst[e] : (int)(e - N_EDGES);
    float ex = expf(logit[idx] - mx[(long)d * HEADS + hh]);
    logit[idx] = ex;
    atomicAdd(&den[(long)d * HEADS + hh], ex);
}

// ---------- alpha-weighted aggregation ----------
__global__ void aggregate_kernel(const float* __restrict__ logit, const float* __restrict__ den,
                                 const float* __restrict__ xl,
                                 const int* __restrict__ ei_src, const int* __restrict__ ei_dst,
                                 float* __restrict__ aggout) {
    long idx = (long)blockIdx.x * blockDim.x + threadIdx.x;
    if (idx >= (long)EF * HID) return;
    long e = idx >> 7;
    int j = (int)(idx & 127);
    int s, d;
    if (e < N_EDGES) { s = ei_src[e]; d = ei_dst[e]; }
    else             { s = d = (int)(e - N_EDGES); }
    int head = j >> 4;
    float alpha = logit[e * HEADS + head] / (den[(long)d * HEADS + head] + 1e-16f);
    atomicAdd(&aggout[(long)d * HID + j], alpha * xl[(long)s * HID + j]);
}

// ---------- h = gelu(aggout + cbias) + h ----------
__global__ void residual_kernel(const float* __restrict__ aggout, const float* __restrict__ cbias_l,
                                float* __restrict__ h) {
    int idx = blockIdx.x * blockDim.x + threadIdx.x;
    if (idx >= N_NODES * HID) return;
    int j = idx & 127;
    h[idx] = gelu_f(aggout[idx] + cbias_l[j]) + h[idx];
}

// ---------- pooling ----------
#define POOL_NODES 64
__global__ void pool_kernel(const float* __restrict__ h, const int* __restrict__ batch,
                            float* __restrict__ gsum, float* __restrict__ gcnt) {
    __shared__ float acc[N_GRAPHS][HID];
    __shared__ float cnt_sh[N_GRAPHS];
    int j = threadIdx.x;
    for (int g = 0; g < N_GRAPHS; ++g) acc[g][j] = 0.0f;
    if (j < N_GRAPHS) cnt_sh[j] = 0.0f;
    __syncthreads();
    int n0 = blockIdx.x * POOL_NODES;
    for (int i = 0; i < POOL_NODES; ++i) {
        int n = n0 + i;
        if (n >= N_NODES) break;
        int g = batch[n];
        acc[g][j] += h[(long)n * HID + j];
        if (j == 0) cnt_sh[g] += 1.0f;
    }
    __syncthreads();
    for (int g = 0; g < N_GRAPHS; ++g) atomicAdd(&gsum[g * HID + j], acc[g][j]);
    if (j < N_GRAPHS) atomicAdd(&gcnt[j], cnt_sh[j]);
}

// ---------- props head ----------
__global__ void props_kernel(const float* __restrict__ gsum, const float* __restrict__ gcnt,
                             const float* __restrict__ pW1, const float* __restrict__ pb1,
                             const float* __restrict__ pg, const float* __restrict__ pbe,
                             const float* __restrict__ pW2, const float* __restrict__ pb2,
                             float* __restrict__ out_props) {
    int g = blockIdx.x, j = threadIdx.x;
    __shared__ float feat[HID], red[HID], t2[HID];
    float c = fmaxf(gcnt[g], 1.0f);
    feat[j] = gsum[g * HID + j] / c;
    __syncthreads();
    float acc = pb1[j];
    for (int k = 0; k < HID; ++k) acc += feat[k] * pW1[k * HID + j];
    red[j] = acc;
    __syncthreads();
    for (int s = 64; s > 0; s >>= 1) { if (j < s) red[j] += red[j + s]; __syncthreads(); }
    float mean = red[0] * (1.0f / HID);
    __syncthreads();
    float dd = acc - mean;
    red[j] = dd * dd;
    __syncthreads();
    for (int s = 64; s > 0; s >>= 1) { if (j < s) red[j] += red[j + s]; __syncthreads(); }
    float var = red[0] * (1.0f / HID);
    t2[j] = gelu_f(dd * rsqrtf(var + LN_EPS) * pg[j] + pbe[j]);
    __syncthreads();
    if (j < COND) {
        float a = pb2[j];
        for (int k = 0; k < HID; ++k) a += t2[k] * pW2[k * COND + j];
        out_props[g * COND + j] = a;
    }
}

extern "C" void kernel_launch(void* const* d_in, const int* in_sizes, int n_in,
                              void* d_out, int out_size, void* d_ws, size_t ws_size,
                              hipStream_t stream) {
    const float* x        = (const float*)d_in[0];
    const float* edge_attr= (const float*)d_in[1];
    const float* t        = (const float*)d_in[2];
    const float* conds    = (const float*)d_in[3];
    const float* tW1      = (const float*)d_in[4];
    const float* tb1      = (const float*)d_in[5];
    const float* tW2      = (const float*)d_in[6];
    const float* tb2      = (const float*)d_in[7];
    const float* encW     = (const float*)d_in[8];
    const float* encb     = (const float*)d_in[9];
    const float* encg     = (const float*)d_in[10];
    const float* encbe    = (const float*)d_in[11];
    const float* eW       = (const float*)d_in[12];
    const float* eb       = (const float*)d_in[13];
    const float* eg       = (const float*)d_in[14];
    const float* ebe      = (const float*)d_in[15];
    const float* cWl      = (const float*)d_in[16];
    const float* cbl      = (const float*)d_in[17];
    const float* cWr      = (const float*)d_in[18];
    const float* cbr      = (const float*)d_in[19];
    const float* cWe      = (const float*)d_in[20];
    const float* catt     = (const float*)d_in[21];
    const float* cbias    = (const float*)d_in[22];
    const float* nW1      = (const float*)d_in[23];
    const float* nb1      = (const float*)d_in[24];
    const float* ng       = (const float*)d_in[25];
    const float* nbe      = (const float*)d_in[26];
    const float* nW2      = (const float*)d_in[27];
    const float* nb2      = (const float*)d_in[28];
    const float* pW1      = (const float*)d_in[29];
    const float* pb1      = (const float*)d_in[30];
    const float* pg       = (const float*)d_in[31];
    const float* pbe      = (const float*)d_in[32];
    const float* pW2      = (const float*)d_in[33];
    const float* pb2      = (const float*)d_in[34];
    const int* edge_index = (const int*)d_in[35];
    const int* batch      = (const int*)d_in[36];
    const int* ei_src = edge_index;
    const int* ei_dst = edge_index + N_EDGES;

    // workspace layout (base ~98.5 MB of f32; + ea if it fits: fp32 246 MB / fp16 123 MB)
    float* ws = (float*)d_ws;
    size_t off = 0;
    auto alloc = [&](size_t n) { float* p = ws + off; off += n; return p; };
    float* t_emb     = alloc((size_t)N_GRAPHS * HID);
    float* h         = alloc((size_t)N_NODES * HID);
    float* loop_attr = alloc((size_t)N_NODES * HID);
    float* cnt       = alloc((size_t)N_NODES);
    float* xl        = alloc((size_t)N_NODES * HID);
    float* xr        = alloc((size_t)N_NODES * HID);
    float* logit     = alloc((size_t)EF * HEADS);      // 4.08M floats
    float* mx        = alloc((size_t)N_NODES * HEADS);
    float* den       = alloc((size_t)N_NODES * HEADS);
    float* aggout    = alloc((size_t)N_NODES * HID);
    float* gsum      = alloc((size_t)N_GRAPHS * HID);
    float* gcnt      = alloc((size_t)N_GRAPHS);
    float* stat      = alloc((size_t)N_EDGES * 2);     // mean,rstd per edge (3.84 MB)
    size_t base_bytes = off * sizeof(float);
    float*  ea32 = ws + off;
    __half* ea16 = (__half*)(ws + off);
    int mode = 0;
    if (ws_size >= base_bytes + (size_t)N_EDGES * HID * sizeof(float)) mode = 2;
    else if (ws_size >= base_bytes + (size_t)N_EDGES * HID * sizeof(__half)) mode = 1;
    // aliases (disjoint lifetimes):
    float* xc   = logit;  // [N,72] = 2.16M floats, used only pre-layers; logit is 4.08M
    float* tmp1 = xl;     // used only post-layers
    (void)in_sizes; (void)n_in; (void)out_size;

    float* pred_noise = (float*)d_out;                              // [N,64]
    float* pred_props = (float*)d_out + (size_t)N_NODES * NODE_OUT; // [16,8]

    // 1. time MLP
    hipLaunchKernelGGL(time_mlp_kernel, dim3(N_GRAPHS), dim3(HID), 0, stream,
                       t, tW1, tb1, tW2, tb2, t_emb);
    // 2. concat
    hipLaunchKernelGGL(concat_kernel, dim3((N_NODES * 72 + 255) / 256), dim3(256), 0, stream,
                       x, conds, batch, xc);
    // 3. node encoder gemm + LN/GELU (+t_emb[batch])
    hipLaunchKernelGGL((gemm_kernel<HID, 8>), dim3(N_NODES / 8), dim3(HID), 0, stream,
                       xc, encW, encb, h, N_NODES, 72);
    hipLaunchKernelGGL(ln_gelu_kernel, dim3(N_NODES), dim3(HID), 0, stream,
                       h, encg, encbe, t_emb, batch);
    // 4. edge encode (ea memoized per mode) + self-loop segment-mean
    hipLaunchKernelGGL(zero_kernel, dim3(1024), dim3(256), 0, stream,
                       loop_attr, (long)N_NODES * HID);
    hipLaunchKernelGGL(zero_kernel, dim3(64), dim3(256), 0, stream, cnt, (long)N_NODES);
    if (mode == 2) {
        hipLaunchKernelGGL((edge_enc_loop_kernel<8, 2>), dim3(N_EDGES / 8), dim3(HID), 0, stream,
                           edge_attr, eW, eb, eg, ebe, ei_dst, loop_attr, cnt, stat, ea32, ea16);
    } else if (mode == 1) {
        hipLaunchKernelGGL(edge_enc_loop_w_kernel, dim3(N_EDGES / 8), dim3(128), 0, stream,
                           edge_attr, eW, eb, eg, ebe, ei_dst, loop_attr, cnt, ea16);
    } else {
        hipLaunchKernelGGL((edge_enc_loop_kernel<8, 0>), dim3(N_EDGES / 8), dim3(HID), 0, stream,
                           edge_attr, eW, eb, eg, ebe, ei_dst, loop_attr, cnt, stat, ea32, ea16);
    }
    hipLaunchKernelGGL(loop_div_kernel, dim3((N_NODES * HID + 255) / 256), dim3(256), 0, stream,
                       loop_attr, cnt);

    // 5. layers
    for (int l = 0; l < NLAYERS; ++l) {
        const float* cWl_l = cWl + (size_t)l * HID * HID;
        const float* cWr_l = cWr + (size_t)l * HID * HID;
        const float* cWe_l = cWe + (size_t)l * HID * HID;
        const float* cbl_l = cbl + (size_t)l * HID;
        const float* cbr_l = cbr + (size_t)l * HID;
        const float* catt_l = catt + (size_t)l * HID;
        const float* cbias_l = cbias + (size_t)l * HID;

        hipLaunchKernelGGL((gemm2_kernel<8>), dim3(N_NODES / 8), dim3(HID), 0, stream,
                           h, cWl_l, cbl_l, cWr_l, cbr_l, xl, xr, N_NODES);
        hipLaunchKernelGGL(init_mx_den_kernel, dim3((N_NODES * HEADS + 255) / 256), dim3(256), 0,
                           stream, mx, den);
        if (mode == 2) {
            hipLaunchKernelGGL((att_logit6_kernel<8>), dim3(EF / 8), dim3(HID), 0, stream,
                               ea32, loop_attr, cWe_l, catt_l, xl, xr, ei_src, ei_dst, logit, mx);
        } else if (mode == 1) {
            hipLaunchKernelGGL(att_logit9h_kernel, dim3(EF / 16), dim3(128), 0, stream,
                               ea16, loop_attr, cWe_l, catt_l, xl, xr, ei_src, ei_dst, logit, mx);
        } else {
            hipLaunchKernelGGL((att_logit7_kernel<8>), dim3(EF / 8), dim3(HID), 0, stream,
                               edge_attr, eW, eb, eg, ebe, stat, loop_attr,
                               cWe_l, catt_l, xl, xr, ei_src, ei_dst, logit, mx);
        }
        hipLaunchKernelGGL(softmax_norm_kernel,
                           dim3((int)(((long)EF * HEADS + 255) / 256)), dim3(256), 0, stream,
                           ei_dst, mx, logit, den);
        hipLaunchKernelGGL(zero_kernel, dim3(1024), dim3(256), 0, stream,
                           aggout, (long)N_NODES * HID);
        hipLaunchKernelGGL(aggregate_kernel,
                           dim3((int)(((long)EF * HID + 255) / 256)), dim3(256), 0, stream,
                           logit, den, xl, ei_src, ei_dst, aggout);
        hipLaunchKernelGGL(residual_kernel, dim3((N_NODES * HID + 255) / 256), dim3(256), 0, stream,
                           aggout, cbias_l, h);
    }

    // 6. noise head
    hipLaunchKernelGGL((gemm_kernel<HID, 8>), dim3(N_NODES / 8), dim3(HID), 0, stream,
                       h, nW1, nb1, tmp1, N_NODES, HID);
    hipLaunchKernelGGL(ln_gelu_kernel, dim3(N_NODES), dim3(HID), 0, stream,
                       tmp1, ng, nbe, (const float*)nullptr, (const int*)nullptr);
    hipLaunchKernelGGL((gemm_kernel<NODE_OUT, 8>), dim3(N_NODES / 8), dim3(NODE_OUT), 0, stream,
                       tmp1, nW2, nb2, pred_noise, N_NODES, HID);

    // 7. pooling + props head
    hipLaunchKernelGGL(zero_kernel, dim3(4), dim3(256), 0, stream,
                       gsum, (long)N_GRAPHS * HID);
    hipLaunchKernelGGL(zero_kernel, dim3(1), dim3(64), 0, stream, gcnt, (long)N_GRAPHS);
    hipLaunchKernelGGL(pool_kernel, dim3((N_NODES + POOL_NODES - 1) / POOL_NODES), dim3(HID), 0,
                       stream, h, batch, gsum, gcnt);
    hipLaunchKernelGGL(props_kernel, dim3(N_GRAPHS), dim3(HID), 0, stream,
                       gsum, gcnt, pW1, pb1, pg, pbe, pW2, pb2, pred_props);
}

// Round 11
// 2495.346 us; speedup vs baseline: 1.3014x; 1.3014x over previous
//
#include <hip/hip_runtime.h>
#include <hip/hip_fp16.h>
#include <math.h>

#define N_NODES 30000
#define N_EDGES 480000
#define N_GRAPHS 16
#define HID 128
#define HEADS 8
#define HEAD_DIM 16
#define NODE_IN 64
#define EDGE_IN 32
#define COND 8
#define NODE_OUT 64
#define NLAYERS 4
#define EF (N_EDGES + N_NODES) /* 510000 */
#define LN_EPS 1e-5f
#define SH_STRIDE 132

__device__ __forceinline__ float gelu_f(float x) {
    return 0.5f * x * (1.0f + erff(x * 0.70710678118654752440f));
}

__device__ __forceinline__ void atomicMaxF(float* addr, float val) {
    if (val >= 0.0f) {
        atomicMax((int*)addr, __float_as_int(val));
    } else {
        atomicMin((unsigned int*)addr, __float_as_uint(val));
    }
}

// ---------- generic zero ----------
__global__ void zero_kernel(float* __restrict__ p, long n) {
    long i = (long)blockIdx.x * blockDim.x + threadIdx.x;
    long stride = (long)gridDim.x * blockDim.x;
    for (; i < n; i += stride) p[i] = 0.0f;
}

// ---------- time MLP ----------
__global__ void time_mlp_kernel(const float* __restrict__ t,
                                const float* __restrict__ tW1, const float* __restrict__ tb1,
                                const float* __restrict__ tW2, const float* __restrict__ tb2,
                                float* __restrict__ t_emb) {
    __shared__ float hsh[HID];
    int b = blockIdx.x, j = threadIdx.x;
    float tv = t[b];
    hsh[j] = gelu_f(tv * tW1[j] + tb1[j]);
    __syncthreads();
    float acc = tb2[j];
    for (int k = 0; k < HID; ++k) acc += hsh[k] * tW2[k * HID + j];
    t_emb[b * HID + j] = acc;
}

// ---------- concat ----------
__global__ void concat_kernel(const float* __restrict__ x, const float* __restrict__ cond,
                              const int* __restrict__ batch, float* __restrict__ xc) {
    int idx = blockIdx.x * blockDim.x + threadIdx.x;
    if (idx >= N_NODES * 72) return;
    int n = idx / 72, c = idx % 72;
    xc[idx] = (c < NODE_IN) ? x[n * NODE_IN + c] : cond[batch[n] * COND + (c - NODE_IN)];
}

// ---------- generic GEMM ----------
template <int NCOL, int R>
__global__ void gemm_kernel(const float* __restrict__ A, const float* __restrict__ B,
                            const float* __restrict__ bias, float* __restrict__ C,
                            int M, int K) {
    __shared__ __align__(16) float sh[R * HID];
    int j = threadIdx.x;
    int row0 = blockIdx.x * R;
    int total = R * K;
    for (int i = j; i < total; i += NCOL) {
        int r = i / K, k = i - r * K;
        int row = row0 + r;
        sh[r * K + k] = (row < M) ? A[(long)row * K + k] : 0.0f;
    }
    __syncthreads();
    float acc[R];
    float bv = bias ? bias[j] : 0.0f;
#pragma unroll
    for (int r = 0; r < R; ++r) acc[r] = bv;
    int KB = K >> 2;
    for (int kb = 0; kb < KB; ++kb) {
        float w0 = B[(kb * 4 + 0) * NCOL + j];
        float w1 = B[(kb * 4 + 1) * NCOL + j];
        float w2 = B[(kb * 4 + 2) * NCOL + j];
        float w3 = B[(kb * 4 + 3) * NCOL + j];
#pragma unroll
        for (int r = 0; r < R; ++r) {
            float4 a = *(const float4*)&sh[r * K + kb * 4];
            acc[r] += a.x * w0 + a.y * w1 + a.z * w2 + a.w * w3;
        }
    }
#pragma unroll
    for (int r = 0; r < R; ++r) {
        int row = row0 + r;
        if (row < M) C[(long)row * NCOL + j] = acc[r];
    }
}

// ---------- fused dual GEMM ----------
template <int R>
__global__ void gemm2_kernel(const float* __restrict__ A,
                             const float* __restrict__ Bl, const float* __restrict__ bl,
                             const float* __restrict__ Br, const float* __restrict__ br,
                             float* __restrict__ Cl, float* __restrict__ Cr, int M) {
    __shared__ __align__(16) float sh[R * HID];
    int j = threadIdx.x;
    int row0 = blockIdx.x * R;
    for (int i = j; i < R * HID; i += HID) {
        int r = i >> 7, k = i & 127;
        int row = row0 + r;
        sh[i] = (row < M) ? A[(long)row * HID + k] : 0.0f;
    }
    __syncthreads();
    float accl[R], accr[R];
    float blv = bl[j], brv = br[j];
#pragma unroll
    for (int r = 0; r < R; ++r) { accl[r] = blv; accr[r] = brv; }
    for (int kb = 0; kb < HID / 4; ++kb) {
        float l0 = Bl[(kb * 4 + 0) * HID + j];
        float l1 = Bl[(kb * 4 + 1) * HID + j];
        float l2 = Bl[(kb * 4 + 2) * HID + j];
        float l3 = Bl[(kb * 4 + 3) * HID + j];
        float r0 = Br[(kb * 4 + 0) * HID + j];
        float r1 = Br[(kb * 4 + 1) * HID + j];
        float r2 = Br[(kb * 4 + 2) * HID + j];
        float r3 = Br[(kb * 4 + 3) * HID + j];
#pragma unroll
        for (int r = 0; r < R; ++r) {
            float4 a = *(const float4*)&sh[r * HID + kb * 4];
            accl[r] += a.x * l0 + a.y * l1 + a.z * l2 + a.w * l3;
            accr[r] += a.x * r0 + a.y * r1 + a.z * r2 + a.w * r3;
        }
    }
#pragma unroll
    for (int r = 0; r < R; ++r) {
        int row = row0 + r;
        if (row < M) {
            Cl[(long)row * HID + j] = accl[r];
            Cr[(long)row * HID + j] = accr[r];
        }
    }
}

// ---------- in-place LayerNorm + GELU ----------
__global__ void ln_gelu_kernel(float* __restrict__ X, const float* __restrict__ g,
                               const float* __restrict__ bta,
                               const float* __restrict__ t_emb, const int* __restrict__ batch) {
    int row = blockIdx.x, j = threadIdx.x;
    __shared__ float red[HID];
    float v = X[(long)row * HID + j];
    red[j] = v;
    __syncthreads();
    for (int s = 64; s > 0; s >>= 1) { if (j < s) red[j] += red[j + s]; __syncthreads(); }
    float mean = red[0] * (1.0f / HID);
    __syncthreads();
    float d = v - mean;
    red[j] = d * d;
    __syncthreads();
    for (int s = 64; s > 0; s >>= 1) { if (j < s) red[j] += red[j + s]; __syncthreads(); }
    float var = red[0] * (1.0f / HID);
    float y = gelu_f(d * rsqrtf(var + LN_EPS) * g[j] + bta[j]);
    if (t_emb) y += t_emb[batch[row] * HID + j];
    X[(long)row * HID + j] = y;
}

// ================= CSR sort setup (mode 1) =================
// hist: counts into ibase[d+1]
__global__ void hist_kernel(const int* __restrict__ ei_dst, int* __restrict__ ibase) {
    int idx = blockIdx.x * blockDim.x + threadIdx.x;
    if (idx >= EF) return;
    int d = (idx < N_EDGES) ? ei_dst[idx] : (idx - N_EDGES);
    atomicAdd(&ibase[d + 1], 1);
}

// single-block prefix sum: ibase[1..N] -> inclusive prefix (ibase[0]=0 pre-zeroed)
__global__ __launch_bounds__(1024) void scan_kernel(int* __restrict__ ibase) {
    __shared__ int wsums[16];
    __shared__ int s_carry;
    int t = threadIdx.x, lane = t & 63, w = t >> 6;
    if (t == 0) s_carry = 0;
    __syncthreads();
    for (int start = 0; start < N_NODES; start += 1024) {
        int i = start + t;
        int v = (i < N_NODES) ? ibase[i + 1] : 0;
        int x = v;
#pragma unroll
        for (int m = 1; m < 64; m <<= 1) {
            int y = __shfl_up(x, m);
            if (lane >= m) x += y;
        }
        if (lane == 63) wsums[w] = x;
        __syncthreads();
        if (w == 0 && lane < 16) {
            int ws = wsums[lane];
#pragma unroll
            for (int m = 1; m < 16; m <<= 1) {
                int y = __shfl_up(ws, m);
                if (lane >= m) ws += y;
            }
            wsums[lane] = ws;
        }
        __syncthreads();
        int waveoff = (w == 0) ? 0 : wsums[w - 1];
        int incl = x + waveoff + s_carry;
        if (i < N_NODES) ibase[i + 1] = incl;
        __syncthreads();
        if (t == 1023) s_carry = incl;
        __syncthreads();
    }
}

// scatter: fill src_s/dst_s and inv (orig index -> sorted pos)
__global__ void scatter_kernel(const int* __restrict__ ei_src, const int* __restrict__ ei_dst,
                               const int* __restrict__ ibase, int* __restrict__ icursor,
                               int* __restrict__ src_s, int* __restrict__ dst_s,
                               int* __restrict__ inv) {
    int idx = blockIdx.x * blockDim.x + threadIdx.x;
    if (idx >= EF) return;
    int s, d;
    if (idx < N_EDGES) { s = ei_src[idx]; d = ei_dst[idx]; }
    else               { s = d = idx - N_EDGES; }
    int pos = ibase[d] + atomicAdd(&icursor[d], 1);
    src_s[pos] = s;
    dst_s[pos] = d;
    inv[idx] = pos;
}

// fill self-loop rows of sorted ea16 from loop_attr
__global__ void fill_loop_ea_kernel(const float* __restrict__ loop_attr,
                                    const int* __restrict__ inv,
                                    __half* __restrict__ ea16) {
    int idx = blockIdx.x * blockDim.x + threadIdx.x;
    if (idx >= N_NODES * HID) return;
    int n = idx >> 7, j = idx & 127;
    ea16[(long)inv[N_EDGES + n] * HID + j] = __float2half(loop_attr[(long)n * HID + j]);
}

// ---------- fallback (modes 0/2): edge-encode + segment-sum, LDS-tree LN ----------
template <int R, int MODE>
__global__ void edge_enc_loop_kernel(const float* __restrict__ edge_attr,
                                     const float* __restrict__ eW, const float* __restrict__ eb,
                                     const float* __restrict__ eg, const float* __restrict__ ebe,
                                     const int* __restrict__ ei_dst,
                                     float* __restrict__ loop_sum, float* __restrict__ cnt,
                                     float* __restrict__ stat,
                                     float* __restrict__ ea32, __half* __restrict__ ea16) {
    __shared__ float red[R * HID];
    __shared__ __align__(16) float sattr[R * EDGE_IN];
    __shared__ int sdst[R];
    int j = threadIdx.x;
    long e0 = (long)blockIdx.x * R;
    if (j < R * EDGE_IN / 4)
        ((float4*)sattr)[j] = ((const float4*)(edge_attr + e0 * EDGE_IN))[j];
    if (j < R) sdst[j] = ei_dst[e0 + j];
    __syncthreads();
    float val[R];
    float ebv = eb[j];
#pragma unroll
    for (int r = 0; r < R; ++r) val[r] = ebv;
#pragma unroll
    for (int kb = 0; kb < EDGE_IN / 4; ++kb) {
        float w0 = eW[(kb * 4 + 0) * HID + j];
        float w1 = eW[(kb * 4 + 1) * HID + j];
        float w2 = eW[(kb * 4 + 2) * HID + j];
        float w3 = eW[(kb * 4 + 3) * HID + j];
#pragma unroll
        for (int r = 0; r < R; ++r) {
            float4 a = *(const float4*)&sattr[r * EDGE_IN + kb * 4];
            val[r] += a.x * w0 + a.y * w1 + a.z * w2 + a.w * w3;
        }
    }
#pragma unroll
    for (int r = 0; r < R; ++r) red[r * HID + j] = val[r];
    __syncthreads();
    for (int s = 64; s > 0; s >>= 1) {
        if (j < s) {
#pragma unroll
            for (int r = 0; r < R; ++r) red[r * HID + j] += red[r * HID + j + s];
        }
        __syncthreads();
    }
    float mean[R];
#pragma unroll
    for (int r = 0; r < R; ++r) mean[r] = red[r * HID] * (1.0f / HID);
    __syncthreads();
#pragma unroll
    for (int r = 0; r < R; ++r) { float d = val[r] - mean[r]; red[r * HID + j] = d * d; }
    __syncthreads();
    for (int s = 64; s > 0; s >>= 1) {
        if (j < s) {
#pragma unroll
            for (int r = 0; r < R; ++r) red[r * HID + j] += red[r * HID + j + s];
        }
        __syncthreads();
    }
    float egv = eg[j], bev = ebe[j];
#pragma unroll
    for (int r = 0; r < R; ++r) {
        float var = red[r * HID] * (1.0f / HID);
        float rstd = rsqrtf(var + LN_EPS);
        float y = gelu_f((val[r] - mean[r]) * rstd * egv + bev);
        int d = sdst[r];
        long e = e0 + r;
        if (j == 0) { stat[e * 2] = mean[r]; stat[e * 2 + 1] = rstd; }
        if (MODE == 2) ea32[e * HID + j] = y;
        if (MODE == 1) ea16[e * HID + j] = __float2half(y);
        atomicAdd(&loop_sum[(long)d * HID + j], y);
        if (j == 0) atomicAdd(&cnt[d], 1.0f);
    }
}

// ---------- mode-1 MAIN enc: wave-owns-rows, shfl LN, fp16 ea scattered to sorted pos ----------
__global__ __launch_bounds__(128) void edge_enc_loop_w_kernel(
        const float* __restrict__ edge_attr,
        const float* __restrict__ eW, const float* __restrict__ eb,
        const float* __restrict__ eg, const float* __restrict__ ebe,
        const int* __restrict__ ei_dst, const int* __restrict__ inv,
        float* __restrict__ loop_sum, float* __restrict__ cnt,
        __half* __restrict__ ea16) {
    const int R = 8;
    __shared__ __align__(16) float sattr[R * EDGE_IN];
    __shared__ int sdst[R], spos[R];
    int t = threadIdx.x;
    long e0 = (long)blockIdx.x * R;
    if (t < R * EDGE_IN / 4)
        ((float4*)sattr)[t] = ((const float4*)(edge_attr + e0 * EDGE_IN))[t];
    if (t < R) { sdst[t] = ei_dst[e0 + t]; spos[t] = inv[e0 + t]; }
    __syncthreads();
    int lane = t & 63, w = t >> 6;
    int r0 = w * 4;
    int j1 = lane, j2 = lane + 64;
    float eb1 = eb[j1], eb2 = eb[j2];
    float v0[4], v1[4];
#pragma unroll
    for (int q = 0; q < 4; ++q) { v0[q] = eb1; v1[q] = eb2; }
#pragma unroll
    for (int kb = 0; kb < EDGE_IN / 4; ++kb) {
        float w10 = eW[(kb * 4 + 0) * HID + j1];
        float w11 = eW[(kb * 4 + 1) * HID + j1];
        float w12 = eW[(kb * 4 + 2) * HID + j1];
        float w13 = eW[(kb * 4 + 3) * HID + j1];
        float w20 = eW[(kb * 4 + 0) * HID + j2];
        float w21 = eW[(kb * 4 + 1) * HID + j2];
        float w22 = eW[(kb * 4 + 2) * HID + j2];
        float w23 = eW[(kb * 4 + 3) * HID + j2];
#pragma unroll
        for (int q = 0; q < 4; ++q) {
            float4 a = *(const float4*)&sattr[(r0 + q) * EDGE_IN + kb * 4];
            v0[q] += a.x * w10 + a.y * w11 + a.z * w12 + a.w * w13;
            v1[q] += a.x * w20 + a.y * w21 + a.z * w22 + a.w * w23;
        }
    }
    float eg1 = eg[j1], eg2 = eg[j2];
    float be1 = ebe[j1], be2 = ebe[j2];
#pragma unroll
    for (int q = 0; q < 4; ++q) {
        float s1 = v0[q] + v1[q];
        float s2 = v0[q] * v0[q] + v1[q] * v1[q];
#pragma unroll
        for (int m = 1; m < 64; m <<= 1) {
            s1 += __shfl_xor(s1, m);
            s2 += __shfl_xor(s2, m);
        }
        float mean = s1 * (1.0f / 128.0f);
        float var = s2 * (1.0f / 128.0f) - mean * mean;
        float rstd = rsqrtf(var + LN_EPS);
        float y0 = gelu_f((v0[q] - mean) * rstd * eg1 + be1);
        float y1 = gelu_f((v1[q] - mean) * rstd * eg2 + be2);
        long pos = spos[r0 + q];
        int d = sdst[r0 + q];
        ea16[pos * HID + j1] = __float2half(y0);
        ea16[pos * HID + j2] = __float2half(y1);
        atomicAdd(&loop_sum[(long)d * HID + j1], y0);
        atomicAdd(&loop_sum[(long)d * HID + j2], y1);
        if (lane == 0) atomicAdd(&cnt[d], 1.0f);
    }
}

__global__ void loop_div_kernel(float* __restrict__ loop_attr, const float* __restrict__ cnt) {
    int idx = blockIdx.x * blockDim.x + threadIdx.x;
    if (idx >= N_NODES * HID) return;
    int n = idx >> 7;
    loop_attr[idx] = loop_attr[idx] / fmaxf(cnt[n], 1.0f);
}

// ---------- init mx=-inf, den=0 (modes 0/2) ----------
__global__ void init_mx_den_kernel(float* __restrict__ mx, float* __restrict__ den) {
    int idx = blockIdx.x * blockDim.x + threadIdx.x;
    if (idx >= N_NODES * HEADS) return;
    mx[idx] = -INFINITY;
    den[idx] = 0.0f;
}

// ---------- shared epilogue (fallback variants) ----------
template <int R>
__device__ __forceinline__ void em_logit_body(
        const float* __restrict__ sh, const int* __restrict__ ssrc, const int* __restrict__ sdst,
        const float* __restrict__ cWe_l, const float* __restrict__ catt_l,
        const float* __restrict__ xl, const float* __restrict__ xr,
        float* __restrict__ logit, float* __restrict__ mx, long e0, int j) {
    float acc[R];
#pragma unroll
    for (int r = 0; r < R; ++r) acc[r] = 0.0f;
    for (int kb = 0; kb < HID / 4; ++kb) {
        float w0 = cWe_l[(kb * 4 + 0) * HID + j];
        float w1 = cWe_l[(kb * 4 + 1) * HID + j];
        float w2 = cWe_l[(kb * 4 + 2) * HID + j];
        float w3 = cWe_l[(kb * 4 + 3) * HID + j];
#pragma unroll
        for (int r = 0; r < R; ++r) {
            float4 a = *(const float4*)&sh[r * HID + kb * 4];
            acc[r] += a.x * w0 + a.y * w1 + a.z * w2 + a.w * w3;
        }
    }
    float cj = catt_l[j];
    int head = j >> 4;
#pragma unroll
    for (int r = 0; r < R; ++r) {
        long e = e0 + r;
        int s = ssrc[r], d = sdst[r];
        float m = xl[(long)s * HID + j] + xr[(long)d * HID + j] + acc[r];
        m = (m > 0.0f) ? m : 0.2f * m;
        float p = m * cj;
        p += __shfl_down(p, 8, 16);
        p += __shfl_down(p, 4, 16);
        p += __shfl_down(p, 2, 16);
        p += __shfl_down(p, 1, 16);
        if ((j & 15) == 0) {
            logit[e * HEADS + head] = p;
            atomicMaxF(&mx[(long)d * HEADS + head], p);
        }
    }
}

// ---------- att kernel, mode 0 fallback ----------
template <int R>
__global__ void att_logit7_kernel(const float* __restrict__ edge_attr,
                                  const float* __restrict__ eW, const float* __restrict__ eb,
                                  const float* __restrict__ eg, const float* __restrict__ ebe,
                                  const float* __restrict__ stat,
                                  const float* __restrict__ loop_attr,
                                  const float* __restrict__ cWe_l, const float* __restrict__ catt_l,
                                  const float* __restrict__ xl, const float* __restrict__ xr,
                                  const int* __restrict__ ei_src, const int* __restrict__ ei_dst,
                                  float* __restrict__ logit, float* __restrict__ mx) {
    __shared__ __align__(16) float sh[R * HID];
    __shared__ __align__(16) float sattr[R * EDGE_IN];
    __shared__ float sstat[R * 2];
    __shared__ int ssrc[R], sdst[R];
    int j = threadIdx.x;
    long e0 = (long)blockIdx.x * R;
    bool realblk = (e0 < N_EDGES);

    if (realblk) {
        if (j < R * EDGE_IN / 4)
            ((float4*)sattr)[j] = ((const float4*)(edge_attr + e0 * EDGE_IN))[j];
        if (j < R * 2) sstat[j] = stat[e0 * 2 + j];
        if (j < R) { ssrc[j] = ei_src[e0 + j]; sdst[j] = ei_dst[e0 + j]; }
    } else {
        if (j < R) ssrc[j] = sdst[j] = (int)(e0 + j - N_EDGES);
    }
    __syncthreads();

    if (realblk) {
        float val[R];
        float ebv = eb[j];
#pragma unroll
        for (int r = 0; r < R; ++r) val[r] = ebv;
#pragma unroll
        for (int kb = 0; kb < EDGE_IN / 4; ++kb) {
            float w0 = eW[(kb * 4 + 0) * HID + j];
            float w1 = eW[(kb * 4 + 1) * HID + j];
            float w2 = eW[(kb * 4 + 2) * HID + j];
            float w3 = eW[(kb * 4 + 3) * HID + j];
#pragma unroll
            for (int r = 0; r < R; ++r) {
                float4 a = *(const float4*)&sattr[r * EDGE_IN + kb * 4];
                val[r] += a.x * w0 + a.y * w1 + a.z * w2 + a.w * w3;
            }
        }
        float egv = eg[j], bev = ebe[j];
#pragma unroll
        for (int r = 0; r < R; ++r) {
            float mean = sstat[r * 2], rstd = sstat[r * 2 + 1];
            sh[r * HID + j] = gelu_f((val[r] - mean) * rstd * egv + bev);
        }
    } else {
#pragma unroll
        for (int r = 0; r < R; ++r)
            sh[r * HID + j] = loop_attr[(long)(e0 + r - N_EDGES) * HID + j];
    }
    __syncthreads();
    em_logit_body<R>(sh, ssrc, sdst, cWe_l, catt_l, xl, xr, logit, mx, e0, j);
}

// ---------- att kernel, mode 2 fallback ----------
template <int R>
__global__ void att_logit6_kernel(const float* __restrict__ ea,
                                  const float* __restrict__ loop_attr,
                                  const float* __restrict__ cWe_l, const float* __restrict__ catt_l,
                                  const float* __restrict__ xl, const float* __restrict__ xr,
                                  const int* __restrict__ ei_src, const int* __restrict__ ei_dst,
                                  float* __restrict__ logit, float* __restrict__ mx) {
    __shared__ __align__(16) float sh[R * HID];
    __shared__ int ssrc[R], sdst[R];
    int j = threadIdx.x;
    long e0 = (long)blockIdx.x * R;
    bool realblk = (e0 < N_EDGES);
    const float* srcp = realblk ? (ea + e0 * HID) : (loop_attr + (e0 - N_EDGES) * HID);
    const float4* s4 = (const float4*)srcp;
    ((float4*)sh)[j]       = s4[j];
    ((float4*)sh)[j + HID] = s4[j + HID];
    if (j < R) {
        long e = e0 + j;
        if (realblk) { ssrc[j] = ei_src[e]; sdst[j] = ei_dst[e]; }
        else         { ssrc[j] = sdst[j] = (int)(e - N_EDGES); }
    }
    __syncthreads();
    em_logit_body<R>(sh, ssrc, sdst, cWe_l, catt_l, xl, xr, logit, mx, e0, j);
}

// ---------- att kernel, mode 1 MAIN: sorted fp16 ea stream, no atomics, no branches ----------
__global__ __launch_bounds__(128) void att_logit10h_kernel(
        const __half* __restrict__ ea,          /* sorted [EF,128] */
        const int* __restrict__ src_s, const int* __restrict__ dst_s,
        const float* __restrict__ cWe_l, const float* __restrict__ catt_l,
        const float* __restrict__ xl, const float* __restrict__ xr,
        float* __restrict__ logit) {
    const int R = 16;
    __shared__ __align__(16) float sh[R * SH_STRIDE];
    __shared__ int ssrc[R], sdst[R];
    int t = threadIdx.x;
    long e0 = (long)blockIdx.x * R;

    const uint4* s16 = (const uint4*)(ea + e0 * HID);
#pragma unroll
    for (int i = 0; i < 2; ++i) {
        uint4 u = s16[t + i * 128];
        int o = (t + i * 128) * 8;
        int row = o >> 7, col = o & 127;
        float* dst = &sh[row * SH_STRIDE + col];
        const __half2* hp = (const __half2*)&u;
        float2 f0 = __half22float2(hp[0]);
        float2 f1 = __half22float2(hp[1]);
        float2 f2 = __half22float2(hp[2]);
        float2 f3 = __half22float2(hp[3]);
        *(float4*)dst       = make_float4(f0.x, f0.y, f1.x, f1.y);
        *(float4*)(dst + 4) = make_float4(f2.x, f2.y, f3.x, f3.y);
    }
    if (t < R) ssrc[t] = src_s[e0 + t];
    else if (t < 2 * R) sdst[t - R] = dst_s[e0 + (t - R)];
    __syncthreads();

    int cg = t & 31, rg = t >> 5;
    int c0 = cg * 4;
    float acc[4][4];
#pragma unroll
    for (int i = 0; i < 4; ++i)
#pragma unroll
        for (int c = 0; c < 4; ++c) acc[i][c] = 0.0f;
    for (int kb = 0; kb < HID / 4; ++kb) {
        float4 w0 = *(const float4*)&cWe_l[(kb * 4 + 0) * HID + c0];
        float4 w1 = *(const float4*)&cWe_l[(kb * 4 + 1) * HID + c0];
        float4 w2 = *(const float4*)&cWe_l[(kb * 4 + 2) * HID + c0];
        float4 w3 = *(const float4*)&cWe_l[(kb * 4 + 3) * HID + c0];
#pragma unroll
        for (int i = 0; i < 4; ++i) {
            float4 a = *(const float4*)&sh[(rg * 4 + i) * SH_STRIDE + kb * 4];
            acc[i][0] += a.x * w0.x + a.y * w1.x + a.z * w2.x + a.w * w3.x;
            acc[i][1] += a.x * w0.y + a.y * w1.y + a.z * w2.y + a.w * w3.y;
            acc[i][2] += a.x * w0.z + a.y * w1.z + a.z * w2.z + a.w * w3.z;
            acc[i][3] += a.x * w0.w + a.y * w1.w + a.z * w2.w + a.w * w3.w;
        }
    }

    float4 cat4 = *(const float4*)&catt_l[c0];
    int head = cg >> 2;
#pragma unroll
    for (int i = 0; i < 4; ++i) {
        int r = rg * 4 + i;
        long e = e0 + r;
        int s = ssrc[r], d = sdst[r];
        float4 xlv = *(const float4*)&xl[(long)s * HID + c0];
        float4 xrv = *(const float4*)&xr[(long)d * HID + c0];
        float m0 = xlv.x + xrv.x + acc[i][0]; m0 = (m0 > 0.0f) ? m0 : 0.2f * m0;
        float m1 = xlv.y + xrv.y + acc[i][1]; m1 = (m1 > 0.0f) ? m1 : 0.2f * m1;
        float m2 = xlv.z + xrv.z + acc[i][2]; m2 = (m2 > 0.0f) ? m2 : 0.2f * m2;
        float m3 = xlv.w + xrv.w + acc[i][3]; m3 = (m3 > 0.0f) ? m3 : 0.2f * m3;
        float p = m0 * cat4.x + m1 * cat4.y + m2 * cat4.z + m3 * cat4.w;
        p += __shfl_xor(p, 1);
        p += __shfl_xor(p, 2);
        if ((cg & 3) == 0) logit[e * HEADS + head] = p;
    }
}

// ---------- CSR fused softmax + aggregate + residual (mode 1) ----------
// One wave per dst node. Per-head max/den via strided loop + shfl_xor; then
// accumulate alpha*xl[src] (2 cols/lane) and apply gelu+bias residual in place.
__global__ __launch_bounds__(128) void csr_smax_agg_kernel(
        const int* __restrict__ ibase, const int* __restrict__ src_s,
        const float* __restrict__ logit, const float* __restrict__ xl,
        const float* __restrict__ cbias_l, float* __restrict__ h) {
    int w = threadIdx.x >> 6, lane = threadIdx.x & 63;
    int d = blockIdx.x * 2 + w;
    if (d >= N_NODES) return;
    int b0 = ibase[d], b1 = ibase[d + 1];
    int hh = lane & 7, g = lane >> 3;
    float m = -INFINITY;
    for (int i = b0 + g; i < b1; i += 8) m = fmaxf(m, logit[(long)i * 8 + hh]);
    m = fmaxf(m, __shfl_xor(m, 8));
    m = fmaxf(m, __shfl_xor(m, 16));
    m = fmaxf(m, __shfl_xor(m, 32));
    float den = 0.0f;
    for (int i = b0 + g; i < b1; i += 8) den += expf(logit[(long)i * 8 + hh] - m);
    den += __shfl_xor(den, 8);
    den += __shfl_xor(den, 16);
    den += __shfl_xor(den, 32);
    int h1 = lane >> 4, h2 = 4 + (lane >> 4);
    float mx1 = __shfl(m, h1), mx2 = __shfl(m, h2);
    float dn1 = __shfl(den, h1) + 1e-16f, dn2 = __shfl(den, h2) + 1e-16f;
    float acc0 = 0.0f, acc1 = 0.0f;
    for (int i = b0; i < b1; ++i) {
        int s = src_s[i];
        float a0 = expf(logit[(long)i * 8 + h1] - mx1) / dn1;
        float a1 = expf(logit[(long)i * 8 + h2] - mx2) / dn2;
        acc0 += a0 * xl[(long)s * HID + lane];
        acc1 += a1 * xl[(long)s * HID + lane + 64];
    }
    long o = (long)d * HID + lane;
    h[o]      = gelu_f(acc0 + cbias_l[lane])      + h[o];
    h[o + 64] = gelu_f(acc1 + cbias_l[lane + 64]) + h[o + 64];
}

// ---------- fallback chain kernels (modes 0/2) ----------
__global__ void softmax_norm_kernel(const int* __restrict__ ei_dst, const float* __restrict__ mx,
                                    float* __restrict__ logit, float* __restrict__ den) {
    long idx = (long)blockIdx.x * blockDim.x + threadIdx.x;
    if (idx >= (long)EF * HEADS) return;
    long e = idx >> 3;
    int hh = (int)(idx & 7);
    int d = (e < N_EDGES) ? ei_dst[e] : (int)(e - N_EDGES);
    float ex = expf(logit[idx] - mx[(long)d * HEADS + hh]);
    logit[idx] = ex;
    atomicAdd(&den[(long)d * HEADS + hh], ex);
}

__global__ void aggregate_kernel(const float* __restrict__ logit, const float* __restrict__ den,
                                 const float* __restrict__ xl,
                                 const int* __restrict__ ei_src, const int* __restrict__ ei_dst,
                                 float* __restrict__ aggout) {
    long idx = (long)blockIdx.x * blockDim.x + threadIdx.x;
    if (idx >= (long)EF * HID) return;
    long e = idx >> 7;
    int j = (int)(idx & 127);
    int s, d;
    if (e < N_EDGES) { s = ei_src[e]; d = ei_dst[e]; }
    else             { s = d = (int)(e - N_EDGES); }
    int head = j >> 4;
    float alpha = logit[e * HEADS + head] / (den[(long)d * HEADS + head] + 1e-16f);
    atomicAdd(&aggout[(long)d * HID + j], alpha * xl[(long)s * HID + j]);
}

__global__ void residual_kernel(const float* __restrict__ aggout, const float* __restrict__ cbias_l,
                                float* __restrict__ h) {
    int idx = blockIdx.x * blockDim.x + threadIdx.x;
    if (idx >= N_NODES * HID) return;
    int j = idx & 127;
    h[idx] = gelu_f(aggout[idx] + cbias_l[j]) + h[idx];
}

// ---------- pooling ----------
#define POOL_NODES 64
__global__ void pool_kernel(const float* __restrict__ h, const int* __restrict__ batch,
                            float* __restrict__ gsum, float* __restrict__ gcnt) {
    __shared__ float acc[N_GRAPHS][HID];
    __shared__ float cnt_sh[N_GRAPHS];
    int j = threadIdx.x;
    for (int g = 0; g < N_GRAPHS; ++g) acc[g][j] = 0.0f;
    if (j < N_GRAPHS) cnt_sh[j] = 0.0f;
    __syncthreads();
    int n0 = blockIdx.x * POOL_NODES;
    for (int i = 0; i < POOL_NODES; ++i) {
        int n = n0 + i;
        if (n >= N_NODES) break;
        int g = batch[n];
        acc[g][j] += h[(long)n * HID + j];
        if (j == 0) cnt_sh[g] += 1.0f;
    }
    __syncthreads();
    for (int g = 0; g < N_GRAPHS; ++g) atomicAdd(&gsum[g * HID + j], acc[g][j]);
    if (j < N_GRAPHS) atomicAdd(&gcnt[j], cnt_sh[j]);
}

// ---------- props head ----------
__global__ void props_kernel(const float* __restrict__ gsum, const float* __restrict__ gcnt,
                             const float* __restrict__ pW1, const float* __restrict__ pb1,
                             const float* __restrict__ pg, const float* __restrict__ pbe,
                             const float* __restrict__ pW2, const float* __restrict__ pb2,
                             float* __restrict__ out_props) {
    int g = blockIdx.x, j = threadIdx.x;
    __shared__ float feat[HID], red[HID], t2[HID];
    float c = fmaxf(gcnt[g], 1.0f);
    feat[j] = gsum[g * HID + j] / c;
    __syncthreads();
    float acc = pb1[j];
    for (int k = 0; k < HID; ++k) acc += feat[k] * pW1[k * HID + j];
    red[j] = acc;
    __syncthreads();
    for (int s = 64; s > 0; s >>= 1) { if (j < s) red[j] += red[j + s]; __syncthreads(); }
    float mean = red[0] * (1.0f / HID);
    __syncthreads();
    float dd = acc - mean;
    red[j] = dd * dd;
    __syncthreads();
    for (int s = 64; s > 0; s >>= 1) { if (j < s) red[j] += red[j + s]; __syncthreads(); }
    float var = red[0] * (1.0f / HID);
    t2[j] = gelu_f(dd * rsqrtf(var + LN_EPS) * pg[j] + pbe[j]);
    __syncthreads();
    if (j < COND) {
        float a = pb2[j];
        for (int k = 0; k < HID; ++k) a += t2[k] * pW2[k * COND + j];
        out_props[g * COND + j] = a;
    }
}

extern "C" void kernel_launch(void* const* d_in, const int* in_sizes, int n_in,
                              void* d_out, int out_size, void* d_ws, size_t ws_size,
                              hipStream_t stream) {
    const float* x        = (const float*)d_in[0];
    const float* edge_attr= (const float*)d_in[1];
    const float* t        = (const float*)d_in[2];
    const float* conds    = (const float*)d_in[3];
    const float* tW1      = (const float*)d_in[4];
    const float* tb1      = (const float*)d_in[5];
    const float* tW2      = (const float*)d_in[6];
    const float* tb2      = (const float*)d_in[7];
    const float* encW     = (const float*)d_in[8];
    const float* encb     = (const float*)d_in[9];
    const float* encg     = (const float*)d_in[10];
    const float* encbe    = (const float*)d_in[11];
    const float* eW       = (const float*)d_in[12];
    const float* eb       = (const float*)d_in[13];
    const float* eg       = (const float*)d_in[14];
    const float* ebe      = (const float*)d_in[15];
    const float* cWl      = (const float*)d_in[16];
    const float* cbl      = (const float*)d_in[17];
    const float* cWr      = (const float*)d_in[18];
    const float* cbr      = (const float*)d_in[19];
    const float* cWe      = (const float*)d_in[20];
    const float* catt     = (const float*)d_in[21];
    const float* cbias    = (const float*)d_in[22];
    const float* nW1      = (const float*)d_in[23];
    const float* nb1      = (const float*)d_in[24];
    const float* ng       = (const float*)d_in[25];
    const float* nbe      = (const float*)d_in[26];
    const float* nW2      = (const float*)d_in[27];
    const float* nb2      = (const float*)d_in[28];
    const float* pW1      = (const float*)d_in[29];
    const float* pb1      = (const float*)d_in[30];
    const float* pg       = (const float*)d_in[31];
    const float* pbe      = (const float*)d_in[32];
    const float* pW2      = (const float*)d_in[33];
    const float* pb2      = (const float*)d_in[34];
    const int* edge_index = (const int*)d_in[35];
    const int* batch      = (const int*)d_in[36];
    const int* ei_src = edge_index;
    const int* ei_dst = edge_index + N_EDGES;

    // workspace: common + union(mode1 sort ints | mode0/2 stat+mx+den+aggout) + ea
    float* ws = (float*)d_ws;
    size_t off = 0;
    auto alloc = [&](size_t n) { float* p = ws + off; off += n; return p; };
    float* t_emb     = alloc((size_t)N_GRAPHS * HID);
    float* h         = alloc((size_t)N_NODES * HID);
    float* loop_attr = alloc((size_t)N_NODES * HID);
    float* cnt       = alloc((size_t)N_NODES);
    float* xl        = alloc((size_t)N_NODES * HID);
    float* xr        = alloc((size_t)N_NODES * HID);
    float* logit     = alloc((size_t)EF * HEADS);      // 4.08M floats
    float* gsum      = alloc((size_t)N_GRAPHS * HID);
    float* gcnt      = alloc((size_t)N_GRAPHS);
    // union region (5.28M float slots, same total as round-10's layout):
    float* uni = alloc((size_t)(960000 + 240000 + 240000 + (size_t)N_NODES * HID));
    // mode-0/2 view:
    float* stat   = uni;                  // [N_EDGES*2]
    float* mx     = uni + 960000;         // [N*8]
    float* den    = uni + 960000 + 240000;
    float* aggout = uni + 960000 + 480000; // [N*128]
    // mode-1 view (ints):
    int* ibase   = (int*)uni;                         // [N_NODES+1]
    int* icursor = ibase + (N_NODES + 1);             // [N_NODES]
    int* src_s   = icursor + N_NODES;                 // [EF]
    int* dst_s   = src_s + EF;                        // [EF]
    int* inv     = dst_s + EF;                        // [EF]  (total 1.59M ints < 5.28M slots)
    size_t base_bytes = off * sizeof(float);
    float*  ea32 = ws + off;
    __half* ea16 = (__half*)(ws + off);
    int mode = 0;
    if (ws_size >= base_bytes + (size_t)EF * HID * sizeof(float)) mode = 2;
    else if (ws_size >= base_bytes + (size_t)EF * HID * sizeof(__half)) mode = 1;
    // aliases (disjoint lifetimes):
    float* xc   = logit;  // [N,72] used only pre-layers
    float* tmp1 = xl;     // used only post-layers
    (void)in_sizes; (void)n_in; (void)out_size;

    float* pred_noise = (float*)d_out;                              // [N,64]
    float* pred_props = (float*)d_out + (size_t)N_NODES * NODE_OUT; // [16,8]

    // 0. (mode 1) CSR sort of edges by dst, self-loops included
    if (mode == 1) {
        hipLaunchKernelGGL(zero_kernel, dim3(64), dim3(256), 0, stream,
                           (float*)ibase, (long)(2 * N_NODES + 1));  // ibase + icursor
        hipLaunchKernelGGL(hist_kernel, dim3((EF + 255) / 256), dim3(256), 0, stream,
                           ei_dst, ibase);
        hipLaunchKernelGGL(scan_kernel, dim3(1), dim3(1024), 0, stream, ibase);
        hipLaunchKernelGGL(scatter_kernel, dim3((EF + 255) / 256), dim3(256), 0, stream,
                           ei_src, ei_dst, ibase, icursor, src_s, dst_s, inv);
    }
    // 1. time MLP
    hipLaunchKernelGGL(time_mlp_kernel, dim3(N_GRAPHS), dim3(HID), 0, stream,
                       t, tW1, tb1, tW2, tb2, t_emb);
    // 2. concat
    hipLaunchKernelGGL(concat_kernel, dim3((N_NODES * 72 + 255) / 256), dim3(256), 0, stream,
                       x, conds, batch, xc);
    // 3. node encoder gemm + LN/GELU (+t_emb[batch])
    hipLaunchKernelGGL((gemm_kernel<HID, 8>), dim3(N_NODES / 8), dim3(HID), 0, stream,
                       xc, encW, encb, h, N_NODES, 72);
    hipLaunchKernelGGL(ln_gelu_kernel, dim3(N_NODES), dim3(HID), 0, stream,
                       h, encg, encbe, t_emb, batch);
    // 4. edge encode + self-loop segment-mean
    hipLaunchKernelGGL(zero_kernel, dim3(1024), dim3(256), 0, stream,
                       loop_attr, (long)N_NODES * HID);
    hipLaunchKernelGGL(zero_kernel, dim3(64), dim3(256), 0, stream, cnt, (long)N_NODES);
    if (mode == 2) {
        hipLaunchKernelGGL((edge_enc_loop_kernel<8, 2>), dim3(N_EDGES / 8), dim3(HID), 0, stream,
                           edge_attr, eW, eb, eg, ebe, ei_dst, loop_attr, cnt, stat, ea32, ea16);
    } else if (mode == 1) {
        hipLaunchKernelGGL(edge_enc_loop_w_kernel, dim3(N_EDGES / 8), dim3(128), 0, stream,
                           edge_attr, eW, eb, eg, ebe, ei_dst, inv, loop_attr, cnt, ea16);
    } else {
        hipLaunchKernelGGL((edge_enc_loop_kernel<8, 0>), dim3(N_EDGES / 8), dim3(HID), 0, stream,
                           edge_attr, eW, eb, eg, ebe, ei_dst, loop_attr, cnt, stat, ea32, ea16);
    }
    hipLaunchKernelGGL(loop_div_kernel, dim3((N_NODES * HID + 255) / 256), dim3(256), 0, stream,
                       loop_attr, cnt);
    if (mode == 1) {
        hipLaunchKernelGGL(fill_loop_ea_kernel, dim3((N_NODES * HID + 255) / 256), dim3(256), 0,
                           stream, loop_attr, inv, ea16);
    }

    // 5. layers
    for (int l = 0; l < NLAYERS; ++l) {
        const float* cWl_l = cWl + (size_t)l * HID * HID;
        const float* cWr_l = cWr + (size_t)l * HID * HID;
        const float* cWe_l = cWe + (size_t)l * HID * HID;
        const float* cbl_l = cbl + (size_t)l * HID;
        const float* cbr_l = cbr + (size_t)l * HID;
        const float* catt_l = catt + (size_t)l * HID;
        const float* cbias_l = cbias + (size_t)l * HID;

        hipLaunchKernelGGL((gemm2_kernel<8>), dim3(N_NODES / 8), dim3(HID), 0, stream,
                           h, cWl_l, cbl_l, cWr_l, cbr_l, xl, xr, N_NODES);
        if (mode == 1) {
            hipLaunchKernelGGL(att_logit10h_kernel, dim3(EF / 16), dim3(128), 0, stream,
                               ea16, src_s, dst_s, cWe_l, catt_l, xl, xr, logit);
            hipLaunchKernelGGL(csr_smax_agg_kernel, dim3((N_NODES + 1) / 2), dim3(128), 0, stream,
                               ibase, src_s, logit, xl, cbias_l, h);
        } else {
            hipLaunchKernelGGL(init_mx_den_kernel, dim3((N_NODES * HEADS + 255) / 256), dim3(256),
                               0, stream, mx, den);
            if (mode == 2) {
                hipLaunchKernelGGL((att_logit6_kernel<8>), dim3(EF / 8), dim3(HID), 0, stream,
                                   ea32, loop_attr, cWe_l, catt_l, xl, xr, ei_src, ei_dst,
                                   logit, mx);
            } else {
                hipLaunchKernelGGL((att_logit7_kernel<8>), dim3(EF / 8), dim3(HID), 0, stream,
                                   edge_attr, eW, eb, eg, ebe, stat, loop_attr,
                                   cWe_l, catt_l, xl, xr, ei_src, ei_dst, logit, mx);
            }
            hipLaunchKernelGGL(softmax_norm_kernel,
                               dim3((int)(((long)EF * HEADS + 255) / 256)), dim3(256), 0, stream,
                               ei_dst, mx, logit, den);
            hipLaunchKernelGGL(zero_kernel, dim3(1024), dim3(256), 0, stream,
                               aggout, (long)N_NODES * HID);
            hipLaunchKernelGGL(aggregate_kernel,
                               dim3((int)(((long)EF * HID + 255) / 256)), dim3(256), 0, stream,
                               logit, den, xl, ei_src, ei_dst, aggout);
            hipLaunchKernelGGL(residual_kernel, dim3((N_NODES * HID + 255) / 256), dim3(256), 0,
                               stream, aggout, cbias_l, h);
        }
    }

    // 6. noise head
    hipLaunchKernelGGL((gemm_kernel<HID, 8>), dim3(N_NODES / 8), dim3(HID), 0, stream,
                       h, nW1, nb1, tmp1, N_NODES, HID);
    hipLaunchKernelGGL(ln_gelu_kernel, dim3(N_NODES), dim3(HID), 0, stream,
                       tmp1, ng, nbe, (const float*)nullptr, (const int*)nullptr);
    hipLaunchKernelGGL((gemm_kernel<NODE_OUT, 8>), dim3(N_NODES / 8), dim3(NODE_OUT), 0, stream,
                       tmp1, nW2, nb2, pred_noise, N_NODES, HID);

    // 7. pooling + props head
    hipLaunchKernelGGL(zero_kernel, dim3(4), dim3(256), 0, stream,
                       gsum, (long)N_GRAPHS * HID);
    hipLaunchKernelGGL(zero_kernel, dim3(1), dim3(64), 0, stream, gcnt, (long)N_GRAPHS);
    hipLaunchKernelGGL(pool_kernel, dim3((N_NODES + POOL_NODES - 1) / POOL_NODES), dim3(HID), 0,
                       stream, h, batch, gsum, gcnt);
    hipLaunchKernelGGL(props_kernel, dim3(N_GRAPHS), dim3(HID), 0, stream,
                       gsum, gcnt, pW1, pb1, pg, pbe, pW2, pb2, pred_props);
}

// Round 12
// 2416.480 us; speedup vs baseline: 1.3439x; 1.0326x over previous
//
#include <hip/hip_runtime.h>
#include <hip/hip_fp16.h>
#include <math.h>

#define N_NODES 30000
#define N_EDGES 480000
#define N_GRAPHS 16
#define HID 128
#define HEADS 8
#define HEAD_DIM 16
#define NODE_IN 64
#define EDGE_IN 32
#define COND 8
#define NODE_OUT 64
#define NLAYERS 4
#define EF (N_EDGES + N_NODES) /* 510000 */
#define LN_EPS 1e-5f
#define SH_STRIDE 132

__device__ __forceinline__ float gelu_f(float x) {
    return 0.5f * x * (1.0f + erff(x * 0.70710678118654752440f));
}

__device__ __forceinline__ void atomicMaxF(float* addr, float val) {
    if (val >= 0.0f) {
        atomicMax((int*)addr, __float_as_int(val));
    } else {
        atomicMin((unsigned int*)addr, __float_as_uint(val));
    }
}

// ---------- generic zero ----------
__global__ void zero_kernel(float* __restrict__ p, long n) {
    long i = (long)blockIdx.x * blockDim.x + threadIdx.x;
    long stride = (long)gridDim.x * blockDim.x;
    for (; i < n; i += stride) p[i] = 0.0f;
}

// ---------- time MLP ----------
__global__ void time_mlp_kernel(const float* __restrict__ t,
                                const float* __restrict__ tW1, const float* __restrict__ tb1,
                                const float* __restrict__ tW2, const float* __restrict__ tb2,
                                float* __restrict__ t_emb) {
    __shared__ float hsh[HID];
    int b = blockIdx.x, j = threadIdx.x;
    float tv = t[b];
    hsh[j] = gelu_f(tv * tW1[j] + tb1[j]);
    __syncthreads();
    float acc = tb2[j];
    for (int k = 0; k < HID; ++k) acc += hsh[k] * tW2[k * HID + j];
    t_emb[b * HID + j] = acc;
}

// ---------- concat ----------
__global__ void concat_kernel(const float* __restrict__ x, const float* __restrict__ cond,
                              const int* __restrict__ batch, float* __restrict__ xc) {
    int idx = blockIdx.x * blockDim.x + threadIdx.x;
    if (idx >= N_NODES * 72) return;
    int n = idx / 72, c = idx % 72;
    xc[idx] = (c < NODE_IN) ? x[n * NODE_IN + c] : cond[batch[n] * COND + (c - NODE_IN)];
}

// ---------- generic GEMM ----------
template <int NCOL, int R>
__global__ void gemm_kernel(const float* __restrict__ A, const float* __restrict__ B,
                            const float* __restrict__ bias, float* __restrict__ C,
                            int M, int K) {
    __shared__ __align__(16) float sh[R * HID];
    int j = threadIdx.x;
    int row0 = blockIdx.x * R;
    int total = R * K;
    for (int i = j; i < total; i += NCOL) {
        int r = i / K, k = i - r * K;
        int row = row0 + r;
        sh[r * K + k] = (row < M) ? A[(long)row * K + k] : 0.0f;
    }
    __syncthreads();
    float acc[R];
    float bv = bias ? bias[j] : 0.0f;
#pragma unroll
    for (int r = 0; r < R; ++r) acc[r] = bv;
    int KB = K >> 2;
    for (int kb = 0; kb < KB; ++kb) {
        float w0 = B[(kb * 4 + 0) * NCOL + j];
        float w1 = B[(kb * 4 + 1) * NCOL + j];
        float w2 = B[(kb * 4 + 2) * NCOL + j];
        float w3 = B[(kb * 4 + 3) * NCOL + j];
#pragma unroll
        for (int r = 0; r < R; ++r) {
            float4 a = *(const float4*)&sh[r * K + kb * 4];
            acc[r] += a.x * w0 + a.y * w1 + a.z * w2 + a.w * w3;
        }
    }
#pragma unroll
    for (int r = 0; r < R; ++r) {
        int row = row0 + r;
        if (row < M) C[(long)row * NCOL + j] = acc[r];
    }
}

// ---------- fused dual GEMM ----------
template <int R>
__global__ void gemm2_kernel(const float* __restrict__ A,
                             const float* __restrict__ Bl, const float* __restrict__ bl,
                             const float* __restrict__ Br, const float* __restrict__ br,
                             float* __restrict__ Cl, float* __restrict__ Cr, int M) {
    __shared__ __align__(16) float sh[R * HID];
    int j = threadIdx.x;
    int row0 = blockIdx.x * R;
    for (int i = j; i < R * HID; i += HID) {
        int r = i >> 7, k = i & 127;
        int row = row0 + r;
        sh[i] = (row < M) ? A[(long)row * HID + k] : 0.0f;
    }
    __syncthreads();
    float accl[R], accr[R];
    float blv = bl[j], brv = br[j];
#pragma unroll
    for (int r = 0; r < R; ++r) { accl[r] = blv; accr[r] = brv; }
    for (int kb = 0; kb < HID / 4; ++kb) {
        float l0 = Bl[(kb * 4 + 0) * HID + j];
        float l1 = Bl[(kb * 4 + 1) * HID + j];
        float l2 = Bl[(kb * 4 + 2) * HID + j];
        float l3 = Bl[(kb * 4 + 3) * HID + j];
        float r0 = Br[(kb * 4 + 0) * HID + j];
        float r1 = Br[(kb * 4 + 1) * HID + j];
        float r2 = Br[(kb * 4 + 2) * HID + j];
        float r3 = Br[(kb * 4 + 3) * HID + j];
#pragma unroll
        for (int r = 0; r < R; ++r) {
            float4 a = *(const float4*)&sh[r * HID + kb * 4];
            accl[r] += a.x * l0 + a.y * l1 + a.z * l2 + a.w * l3;
            accr[r] += a.x * r0 + a.y * r1 + a.z * r2 + a.w * r3;
        }
    }
#pragma unroll
    for (int r = 0; r < R; ++r) {
        int row = row0 + r;
        if (row < M) {
            Cl[(long)row * HID + j] = accl[r];
            Cr[(long)row * HID + j] = accr[r];
        }
    }
}

// ---------- in-place LayerNorm + GELU ----------
__global__ void ln_gelu_kernel(float* __restrict__ X, const float* __restrict__ g,
                               const float* __restrict__ bta,
                               const float* __restrict__ t_emb, const int* __restrict__ batch) {
    int row = blockIdx.x, j = threadIdx.x;
    __shared__ float red[HID];
    float v = X[(long)row * HID + j];
    red[j] = v;
    __syncthreads();
    for (int s = 64; s > 0; s >>= 1) { if (j < s) red[j] += red[j + s]; __syncthreads(); }
    float mean = red[0] * (1.0f / HID);
    __syncthreads();
    float d = v - mean;
    red[j] = d * d;
    __syncthreads();
    for (int s = 64; s > 0; s >>= 1) { if (j < s) red[j] += red[j + s]; __syncthreads(); }
    float var = red[0] * (1.0f / HID);
    float y = gelu_f(d * rsqrtf(var + LN_EPS) * g[j] + bta[j]);
    if (t_emb) y += t_emb[batch[row] * HID + j];
    X[(long)row * HID + j] = y;
}

// ================= CSR sort setup (mode 1) =================
__global__ void hist_kernel(const int* __restrict__ ei_dst, int* __restrict__ ibase) {
    int idx = blockIdx.x * blockDim.x + threadIdx.x;
    if (idx >= EF) return;
    int d = (idx < N_EDGES) ? ei_dst[idx] : (idx - N_EDGES);
    atomicAdd(&ibase[d + 1], 1);
}

__global__ __launch_bounds__(1024) void scan_kernel(int* __restrict__ ibase) {
    __shared__ int wsums[16];
    __shared__ int s_carry;
    int t = threadIdx.x, lane = t & 63, w = t >> 6;
    if (t == 0) s_carry = 0;
    __syncthreads();
    for (int start = 0; start < N_NODES; start += 1024) {
        int i = start + t;
        int v = (i < N_NODES) ? ibase[i + 1] : 0;
        int x = v;
#pragma unroll
        for (int m = 1; m < 64; m <<= 1) {
            int y = __shfl_up(x, m);
            if (lane >= m) x += y;
        }
        if (lane == 63) wsums[w] = x;
        __syncthreads();
        if (w == 0 && lane < 16) {
            int ws = wsums[lane];
#pragma unroll
            for (int m = 1; m < 16; m <<= 1) {
                int y = __shfl_up(ws, m);
                if (lane >= m) ws += y;
            }
            wsums[lane] = ws;
        }
        __syncthreads();
        int waveoff = (w == 0) ? 0 : wsums[w - 1];
        int incl = x + waveoff + s_carry;
        if (i < N_NODES) ibase[i + 1] = incl;
        __syncthreads();
        if (t == 1023) s_carry = incl;
        __syncthreads();
    }
}

__global__ void scatter_kernel(const int* __restrict__ ei_src, const int* __restrict__ ei_dst,
                               const int* __restrict__ ibase, int* __restrict__ icursor,
                               int* __restrict__ src_s, int* __restrict__ dst_s,
                               int* __restrict__ inv) {
    int idx = blockIdx.x * blockDim.x + threadIdx.x;
    if (idx >= EF) return;
    int s, d;
    if (idx < N_EDGES) { s = ei_src[idx]; d = ei_dst[idx]; }
    else               { s = d = idx - N_EDGES; }
    int pos = ibase[d] + atomicAdd(&icursor[d], 1);
    src_s[pos] = s;
    dst_s[pos] = d;
    inv[idx] = pos;
}

// ---------- CSR loop-mean: self-loop ea row = mean of real-edge rows in segment ----------
// One wave per dst (2/block). Reads sorted ea16 segment, skips the self-loop slot,
// writes the fp16 mean into that slot. Replaces loop_sum atomics + loop_div + fill.
__global__ __launch_bounds__(128) void csr_loop_mean_kernel(
        const int* __restrict__ ibase, const int* __restrict__ inv,
        __half* __restrict__ ea16) {
    int w = threadIdx.x >> 6, lane = threadIdx.x & 63;
    int d = blockIdx.x * 2 + w;
    if (d >= N_NODES) return;
    int b0 = ibase[d], b1 = ibase[d + 1];
    int selfpos = inv[N_EDGES + d];
    float a0 = 0.0f, a1 = 0.0f;
    for (int i = b0; i < b1; ++i) {
        if (i == selfpos) continue;
        a0 += __half2float(ea16[(long)i * HID + lane]);
        a1 += __half2float(ea16[(long)i * HID + lane + 64]);
    }
    float c = fmaxf((float)(b1 - b0 - 1), 1.0f);
    ea16[(long)selfpos * HID + lane]      = __float2half(a0 / c);
    ea16[(long)selfpos * HID + lane + 64] = __float2half(a1 / c);
}

// ---------- fallback (modes 0/2): edge-encode + segment-sum, LDS-tree LN ----------
template <int R, int MODE>
__global__ void edge_enc_loop_kernel(const float* __restrict__ edge_attr,
                                     const float* __restrict__ eW, const float* __restrict__ eb,
                                     const float* __restrict__ eg, const float* __restrict__ ebe,
                                     const int* __restrict__ ei_dst,
                                     float* __restrict__ loop_sum, float* __restrict__ cnt,
                                     float* __restrict__ stat,
                                     float* __restrict__ ea32, __half* __restrict__ ea16) {
    __shared__ float red[R * HID];
    __shared__ __align__(16) float sattr[R * EDGE_IN];
    __shared__ int sdst[R];
    int j = threadIdx.x;
    long e0 = (long)blockIdx.x * R;
    if (j < R * EDGE_IN / 4)
        ((float4*)sattr)[j] = ((const float4*)(edge_attr + e0 * EDGE_IN))[j];
    if (j < R) sdst[j] = ei_dst[e0 + j];
    __syncthreads();
    float val[R];
    float ebv = eb[j];
#pragma unroll
    for (int r = 0; r < R; ++r) val[r] = ebv;
#pragma unroll
    for (int kb = 0; kb < EDGE_IN / 4; ++kb) {
        float w0 = eW[(kb * 4 + 0) * HID + j];
        float w1 = eW[(kb * 4 + 1) * HID + j];
        float w2 = eW[(kb * 4 + 2) * HID + j];
        float w3 = eW[(kb * 4 + 3) * HID + j];
#pragma unroll
        for (int r = 0; r < R; ++r) {
            float4 a = *(const float4*)&sattr[r * EDGE_IN + kb * 4];
            val[r] += a.x * w0 + a.y * w1 + a.z * w2 + a.w * w3;
        }
    }
#pragma unroll
    for (int r = 0; r < R; ++r) red[r * HID + j] = val[r];
    __syncthreads();
    for (int s = 64; s > 0; s >>= 1) {
        if (j < s) {
#pragma unroll
            for (int r = 0; r < R; ++r) red[r * HID + j] += red[r * HID + j + s];
        }
        __syncthreads();
    }
    float mean[R];
#pragma unroll
    for (int r = 0; r < R; ++r) mean[r] = red[r * HID] * (1.0f / HID);
    __syncthreads();
#pragma unroll
    for (int r = 0; r < R; ++r) { float d = val[r] - mean[r]; red[r * HID + j] = d * d; }
    __syncthreads();
    for (int s = 64; s > 0; s >>= 1) {
        if (j < s) {
#pragma unroll
            for (int r = 0; r < R; ++r) red[r * HID + j] += red[r * HID + j + s];
        }
        __syncthreads();
    }
    float egv = eg[j], bev = ebe[j];
#pragma unroll
    for (int r = 0; r < R; ++r) {
        float var = red[r * HID] * (1.0f / HID);
        float rstd = rsqrtf(var + LN_EPS);
        float y = gelu_f((val[r] - mean[r]) * rstd * egv + bev);
        int d = sdst[r];
        long e = e0 + r;
        if (j == 0) { stat[e * 2] = mean[r]; stat[e * 2 + 1] = rstd; }
        if (MODE == 2) ea32[e * HID + j] = y;
        if (MODE == 1) ea16[e * HID + j] = __float2half(y);
        atomicAdd(&loop_sum[(long)d * HID + j], y);
        if (j == 0) atomicAdd(&cnt[d], 1.0f);
    }
}

// ---------- mode-1 MAIN enc: wave-owns-rows, shfl LN, fp16 ea to sorted pos, NO atomics ----------
__global__ __launch_bounds__(128) void edge_enc_loop_w_kernel(
        const float* __restrict__ edge_attr,
        const float* __restrict__ eW, const float* __restrict__ eb,
        const float* __restrict__ eg, const float* __restrict__ ebe,
        const int* __restrict__ inv,
        __half* __restrict__ ea16) {
    const int R = 8;
    __shared__ __align__(16) float sattr[R * EDGE_IN];
    __shared__ int spos[R];
    int t = threadIdx.x;
    long e0 = (long)blockIdx.x * R;
    if (t < R * EDGE_IN / 4)
        ((float4*)sattr)[t] = ((const float4*)(edge_attr + e0 * EDGE_IN))[t];
    if (t < R) spos[t] = inv[e0 + t];
    __syncthreads();
    int lane = t & 63, w = t >> 6;
    int r0 = w * 4;
    int j1 = lane, j2 = lane + 64;
    float eb1 = eb[j1], eb2 = eb[j2];
    float v0[4], v1[4];
#pragma unroll
    for (int q = 0; q < 4; ++q) { v0[q] = eb1; v1[q] = eb2; }
#pragma unroll
    for (int kb = 0; kb < EDGE_IN / 4; ++kb) {
        float w10 = eW[(kb * 4 + 0) * HID + j1];
        float w11 = eW[(kb * 4 + 1) * HID + j1];
        float w12 = eW[(kb * 4 + 2) * HID + j1];
        float w13 = eW[(kb * 4 + 3) * HID + j1];
        float w20 = eW[(kb * 4 + 0) * HID + j2];
        float w21 = eW[(kb * 4 + 1) * HID + j2];
        float w22 = eW[(kb * 4 + 2) * HID + j2];
        float w23 = eW[(kb * 4 + 3) * HID + j2];
#pragma unroll
        for (int q = 0; q < 4; ++q) {
            float4 a = *(const float4*)&sattr[(r0 + q) * EDGE_IN + kb * 4];
            v0[q] += a.x * w10 + a.y * w11 + a.z * w12 + a.w * w13;
            v1[q] += a.x * w20 + a.y * w21 + a.z * w22 + a.w * w23;
        }
    }
    float eg1 = eg[j1], eg2 = eg[j2];
    float be1 = ebe[j1], be2 = ebe[j2];
#pragma unroll
    for (int q = 0; q < 4; ++q) {
        float s1 = v0[q] + v1[q];
        float s2 = v0[q] * v0[q] + v1[q] * v1[q];
#pragma unroll
        for (int m = 1; m < 64; m <<= 1) {
            s1 += __shfl_xor(s1, m);
            s2 += __shfl_xor(s2, m);
        }
        float mean = s1 * (1.0f / 128.0f);
        float var = s2 * (1.0f / 128.0f) - mean * mean;
        float rstd = rsqrtf(var + LN_EPS);
        float y0 = gelu_f((v0[q] - mean) * rstd * eg1 + be1);
        float y1 = gelu_f((v1[q] - mean) * rstd * eg2 + be2);
        long pos = spos[r0 + q];
        ea16[pos * HID + j1] = __float2half(y0);
        ea16[pos * HID + j2] = __float2half(y1);
    }
}

__global__ void loop_div_kernel(float* __restrict__ loop_attr, const float* __restrict__ cnt) {
    int idx = blockIdx.x * blockDim.x + threadIdx.x;
    if (idx >= N_NODES * HID) return;
    int n = idx >> 7;
    loop_attr[idx] = loop_attr[idx] / fmaxf(cnt[n], 1.0f);
}

// ---------- init mx=-inf, den=0 (modes 0/2) ----------
__global__ void init_mx_den_kernel(float* __restrict__ mx, float* __restrict__ den) {
    int idx = blockIdx.x * blockDim.x + threadIdx.x;
    if (idx >= N_NODES * HEADS) return;
    mx[idx] = -INFINITY;
    den[idx] = 0.0f;
}

// ---------- shared epilogue (fallback variants) ----------
template <int R>
__device__ __forceinline__ void em_logit_body(
        const float* __restrict__ sh, const int* __restrict__ ssrc, const int* __restrict__ sdst,
        const float* __restrict__ cWe_l, const float* __restrict__ catt_l,
        const float* __restrict__ xl, const float* __restrict__ xr,
        float* __restrict__ logit, float* __restrict__ mx, long e0, int j) {
    float acc[R];
#pragma unroll
    for (int r = 0; r < R; ++r) acc[r] = 0.0f;
    for (int kb = 0; kb < HID / 4; ++kb) {
        float w0 = cWe_l[(kb * 4 + 0) * HID + j];
        float w1 = cWe_l[(kb * 4 + 1) * HID + j];
        float w2 = cWe_l[(kb * 4 + 2) * HID + j];
        float w3 = cWe_l[(kb * 4 + 3) * HID + j];
#pragma unroll
        for (int r = 0; r < R; ++r) {
            float4 a = *(const float4*)&sh[r * HID + kb * 4];
            acc[r] += a.x * w0 + a.y * w1 + a.z * w2 + a.w * w3;
        }
    }
    float cj = catt_l[j];
    int head = j >> 4;
#pragma unroll
    for (int r = 0; r < R; ++r) {
        long e = e0 + r;
        int s = ssrc[r], d = sdst[r];
        float m = xl[(long)s * HID + j] + xr[(long)d * HID + j] + acc[r];
        m = (m > 0.0f) ? m : 0.2f * m;
        float p = m * cj;
        p += __shfl_down(p, 8, 16);
        p += __shfl_down(p, 4, 16);
        p += __shfl_down(p, 2, 16);
        p += __shfl_down(p, 1, 16);
        if ((j & 15) == 0) {
            logit[e * HEADS + head] = p;
            atomicMaxF(&mx[(long)d * HEADS + head], p);
        }
    }
}

// ---------- att kernel, mode 0 fallback ----------
template <int R>
__global__ void att_logit7_kernel(const float* __restrict__ edge_attr,
                                  const float* __restrict__ eW, const float* __restrict__ eb,
                                  const float* __restrict__ eg, const float* __restrict__ ebe,
                                  const float* __restrict__ stat,
                                  const float* __restrict__ loop_attr,
                                  const float* __restrict__ cWe_l, const float* __restrict__ catt_l,
                                  const float* __restrict__ xl, const float* __restrict__ xr,
                                  const int* __restrict__ ei_src, const int* __restrict__ ei_dst,
                                  float* __restrict__ logit, float* __restrict__ mx) {
    __shared__ __align__(16) float sh[R * HID];
    __shared__ __align__(16) float sattr[R * EDGE_IN];
    __shared__ float sstat[R * 2];
    __shared__ int ssrc[R], sdst[R];
    int j = threadIdx.x;
    long e0 = (long)blockIdx.x * R;
    bool realblk = (e0 < N_EDGES);

    if (realblk) {
        if (j < R * EDGE_IN / 4)
            ((float4*)sattr)[j] = ((const float4*)(edge_attr + e0 * EDGE_IN))[j];
        if (j < R * 2) sstat[j] = stat[e0 * 2 + j];
        if (j < R) { ssrc[j] = ei_src[e0 + j]; sdst[j] = ei_dst[e0 + j]; }
    } else {
        if (j < R) ssrc[j] = sdst[j] = (int)(e0 + j - N_EDGES);
    }
    __syncthreads();

    if (realblk) {
        float val[R];
        float ebv = eb[j];
#pragma unroll
        for (int r = 0; r < R; ++r) val[r] = ebv;
#pragma unroll
        for (int kb = 0; kb < EDGE_IN / 4; ++kb) {
            float w0 = eW[(kb * 4 + 0) * HID + j];
            float w1 = eW[(kb * 4 + 1) * HID + j];
            float w2 = eW[(kb * 4 + 2) * HID + j];
            float w3 = eW[(kb * 4 + 3) * HID + j];
#pragma unroll
            for (int r = 0; r < R; ++r) {
                float4 a = *(const float4*)&sattr[r * EDGE_IN + kb * 4];
                val[r] += a.x * w0 + a.y * w1 + a.z * w2 + a.w * w3;
            }
        }
        float egv = eg[j], bev = ebe[j];
#pragma unroll
        for (int r = 0; r < R; ++r) {
            float mean = sstat[r * 2], rstd = sstat[r * 2 + 1];
            sh[r * HID + j] = gelu_f((val[r] - mean) * rstd * egv + bev);
        }
    } else {
#pragma unroll
        for (int r = 0; r < R; ++r)
            sh[r * HID + j] = loop_attr[(long)(e0 + r - N_EDGES) * HID + j];
    }
    __syncthreads();
    em_logit_body<R>(sh, ssrc, sdst, cWe_l, catt_l, xl, xr, logit, mx, e0, j);
}

// ---------- att kernel, mode 2 fallback ----------
template <int R>
__global__ void att_logit6_kernel(const float* __restrict__ ea,
                                  const float* __restrict__ loop_attr,
                                  const float* __restrict__ cWe_l, const float* __restrict__ catt_l,
                                  const float* __restrict__ xl, const float* __restrict__ xr,
                                  const int* __restrict__ ei_src, const int* __restrict__ ei_dst,
                                  float* __restrict__ logit, float* __restrict__ mx) {
    __shared__ __align__(16) float sh[R * HID];
    __shared__ int ssrc[R], sdst[R];
    int j = threadIdx.x;
    long e0 = (long)blockIdx.x * R;
    bool realblk = (e0 < N_EDGES);
    const float* srcp = realblk ? (ea + e0 * HID) : (loop_attr + (e0 - N_EDGES) * HID);
    const float4* s4 = (const float4*)srcp;
    ((float4*)sh)[j]       = s4[j];
    ((float4*)sh)[j + HID] = s4[j + HID];
    if (j < R) {
        long e = e0 + j;
        if (realblk) { ssrc[j] = ei_src[e]; sdst[j] = ei_dst[e]; }
        else         { ssrc[j] = sdst[j] = (int)(e - N_EDGES); }
    }
    __syncthreads();
    em_logit_body<R>(sh, ssrc, sdst, cWe_l, catt_l, xl, xr, logit, mx, e0, j);
}

// ---------- att kernel, mode 1 MAIN: sorted fp16 ea stream, no atomics, no branches ----------
__global__ __launch_bounds__(128) void att_logit10h_kernel(
        const __half* __restrict__ ea,          /* sorted [EF,128] */
        const int* __restrict__ src_s, const int* __restrict__ dst_s,
        const float* __restrict__ cWe_l, const float* __restrict__ catt_l,
        const float* __restrict__ xl, const float* __restrict__ xr,
        float* __restrict__ logit) {
    const int R = 16;
    __shared__ __align__(16) float sh[R * SH_STRIDE];
    __shared__ int ssrc[R], sdst[R];
    int t = threadIdx.x;
    long e0 = (long)blockIdx.x * R;

    const uint4* s16 = (const uint4*)(ea + e0 * HID);
#pragma unroll
    for (int i = 0; i < 2; ++i) {
        uint4 u = s16[t + i * 128];
        int o = (t + i * 128) * 8;
        int row = o >> 7, col = o & 127;
        float* dst = &sh[row * SH_STRIDE + col];
        const __half2* hp = (const __half2*)&u;
        float2 f0 = __half22float2(hp[0]);
        float2 f1 = __half22float2(hp[1]);
        float2 f2 = __half22float2(hp[2]);
        float2 f3 = __half22float2(hp[3]);
        *(float4*)dst       = make_float4(f0.x, f0.y, f1.x, f1.y);
        *(float4*)(dst + 4) = make_float4(f2.x, f2.y, f3.x, f3.y);
    }
    if (t < R) ssrc[t] = src_s[e0 + t];
    else if (t < 2 * R) sdst[t - R] = dst_s[e0 + (t - R)];
    __syncthreads();

    int cg = t & 31, rg = t >> 5;
    int c0 = cg * 4;
    float acc[4][4];
#pragma unroll
    for (int i = 0; i < 4; ++i)
#pragma unroll
        for (int c = 0; c < 4; ++c) acc[i][c] = 0.0f;
    for (int kb = 0; kb < HID / 4; ++kb) {
        float4 w0 = *(const float4*)&cWe_l[(kb * 4 + 0) * HID + c0];
        float4 w1 = *(const float4*)&cWe_l[(kb * 4 + 1) * HID + c0];
        float4 w2 = *(const float4*)&cWe_l[(kb * 4 + 2) * HID + c0];
        float4 w3 = *(const float4*)&cWe_l[(kb * 4 + 3) * HID + c0];
#pragma unroll
        for (int i = 0; i < 4; ++i) {
            float4 a = *(const float4*)&sh[(rg * 4 + i) * SH_STRIDE + kb * 4];
            acc[i][0] += a.x * w0.x + a.y * w1.x + a.z * w2.x + a.w * w3.x;
            acc[i][1] += a.x * w0.y + a.y * w1.y + a.z * w2.y + a.w * w3.y;
            acc[i][2] += a.x * w0.z + a.y * w1.z + a.z * w2.z + a.w * w3.z;
            acc[i][3] += a.x * w0.w + a.y * w1.w + a.z * w2.w + a.w * w3.w;
        }
    }

    float4 cat4 = *(const float4*)&catt_l[c0];
    int head = cg >> 2;
#pragma unroll
    for (int i = 0; i < 4; ++i) {
        int r = rg * 4 + i;
        long e = e0 + r;
        int s = ssrc[r], d = sdst[r];
        float4 xlv = *(const float4*)&xl[(long)s * HID + c0];
        float4 xrv = *(const float4*)&xr[(long)d * HID + c0];
        float m0 = xlv.x + xrv.x + acc[i][0]; m0 = (m0 > 0.0f) ? m0 : 0.2f * m0;
        float m1 = xlv.y + xrv.y + acc[i][1]; m1 = (m1 > 0.0f) ? m1 : 0.2f * m1;
        float m2 = xlv.z + xrv.z + acc[i][2]; m2 = (m2 > 0.0f) ? m2 : 0.2f * m2;
        float m3 = xlv.w + xrv.w + acc[i][3]; m3 = (m3 > 0.0f) ? m3 : 0.2f * m3;
        float p = m0 * cat4.x + m1 * cat4.y + m2 * cat4.z + m3 * cat4.w;
        p += __shfl_xor(p, 1);
        p += __shfl_xor(p, 2);
        if ((cg & 3) == 0) logit[e * HEADS + head] = p;
    }
}

// ---------- CSR fused softmax + aggregate + residual (mode 1) ----------
__global__ __launch_bounds__(128) void csr_smax_agg_kernel(
        const int* __restrict__ ibase, const int* __restrict__ src_s,
        const float* __restrict__ logit, const float* __restrict__ xl,
        const float* __restrict__ cbias_l, float* __restrict__ h) {
    int w = threadIdx.x >> 6, lane = threadIdx.x & 63;
    int d = blockIdx.x * 2 + w;
    if (d >= N_NODES) return;
    int b0 = ibase[d], b1 = ibase[d + 1];
    int hh = lane & 7, g = lane >> 3;
    float m = -INFINITY;
    for (int i = b0 + g; i < b1; i += 8) m = fmaxf(m, logit[(long)i * 8 + hh]);
    m = fmaxf(m, __shfl_xor(m, 8));
    m = fmaxf(m, __shfl_xor(m, 16));
    m = fmaxf(m, __shfl_xor(m, 32));
    float den = 0.0f;
    for (int i = b0 + g; i < b1; i += 8) den += expf(logit[(long)i * 8 + hh] - m);
    den += __shfl_xor(den, 8);
    den += __shfl_xor(den, 16);
    den += __shfl_xor(den, 32);
    int h1 = lane >> 4, h2 = 4 + (lane >> 4);
    float mx1 = __shfl(m, h1), mx2 = __shfl(m, h2);
    float dn1 = __shfl(den, h1) + 1e-16f, dn2 = __shfl(den, h2) + 1e-16f;
    float acc0 = 0.0f, acc1 = 0.0f;
    for (int i = b0; i < b1; ++i) {
        int s = src_s[i];
        float a0 = expf(logit[(long)i * 8 + h1] - mx1) / dn1;
        float a1 = expf(logit[(long)i * 8 + h2] - mx2) / dn2;
        acc0 += a0 * xl[(long)s * HID + lane];
        acc1 += a1 * xl[(long)s * HID + lane + 64];
    }
    long o = (long)d * HID + lane;
    h[o]      = gelu_f(acc0 + cbias_l[lane])      + h[o];
    h[o + 64] = gelu_f(acc1 + cbias_l[lane + 64]) + h[o + 64];
}

// ---------- fallback chain kernels (modes 0/2) ----------
__global__ void softmax_norm_kernel(const int* __restrict__ ei_dst, const float* __restrict__ mx,
                                    float* __restrict__ logit, float* __restrict__ den) {
    long idx = (long)blockIdx.x * blockDim.x + threadIdx.x;
    if (idx >= (long)EF * HEADS) return;
    long e = idx >> 3;
    int hh = (int)(idx & 7);
    int d = (e < N_EDGES) ? ei_dst[e] : (int)(e - N_EDGES);
    float ex = expf(logit[idx] - mx[(long)d * HEADS + hh]);
    logit[idx] = ex;
    atomicAdd(&den[(long)d * HEADS + hh], ex);
}

__global__ void aggregate_kernel(const float* __restrict__ logit, const float* __restrict__ den,
                                 const float* __restrict__ xl,
                                 const int* __restrict__ ei_src, const int* __restrict__ ei_dst,
                                 float* __restrict__ aggout) {
    long idx = (long)blockIdx.x * blockDim.x + threadIdx.x;
    if (idx >= (long)EF * HID) return;
    long e = idx >> 7;
    int j = (int)(idx & 127);
    int s, d;
    if (e < N_EDGES) { s = ei_src[e]; d = ei_dst[e]; }
    else             { s = d = (int)(e - N_EDGES); }
    int head = j >> 4;
    float alpha = logit[e * HEADS + head] / (den[(long)d * HEADS + head] + 1e-16f);
    atomicAdd(&aggout[(long)d * HID + j], alpha * xl[(long)s * HID + j]);
}

__global__ void residual_kernel(const float* __restrict__ aggout, const float* __restrict__ cbias_l,
                                float* __restrict__ h) {
    int idx = blockIdx.x * blockDim.x + threadIdx.x;
    if (idx >= N_NODES * HID) return;
    int j = idx & 127;
    h[idx] = gelu_f(aggout[idx] + cbias_l[j]) + h[idx];
}

// ---------- pooling ----------
#define POOL_NODES 64
__global__ void pool_kernel(const float* __restrict__ h, const int* __restrict__ batch,
                            float* __restrict__ gsum, float* __restrict__ gcnt) {
    __shared__ float acc[N_GRAPHS][HID];
    __shared__ float cnt_sh[N_GRAPHS];
    int j = threadIdx.x;
    for (int g = 0; g < N_GRAPHS; ++g) acc[g][j] = 0.0f;
    if (j < N_GRAPHS) cnt_sh[j] = 0.0f;
    __syncthreads();
    int n0 = blockIdx.x * POOL_NODES;
    for (int i = 0; i < POOL_NODES; ++i) {
        int n = n0 + i;
        if (n >= N_NODES) break;
        int g = batch[n];
        acc[g][j] += h[(long)n * HID + j];
        if (j == 0) cnt_sh[g] += 1.0f;
    }
    __syncthreads();
    for (int g = 0; g < N_GRAPHS; ++g) atomicAdd(&gsum[g * HID + j], acc[g][j]);
    if (j < N_GRAPHS) atomicAdd(&gcnt[j], cnt_sh[j]);
}

// ---------- props head ----------
__global__ void props_kernel(const float* __restrict__ gsum, const float* __restrict__ gcnt,
                             const float* __restrict__ pW1, const float* __restrict__ pb1,
                             const float* __restrict__ pg, const float* __restrict__ pbe,
                             const float* __restrict__ pW2, const float* __restrict__ pb2,
                             float* __restrict__ out_props) {
    int g = blockIdx.x, j = threadIdx.x;
    __shared__ float feat[HID], red[HID], t2[HID];
    float c = fmaxf(gcnt[g], 1.0f);
    feat[j] = gsum[g * HID + j] / c;
    __syncthreads();
    float acc = pb1[j];
    for (int k = 0; k < HID; ++k) acc += feat[k] * pW1[k * HID + j];
    red[j] = acc;
    __syncthreads();
    for (int s = 64; s > 0; s >>= 1) { if (j < s) red[j] += red[j + s]; __syncthreads(); }
    float mean = red[0] * (1.0f / HID);
    __syncthreads();
    float dd = acc - mean;
    red[j] = dd * dd;
    __syncthreads();
    for (int s = 64; s > 0; s >>= 1) { if (j < s) red[j] += red[j + s]; __syncthreads(); }
    float var = red[0] * (1.0f / HID);
    t2[j] = gelu_f(dd * rsqrtf(var + LN_EPS) * pg[j] + pbe[j]);
    __syncthreads();
    if (j < COND) {
        float a = pb2[j];
        for (int k = 0; k < HID; ++k) a += t2[k] * pW2[k * COND + j];
        out_props[g * COND + j] = a;
    }
}

extern "C" void kernel_launch(void* const* d_in, const int* in_sizes, int n_in,
                              void* d_out, int out_size, void* d_ws, size_t ws_size,
                              hipStream_t stream) {
    const float* x        = (const float*)d_in[0];
    const float* edge_attr= (const float*)d_in[1];
    const float* t        = (const float*)d_in[2];
    const float* conds    = (const float*)d_in[3];
    const float* tW1      = (const float*)d_in[4];
    const float* tb1      = (const float*)d_in[5];
    const float* tW2      = (const float*)d_in[6];
    const float* tb2      = (const float*)d_in[7];
    const float* encW     = (const float*)d_in[8];
    const float* encb     = (const float*)d_in[9];
    const float* encg     = (const float*)d_in[10];
    const float* encbe    = (const float*)d_in[11];
    const float* eW       = (const float*)d_in[12];
    const float* eb       = (const float*)d_in[13];
    const float* eg       = (const float*)d_in[14];
    const float* ebe      = (const float*)d_in[15];
    const float* cWl      = (const float*)d_in[16];
    const float* cbl      = (const float*)d_in[17];
    const float* cWr      = (const float*)d_in[18];
    const float* cbr      = (const float*)d_in[19];
    const float* cWe      = (const float*)d_in[20];
    const float* catt     = (const float*)d_in[21];
    const float* cbias    = (const float*)d_in[22];
    const float* nW1      = (const float*)d_in[23];
    const float* nb1      = (const float*)d_in[24];
    const float* ng       = (const float*)d_in[25];
    const float* nbe      = (const float*)d_in[26];
    const float* nW2      = (const float*)d_in[27];
    const float* nb2      = (const float*)d_in[28];
    const float* pW1      = (const float*)d_in[29];
    const float* pb1      = (const float*)d_in[30];
    const float* pg       = (const float*)d_in[31];
    const float* pbe      = (const float*)d_in[32];
    const float* pW2      = (const float*)d_in[33];
    const float* pb2      = (const float*)d_in[34];
    const int* edge_index = (const int*)d_in[35];
    const int* batch      = (const int*)d_in[36];
    const int* ei_src = edge_index;
    const int* ei_dst = edge_index + N_EDGES;

    // workspace: common + union(mode1 sort ints | mode0/2 stat+mx+den+aggout) + ea
    float* ws = (float*)d_ws;
    size_t off = 0;
    auto alloc = [&](size_t n) { float* p = ws + off; off += n; return p; };
    float* t_emb     = alloc((size_t)N_GRAPHS * HID);
    float* h         = alloc((size_t)N_NODES * HID);
    float* loop_attr = alloc((size_t)N_NODES * HID);
    float* cnt       = alloc((size_t)N_NODES);
    float* xl        = alloc((size_t)N_NODES * HID);
    float* xr        = alloc((size_t)N_NODES * HID);
    float* logit     = alloc((size_t)EF * HEADS);      // 4.08M floats
    float* gsum      = alloc((size_t)N_GRAPHS * HID);
    float* gcnt      = alloc((size_t)N_GRAPHS);
    // union region (5.28M float slots):
    float* uni = alloc((size_t)(960000 + 240000 + 240000 + (size_t)N_NODES * HID));
    // mode-0/2 view:
    float* stat   = uni;                  // [N_EDGES*2]
    float* mx     = uni + 960000;         // [N*8]
    float* den    = uni + 960000 + 240000;
    float* aggout = uni + 960000 + 480000; // [N*128]
    // mode-1 view (ints):
    int* ibase   = (int*)uni;                         // [N_NODES+1]
    int* icursor = ibase + (N_NODES + 1);             // [N_NODES]
    int* src_s   = icursor + N_NODES;                 // [EF]
    int* dst_s   = src_s + EF;                        // [EF]
    int* inv     = dst_s + EF;                        // [EF]
    size_t base_bytes = off * sizeof(float);
    float*  ea32 = ws + off;
    __half* ea16 = (__half*)(ws + off);
    int mode = 0;
    if (ws_size >= base_bytes + (size_t)EF * HID * sizeof(float)) mode = 2;
    else if (ws_size >= base_bytes + (size_t)EF * HID * sizeof(__half)) mode = 1;
    // aliases (disjoint lifetimes):
    float* xc   = logit;  // [N,72] used only pre-layers
    float* tmp1 = xl;     // used only post-layers
    (void)in_sizes; (void)n_in; (void)out_size;

    float* pred_noise = (float*)d_out;                              // [N,64]
    float* pred_props = (float*)d_out + (size_t)N_NODES * NODE_OUT; // [16,8]

    // 0. (mode 1) CSR sort of edges by dst, self-loops included
    if (mode == 1) {
        hipLaunchKernelGGL(zero_kernel, dim3(64), dim3(256), 0, stream,
                           (float*)ibase, (long)(2 * N_NODES + 1));  // ibase + icursor
        hipLaunchKernelGGL(hist_kernel, dim3((EF + 255) / 256), dim3(256), 0, stream,
                           ei_dst, ibase);
        hipLaunchKernelGGL(scan_kernel, dim3(1), dim3(1024), 0, stream, ibase);
        hipLaunchKernelGGL(scatter_kernel, dim3((EF + 255) / 256), dim3(256), 0, stream,
                           ei_src, ei_dst, ibase, icursor, src_s, dst_s, inv);
    }
    // 1. time MLP
    hipLaunchKernelGGL(time_mlp_kernel, dim3(N_GRAPHS), dim3(HID), 0, stream,
                       t, tW1, tb1, tW2, tb2, t_emb);
    // 2. concat
    hipLaunchKernelGGL(concat_kernel, dim3((N_NODES * 72 + 255) / 256), dim3(256), 0, stream,
                       x, conds, batch, xc);
    // 3. node encoder gemm + LN/GELU (+t_emb[batch])
    hipLaunchKernelGGL((gemm_kernel<HID, 8>), dim3(N_NODES / 8), dim3(HID), 0, stream,
                       xc, encW, encb, h, N_NODES, 72);
    hipLaunchKernelGGL(ln_gelu_kernel, dim3(N_NODES), dim3(HID), 0, stream,
                       h, encg, encbe, t_emb, batch);
    // 4. edge encode + self-loop mean
    if (mode == 1) {
        // encode directly to sorted fp16 rows (no atomics), then CSR mean for self-loop rows
        hipLaunchKernelGGL(edge_enc_loop_w_kernel, dim3(N_EDGES / 8), dim3(128), 0, stream,
                           edge_attr, eW, eb, eg, ebe, inv, ea16);
        hipLaunchKernelGGL(csr_loop_mean_kernel, dim3((N_NODES + 1) / 2), dim3(128), 0, stream,
                           ibase, inv, ea16);
    } else {
        hipLaunchKernelGGL(zero_kernel, dim3(1024), dim3(256), 0, stream,
                           loop_attr, (long)N_NODES * HID);
        hipLaunchKernelGGL(zero_kernel, dim3(64), dim3(256), 0, stream, cnt, (long)N_NODES);
        if (mode == 2) {
            hipLaunchKernelGGL((edge_enc_loop_kernel<8, 2>), dim3(N_EDGES / 8), dim3(HID), 0,
                               stream, edge_attr, eW, eb, eg, ebe, ei_dst, loop_attr, cnt, stat,
                               ea32, ea16);
        } else {
            hipLaunchKernelGGL((edge_enc_loop_kernel<8, 0>), dim3(N_EDGES / 8), dim3(HID), 0,
                               stream, edge_attr, eW, eb, eg, ebe, ei_dst, loop_attr, cnt, stat,
                               ea32, ea16);
        }
        hipLaunchKernelGGL(loop_div_kernel, dim3((N_NODES * HID + 255) / 256), dim3(256), 0,
                           stream, loop_attr, cnt);
    }

    // 5. layers
    for (int l = 0; l < NLAYERS; ++l) {
        const float* cWl_l = cWl + (size_t)l * HID * HID;
        const float* cWr_l = cWr + (size_t)l * HID * HID;
        const float* cWe_l = cWe + (size_t)l * HID * HID;
        const float* cbl_l = cbl + (size_t)l * HID;
        const float* cbr_l = cbr + (size_t)l * HID;
        const float* catt_l = catt + (size_t)l * HID;
        const float* cbias_l = cbias + (size_t)l * HID;

        hipLaunchKernelGGL((gemm2_kernel<8>), dim3(N_NODES / 8), dim3(HID), 0, stream,
                           h, cWl_l, cbl_l, cWr_l, cbr_l, xl, xr, N_NODES);
        if (mode == 1) {
            hipLaunchKernelGGL(att_logit10h_kernel, dim3(EF / 16), dim3(128), 0, stream,
                               ea16, src_s, dst_s, cWe_l, catt_l, xl, xr, logit);
            hipLaunchKernelGGL(csr_smax_agg_kernel, dim3((N_NODES + 1) / 2), dim3(128), 0, stream,
                               ibase, src_s, logit, xl, cbias_l, h);
        } else {
            hipLaunchKernelGGL(init_mx_den_kernel, dim3((N_NODES * HEADS + 255) / 256), dim3(256),
                               0, stream, mx, den);
            if (mode == 2) {
                hipLaunchKernelGGL((att_logit6_kernel<8>), dim3(EF / 8), dim3(HID), 0, stream,
                                   ea32, loop_attr, cWe_l, catt_l, xl, xr, ei_src, ei_dst,
                                   logit, mx);
            } else {
                hipLaunchKernelGGL((att_logit7_kernel<8>), dim3(EF / 8), dim3(HID), 0, stream,
                                   edge_attr, eW, eb, eg, ebe, stat, loop_attr,
                                   cWe_l, catt_l, xl, xr, ei_src, ei_dst, logit, mx);
            }
            hipLaunchKernelGGL(softmax_norm_kernel,
                               dim3((int)(((long)EF * HEADS + 255) / 256)), dim3(256), 0, stream,
                               ei_dst, mx, logit, den);
            hipLaunchKernelGGL(zero_kernel, dim3(1024), dim3(256), 0, stream,
                               aggout, (long)N_NODES * HID);
            hipLaunchKernelGGL(aggregate_kernel,
                               dim3((int)(((long)EF * HID + 255) / 256)), dim3(256), 0, stream,
                               logit, den, xl, ei_src, ei_dst, aggout);
            hipLaunchKernelGGL(residual_kernel, dim3((N_NODES * HID + 255) / 256), dim3(256), 0,
                               stream, aggout, cbias_l, h);
        }
    }

    // 6. noise head
    hipLaunchKernelGGL((gemm_kernel<HID, 8>), dim3(N_NODES / 8), dim3(HID), 0, stream,
                       h, nW1, nb1, tmp1, N_NODES, HID);
    hipLaunchKernelGGL(ln_gelu_kernel, dim3(N_NODES), dim3(HID), 0, stream,
                       tmp1, ng, nbe, (const float*)nullptr, (const int*)nullptr);
    hipLaunchKernelGGL((gemm_kernel<NODE_OUT, 8>), dim3(N_NODES / 8), dim3(NODE_OUT), 0, stream,
                       tmp1, nW2, nb2, pred_noise, N_NODES, HID);

    // 7. pooling + props head
    hipLaunchKernelGGL(zero_kernel, dim3(4), dim3(256), 0, stream,
                       gsum, (long)N_GRAPHS * HID);
    hipLaunchKernelGGL(zero_kernel, dim3(1), dim3(64), 0, stream, gcnt, (long)N_GRAPHS);
    hipLaunchKernelGGL(pool_kernel, dim3((N_NODES + POOL_NODES - 1) / POOL_NODES), dim3(HID), 0,
                       stream, h, batch, gsum, gcnt);
    hipLaunchKernelGGL(props_kernel, dim3(N_GRAPHS), dim3(HID), 0, stream,
                       gsum, gcnt, pW1, pb1, pg, pbe, pW2, pb2, pred_props);
}

// Round 13
// 1851.550 us; speedup vs baseline: 1.7540x; 1.3051x over previous
//
#include <hip/hip_runtime.h>
#include <hip/hip_fp16.h>
#include <math.h>

#define N_NODES 30000
#define N_EDGES 480000
#define N_GRAPHS 16
#define HID 128
#define HEADS 8
#define HEAD_DIM 16
#define NODE_IN 64
#define EDGE_IN 32
#define COND 8
#define NODE_OUT 64
#define NLAYERS 4
#define EF (N_EDGES + N_NODES) /* 510000 */
#define LN_EPS 1e-5f
#define SH_STRIDE 132
#define SHH_STRIDE 136  /* half-element stride for fp16 LDS tile (272B, 16B-aligned) */

typedef _Float16 hf2 __attribute__((ext_vector_type(2)));
__device__ __forceinline__ float fdot2_u(unsigned int a, unsigned int b, float c) {
    return __builtin_amdgcn_fdot2(__builtin_bit_cast(hf2, a), __builtin_bit_cast(hf2, b), c, false);
}

__device__ __forceinline__ float gelu_f(float x) {
    return 0.5f * x * (1.0f + erff(x * 0.70710678118654752440f));
}

__device__ __forceinline__ void atomicMaxF(float* addr, float val) {
    if (val >= 0.0f) {
        atomicMax((int*)addr, __float_as_int(val));
    } else {
        atomicMin((unsigned int*)addr, __float_as_uint(val));
    }
}

// ---------- generic zero ----------
__global__ void zero_kernel(float* __restrict__ p, long n) {
    long i = (long)blockIdx.x * blockDim.x + threadIdx.x;
    long stride = (long)gridDim.x * blockDim.x;
    for (; i < n; i += stride) p[i] = 0.0f;
}

// ---------- time MLP ----------
__global__ void time_mlp_kernel(const float* __restrict__ t,
                                const float* __restrict__ tW1, const float* __restrict__ tb1,
                                const float* __restrict__ tW2, const float* __restrict__ tb2,
                                float* __restrict__ t_emb) {
    __shared__ float hsh[HID];
    int b = blockIdx.x, j = threadIdx.x;
    float tv = t[b];
    hsh[j] = gelu_f(tv * tW1[j] + tb1[j]);
    __syncthreads();
    float acc = tb2[j];
    for (int k = 0; k < HID; ++k) acc += hsh[k] * tW2[k * HID + j];
    t_emb[b * HID + j] = acc;
}

// ---------- concat ----------
__global__ void concat_kernel(const float* __restrict__ x, const float* __restrict__ cond,
                              const int* __restrict__ batch, float* __restrict__ xc) {
    int idx = blockIdx.x * blockDim.x + threadIdx.x;
    if (idx >= N_NODES * 72) return;
    int n = idx / 72, c = idx % 72;
    xc[idx] = (c < NODE_IN) ? x[n * NODE_IN + c] : cond[batch[n] * COND + (c - NODE_IN)];
}

// ---------- generic GEMM ----------
template <int NCOL, int R>
__global__ void gemm_kernel(const float* __restrict__ A, const float* __restrict__ B,
                            const float* __restrict__ bias, float* __restrict__ C,
                            int M, int K) {
    __shared__ __align__(16) float sh[R * HID];
    int j = threadIdx.x;
    int row0 = blockIdx.x * R;
    int total = R * K;
    for (int i = j; i < total; i += NCOL) {
        int r = i / K, k = i - r * K;
        int row = row0 + r;
        sh[r * K + k] = (row < M) ? A[(long)row * K + k] : 0.0f;
    }
    __syncthreads();
    float acc[R];
    float bv = bias ? bias[j] : 0.0f;
#pragma unroll
    for (int r = 0; r < R; ++r) acc[r] = bv;
    int KB = K >> 2;
    for (int kb = 0; kb < KB; ++kb) {
        float w0 = B[(kb * 4 + 0) * NCOL + j];
        float w1 = B[(kb * 4 + 1) * NCOL + j];
        float w2 = B[(kb * 4 + 2) * NCOL + j];
        float w3 = B[(kb * 4 + 3) * NCOL + j];
#pragma unroll
        for (int r = 0; r < R; ++r) {
            float4 a = *(const float4*)&sh[r * K + kb * 4];
            acc[r] += a.x * w0 + a.y * w1 + a.z * w2 + a.w * w3;
        }
    }
#pragma unroll
    for (int r = 0; r < R; ++r) {
        int row = row0 + r;
        if (row < M) C[(long)row * NCOL + j] = acc[r];
    }
}

// ---------- fused dual GEMM ----------
template <int R>
__global__ void gemm2_kernel(const float* __restrict__ A,
                             const float* __restrict__ Bl, const float* __restrict__ bl,
                             const float* __restrict__ Br, const float* __restrict__ br,
                             float* __restrict__ Cl, float* __restrict__ Cr, int M) {
    __shared__ __align__(16) float sh[R * HID];
    int j = threadIdx.x;
    int row0 = blockIdx.x * R;
    for (int i = j; i < R * HID; i += HID) {
        int r = i >> 7, k = i & 127;
        int row = row0 + r;
        sh[i] = (row < M) ? A[(long)row * HID + k] : 0.0f;
    }
    __syncthreads();
    float accl[R], accr[R];
    float blv = bl[j], brv = br[j];
#pragma unroll
    for (int r = 0; r < R; ++r) { accl[r] = blv; accr[r] = brv; }
    for (int kb = 0; kb < HID / 4; ++kb) {
        float l0 = Bl[(kb * 4 + 0) * HID + j];
        float l1 = Bl[(kb * 4 + 1) * HID + j];
        float l2 = Bl[(kb * 4 + 2) * HID + j];
        float l3 = Bl[(kb * 4 + 3) * HID + j];
        float r0 = Br[(kb * 4 + 0) * HID + j];
        float r1 = Br[(kb * 4 + 1) * HID + j];
        float r2 = Br[(kb * 4 + 2) * HID + j];
        float r3 = Br[(kb * 4 + 3) * HID + j];
#pragma unroll
        for (int r = 0; r < R; ++r) {
            float4 a = *(const float4*)&sh[r * HID + kb * 4];
            accl[r] += a.x * l0 + a.y * l1 + a.z * l2 + a.w * l3;
            accr[r] += a.x * r0 + a.y * r1 + a.z * r2 + a.w * r3;
        }
    }
#pragma unroll
    for (int r = 0; r < R; ++r) {
        int row = row0 + r;
        if (row < M) {
            Cl[(long)row * HID + j] = accl[r];
            Cr[(long)row * HID + j] = accr[r];
        }
    }
}

// ---------- in-place LayerNorm + GELU ----------
__global__ void ln_gelu_kernel(float* __restrict__ X, const float* __restrict__ g,
                               const float* __restrict__ bta,
                               const float* __restrict__ t_emb, const int* __restrict__ batch) {
    int row = blockIdx.x, j = threadIdx.x;
    __shared__ float red[HID];
    float v = X[(long)row * HID + j];
    red[j] = v;
    __syncthreads();
    for (int s = 64; s > 0; s >>= 1) { if (j < s) red[j] += red[j + s]; __syncthreads(); }
    float mean = red[0] * (1.0f / HID);
    __syncthreads();
    float d = v - mean;
    red[j] = d * d;
    __syncthreads();
    for (int s = 64; s > 0; s >>= 1) { if (j < s) red[j] += red[j + s]; __syncthreads(); }
    float var = red[0] * (1.0f / HID);
    float y = gelu_f(d * rsqrtf(var + LN_EPS) * g[j] + bta[j]);
    if (t_emb) y += t_emb[batch[row] * HID + j];
    X[(long)row * HID + j] = y;
}

// ================= CSR sort setup (mode 1) =================
__global__ void hist_kernel(const int* __restrict__ ei_dst, int* __restrict__ ibase) {
    int idx = blockIdx.x * blockDim.x + threadIdx.x;
    if (idx >= EF) return;
    int d = (idx < N_EDGES) ? ei_dst[idx] : (idx - N_EDGES);
    atomicAdd(&ibase[d + 1], 1);
}

__global__ __launch_bounds__(1024) void scan_kernel(int* __restrict__ ibase) {
    __shared__ int wsums[16];
    __shared__ int s_carry;
    int t = threadIdx.x, lane = t & 63, w = t >> 6;
    if (t == 0) s_carry = 0;
    __syncthreads();
    for (int start = 0; start < N_NODES; start += 1024) {
        int i = start + t;
        int v = (i < N_NODES) ? ibase[i + 1] : 0;
        int x = v;
#pragma unroll
        for (int m = 1; m < 64; m <<= 1) {
            int y = __shfl_up(x, m);
            if (lane >= m) x += y;
        }
        if (lane == 63) wsums[w] = x;
        __syncthreads();
        if (w == 0 && lane < 16) {
            int ws = wsums[lane];
#pragma unroll
            for (int m = 1; m < 16; m <<= 1) {
                int y = __shfl_up(ws, m);
                if (lane >= m) ws += y;
            }
            wsums[lane] = ws;
        }
        __syncthreads();
        int waveoff = (w == 0) ? 0 : wsums[w - 1];
        int incl = x + waveoff + s_carry;
        if (i < N_NODES) ibase[i + 1] = incl;
        __syncthreads();
        if (t == 1023) s_carry = incl;
        __syncthreads();
    }
}

__global__ void scatter_kernel(const int* __restrict__ ei_src, const int* __restrict__ ei_dst,
                               const int* __restrict__ ibase, int* __restrict__ icursor,
                               int* __restrict__ src_s, int* __restrict__ dst_s,
                               int* __restrict__ inv) {
    int idx = blockIdx.x * blockDim.x + threadIdx.x;
    if (idx >= EF) return;
    int s, d;
    if (idx < N_EDGES) { s = ei_src[idx]; d = ei_dst[idx]; }
    else               { s = d = idx - N_EDGES; }
    int pos = ibase[d] + atomicAdd(&icursor[d], 1);
    src_s[pos] = s;
    dst_s[pos] = d;
    inv[idx] = pos;
}

// ---------- prep: pack cWe into half2-k layout: W2[l][kp*128+c] = {cWe[2kp][c], cWe[2kp+1][c]} ----------
__global__ void prep_cwe16_kernel(const float* __restrict__ cWe, unsigned int* __restrict__ W2) {
    int idx = blockIdx.x * blockDim.x + threadIdx.x;
    if (idx >= NLAYERS * 64 * HID) return;
    int l = idx / (64 * HID), rem = idx % (64 * HID);
    int kp = rem >> 7, c = rem & 127;
    float w0 = cWe[(size_t)l * HID * HID + (2 * kp) * HID + c];
    float w1 = cWe[(size_t)l * HID * HID + (2 * kp + 1) * HID + c];
    unsigned int u = ((unsigned int)__half_as_ushort(__float2half(w1)) << 16)
                   | (unsigned int)__half_as_ushort(__float2half(w0));
    W2[idx] = u;
}

// ---------- CSR loop-mean ----------
__global__ __launch_bounds__(128) void csr_loop_mean_kernel(
        const int* __restrict__ ibase, const int* __restrict__ inv,
        __half* __restrict__ ea16) {
    int w = threadIdx.x >> 6, lane = threadIdx.x & 63;
    int d = blockIdx.x * 2 + w;
    if (d >= N_NODES) return;
    int b0 = ibase[d], b1 = ibase[d + 1];
    int selfpos = inv[N_EDGES + d];
    float a0 = 0.0f, a1 = 0.0f;
    for (int i = b0; i < b1; ++i) {
        if (i == selfpos) continue;
        a0 += __half2float(ea16[(long)i * HID + lane]);
        a1 += __half2float(ea16[(long)i * HID + lane + 64]);
    }
    float c = fmaxf((float)(b1 - b0 - 1), 1.0f);
    ea16[(long)selfpos * HID + lane]      = __float2half(a0 / c);
    ea16[(long)selfpos * HID + lane + 64] = __float2half(a1 / c);
}

// ---------- fallback (modes 0/2): edge-encode + segment-sum, LDS-tree LN ----------
template <int R, int MODE>
__global__ void edge_enc_loop_kernel(const float* __restrict__ edge_attr,
                                     const float* __restrict__ eW, const float* __restrict__ eb,
                                     const float* __restrict__ eg, const float* __restrict__ ebe,
                                     const int* __restrict__ ei_dst,
                                     float* __restrict__ loop_sum, float* __restrict__ cnt,
                                     float* __restrict__ stat,
                                     float* __restrict__ ea32, __half* __restrict__ ea16) {
    __shared__ float red[R * HID];
    __shared__ __align__(16) float sattr[R * EDGE_IN];
    __shared__ int sdst[R];
    int j = threadIdx.x;
    long e0 = (long)blockIdx.x * R;
    if (j < R * EDGE_IN / 4)
        ((float4*)sattr)[j] = ((const float4*)(edge_attr + e0 * EDGE_IN))[j];
    if (j < R) sdst[j] = ei_dst[e0 + j];
    __syncthreads();
    float val[R];
    float ebv = eb[j];
#pragma unroll
    for (int r = 0; r < R; ++r) val[r] = ebv;
#pragma unroll
    for (int kb = 0; kb < EDGE_IN / 4; ++kb) {
        float w0 = eW[(kb * 4 + 0) * HID + j];
        float w1 = eW[(kb * 4 + 1) * HID + j];
        float w2 = eW[(kb * 4 + 2) * HID + j];
        float w3 = eW[(kb * 4 + 3) * HID + j];
#pragma unroll
        for (int r = 0; r < R; ++r) {
            float4 a = *(const float4*)&sattr[r * EDGE_IN + kb * 4];
            val[r] += a.x * w0 + a.y * w1 + a.z * w2 + a.w * w3;
        }
    }
#pragma unroll
    for (int r = 0; r < R; ++r) red[r * HID + j] = val[r];
    __syncthreads();
    for (int s = 64; s > 0; s >>= 1) {
        if (j < s) {
#pragma unroll
            for (int r = 0; r < R; ++r) red[r * HID + j] += red[r * HID + j + s];
        }
        __syncthreads();
    }
    float mean[R];
#pragma unroll
    for (int r = 0; r < R; ++r) mean[r] = red[r * HID] * (1.0f / HID);
    __syncthreads();
#pragma unroll
    for (int r = 0; r < R; ++r) { float d = val[r] - mean[r]; red[r * HID + j] = d * d; }
    __syncthreads();
    for (int s = 64; s > 0; s >>= 1) {
        if (j < s) {
#pragma unroll
            for (int r = 0; r < R; ++r) red[r * HID + j] += red[r * HID + j + s];
        }
        __syncthreads();
    }
    float egv = eg[j], bev = ebe[j];
#pragma unroll
    for (int r = 0; r < R; ++r) {
        float var = red[r * HID] * (1.0f / HID);
        float rstd = rsqrtf(var + LN_EPS);
        float y = gelu_f((val[r] - mean[r]) * rstd * egv + bev);
        int d = sdst[r];
        long e = e0 + r;
        if (j == 0) { stat[e * 2] = mean[r]; stat[e * 2 + 1] = rstd; }
        if (MODE == 2) ea32[e * HID + j] = y;
        if (MODE == 1) ea16[e * HID + j] = __float2half(y);
        atomicAdd(&loop_sum[(long)d * HID + j], y);
        if (j == 0) atomicAdd(&cnt[d], 1.0f);
    }
}

// ---------- mode-1 MAIN enc: wave-owns-rows, shfl LN, fp16 ea to sorted pos, NO atomics ----------
__global__ __launch_bounds__(128) void edge_enc_loop_w_kernel(
        const float* __restrict__ edge_attr,
        const float* __restrict__ eW, const float* __restrict__ eb,
        const float* __restrict__ eg, const float* __restrict__ ebe,
        const int* __restrict__ inv,
        __half* __restrict__ ea16) {
    const int R = 8;
    __shared__ __align__(16) float sattr[R * EDGE_IN];
    __shared__ int spos[R];
    int t = threadIdx.x;
    long e0 = (long)blockIdx.x * R;
    if (t < R * EDGE_IN / 4)
        ((float4*)sattr)[t] = ((const float4*)(edge_attr + e0 * EDGE_IN))[t];
    if (t < R) spos[t] = inv[e0 + t];
    __syncthreads();
    int lane = t & 63, w = t >> 6;
    int r0 = w * 4;
    int j1 = lane, j2 = lane + 64;
    float eb1 = eb[j1], eb2 = eb[j2];
    float v0[4], v1[4];
#pragma unroll
    for (int q = 0; q < 4; ++q) { v0[q] = eb1; v1[q] = eb2; }
#pragma unroll
    for (int kb = 0; kb < EDGE_IN / 4; ++kb) {
        float w10 = eW[(kb * 4 + 0) * HID + j1];
        float w11 = eW[(kb * 4 + 1) * HID + j1];
        float w12 = eW[(kb * 4 + 2) * HID + j1];
        float w13 = eW[(kb * 4 + 3) * HID + j1];
        float w20 = eW[(kb * 4 + 0) * HID + j2];
        float w21 = eW[(kb * 4 + 1) * HID + j2];
        float w22 = eW[(kb * 4 + 2) * HID + j2];
        float w23 = eW[(kb * 4 + 3) * HID + j2];
#pragma unroll
        for (int q = 0; q < 4; ++q) {
            float4 a = *(const float4*)&sattr[(r0 + q) * EDGE_IN + kb * 4];
            v0[q] += a.x * w10 + a.y * w11 + a.z * w12 + a.w * w13;
            v1[q] += a.x * w20 + a.y * w21 + a.z * w22 + a.w * w23;
        }
    }
    float eg1 = eg[j1], eg2 = eg[j2];
    float be1 = ebe[j1], be2 = ebe[j2];
#pragma unroll
    for (int q = 0; q < 4; ++q) {
        float s1 = v0[q] + v1[q];
        float s2 = v0[q] * v0[q] + v1[q] * v1[q];
#pragma unroll
        for (int m = 1; m < 64; m <<= 1) {
            s1 += __shfl_xor(s1, m);
            s2 += __shfl_xor(s2, m);
        }
        float mean = s1 * (1.0f / 128.0f);
        float var = s2 * (1.0f / 128.0f) - mean * mean;
        float rstd = rsqrtf(var + LN_EPS);
        float y0 = gelu_f((v0[q] - mean) * rstd * eg1 + be1);
        float y1 = gelu_f((v1[q] - mean) * rstd * eg2 + be2);
        long pos = spos[r0 + q];
        ea16[pos * HID + j1] = __float2half(y0);
        ea16[pos * HID + j2] = __float2half(y1);
    }
}

__global__ void loop_div_kernel(float* __restrict__ loop_attr, const float* __restrict__ cnt) {
    int idx = blockIdx.x * blockDim.x + threadIdx.x;
    if (idx >= N_NODES * HID) return;
    int n = idx >> 7;
    loop_attr[idx] = loop_attr[idx] / fmaxf(cnt[n], 1.0f);
}

// ---------- init mx=-inf, den=0 (modes 0/2) ----------
__global__ void init_mx_den_kernel(float* __restrict__ mx, float* __restrict__ den) {
    int idx = blockIdx.x * blockDim.x + threadIdx.x;
    if (idx >= N_NODES * HEADS) return;
    mx[idx] = -INFINITY;
    den[idx] = 0.0f;
}

// ---------- shared epilogue (fallback variants) ----------
template <int R>
__device__ __forceinline__ void em_logit_body(
        const float* __restrict__ sh, const int* __restrict__ ssrc, const int* __restrict__ sdst,
        const float* __restrict__ cWe_l, const float* __restrict__ catt_l,
        const float* __restrict__ xl, const float* __restrict__ xr,
        float* __restrict__ logit, float* __restrict__ mx, long e0, int j) {
    float acc[R];
#pragma unroll
    for (int r = 0; r < R; ++r) acc[r] = 0.0f;
    for (int kb = 0; kb < HID / 4; ++kb) {
        float w0 = cWe_l[(kb * 4 + 0) * HID + j];
        float w1 = cWe_l[(kb * 4 + 1) * HID + j];
        float w2 = cWe_l[(kb * 4 + 2) * HID + j];
        float w3 = cWe_l[(kb * 4 + 3) * HID + j];
#pragma unroll
        for (int r = 0; r < R; ++r) {
            float4 a = *(const float4*)&sh[r * HID + kb * 4];
            acc[r] += a.x * w0 + a.y * w1 + a.z * w2 + a.w * w3;
        }
    }
    float cj = catt_l[j];
    int head = j >> 4;
#pragma unroll
    for (int r = 0; r < R; ++r) {
        long e = e0 + r;
        int s = ssrc[r], d = sdst[r];
        float m = xl[(long)s * HID + j] + xr[(long)d * HID + j] + acc[r];
        m = (m > 0.0f) ? m : 0.2f * m;
        float p = m * cj;
        p += __shfl_down(p, 8, 16);
        p += __shfl_down(p, 4, 16);
        p += __shfl_down(p, 2, 16);
        p += __shfl_down(p, 1, 16);
        if ((j & 15) == 0) {
            logit[e * HEADS + head] = p;
            atomicMaxF(&mx[(long)d * HEADS + head], p);
        }
    }
}

// ---------- att kernel, mode 0 fallback ----------
template <int R>
__global__ void att_logit7_kernel(const float* __restrict__ edge_attr,
                                  const float* __restrict__ eW, const float* __restrict__ eb,
                                  const float* __restrict__ eg, const float* __restrict__ ebe,
                                  const float* __restrict__ stat,
                                  const float* __restrict__ loop_attr,
                                  const float* __restrict__ cWe_l, const float* __restrict__ catt_l,
                                  const float* __restrict__ xl, const float* __restrict__ xr,
                                  const int* __restrict__ ei_src, const int* __restrict__ ei_dst,
                                  float* __restrict__ logit, float* __restrict__ mx) {
    __shared__ __align__(16) float sh[R * HID];
    __shared__ __align__(16) float sattr[R * EDGE_IN];
    __shared__ float sstat[R * 2];
    __shared__ int ssrc[R], sdst[R];
    int j = threadIdx.x;
    long e0 = (long)blockIdx.x * R;
    bool realblk = (e0 < N_EDGES);

    if (realblk) {
        if (j < R * EDGE_IN / 4)
            ((float4*)sattr)[j] = ((const float4*)(edge_attr + e0 * EDGE_IN))[j];
        if (j < R * 2) sstat[j] = stat[e0 * 2 + j];
        if (j < R) { ssrc[j] = ei_src[e0 + j]; sdst[j] = ei_dst[e0 + j]; }
    } else {
        if (j < R) ssrc[j] = sdst[j] = (int)(e0 + j - N_EDGES);
    }
    __syncthreads();

    if (realblk) {
        float val[R];
        float ebv = eb[j];
#pragma unroll
        for (int r = 0; r < R; ++r) val[r] = ebv;
#pragma unroll
        for (int kb = 0; kb < EDGE_IN / 4; ++kb) {
            float w0 = eW[(kb * 4 + 0) * HID + j];
            float w1 = eW[(kb * 4 + 1) * HID + j];
            float w2 = eW[(kb * 4 + 2) * HID + j];
            float w3 = eW[(kb * 4 + 3) * HID + j];
#pragma unroll
            for (int r = 0; r < R; ++r) {
                float4 a = *(const float4*)&sattr[r * EDGE_IN + kb * 4];
                val[r] += a.x * w0 + a.y * w1 + a.z * w2 + a.w * w3;
            }
        }
        float egv = eg[j], bev = ebe[j];
#pragma unroll
        for (int r = 0; r < R; ++r) {
            float mean = sstat[r * 2], rstd = sstat[r * 2 + 1];
            sh[r * HID + j] = gelu_f((val[r] - mean) * rstd * egv + bev);
        }
    } else {
#pragma unroll
        for (int r = 0; r < R; ++r)
            sh[r * HID + j] = loop_attr[(long)(e0 + r - N_EDGES) * HID + j];
    }
    __syncthreads();
    em_logit_body<R>(sh, ssrc, sdst, cWe_l, catt_l, xl, xr, logit, mx, e0, j);
}

// ---------- att kernel, mode 2 fallback ----------
template <int R>
__global__ void att_logit6_kernel(const float* __restrict__ ea,
                                  const float* __restrict__ loop_attr,
                                  const float* __restrict__ cWe_l, const float* __restrict__ catt_l,
                                  const float* __restrict__ xl, const float* __restrict__ xr,
                                  const int* __restrict__ ei_src, const int* __restrict__ ei_dst,
                                  float* __restrict__ logit, float* __restrict__ mx) {
    __shared__ __align__(16) float sh[R * HID];
    __shared__ int ssrc[R], sdst[R];
    int j = threadIdx.x;
    long e0 = (long)blockIdx.x * R;
    bool realblk = (e0 < N_EDGES);
    const float* srcp = realblk ? (ea + e0 * HID) : (loop_attr + (e0 - N_EDGES) * HID);
    const float4* s4 = (const float4*)srcp;
    ((float4*)sh)[j]       = s4[j];
    ((float4*)sh)[j + HID] = s4[j + HID];
    if (j < R) {
        long e = e0 + j;
        if (realblk) { ssrc[j] = ei_src[e]; sdst[j] = ei_dst[e]; }
        else         { ssrc[j] = sdst[j] = (int)(e - N_EDGES); }
    }
    __syncthreads();
    em_logit_body<R>(sh, ssrc, sdst, cWe_l, catt_l, xl, xr, logit, mx, e0, j);
}

// ---------- att kernel, mode 1 MAIN: fp16 LDS + v_dot2_f32_f16 GEMM ----------
// Thread: cg=t&31 -> cols cg*4..+3; rg=t>>5 -> rows rg*4..+3.
// LDS tile kept in raw fp16 (no cvt in staging). Weights in half2-k packed layout:
// W2[kp*128+c] = {w[2kp][c], w[2kp+1][c]}. Per 8-k chunk: 4 ds_read_b128 (rows) +
// 4 uint4 weight loads feed 64 fdot2 (=128 MACs, fp32 accumulate).
__global__ __launch_bounds__(128) void att_logit11h_kernel(
        const __half* __restrict__ ea,          /* sorted [EF,128] */
        const int* __restrict__ src_s, const int* __restrict__ dst_s,
        const unsigned int* __restrict__ cWe16_l, /* [64][128] half2-packed */
        const float* __restrict__ catt_l,
        const float* __restrict__ xl, const float* __restrict__ xr,
        float* __restrict__ logit) {
    const int R = 16;
    __shared__ __align__(16) __half sh[R * SHH_STRIDE];
    __shared__ int ssrc[R], sdst[R];
    int t = threadIdx.x;
    long e0 = (long)blockIdx.x * R;

    // stage raw halves: 256 uint4 (16 rows x 16 uint4/row)
    const uint4* s16 = (const uint4*)(ea + e0 * HID);
#pragma unroll
    for (int i = 0; i < 2; ++i) {
        int idx = t + i * 128;
        uint4 u = s16[idx];
        int row = idx >> 4, col8 = idx & 15;
        *(uint4*)&sh[row * SHH_STRIDE + col8 * 8] = u;
    }
    if (t < R) ssrc[t] = src_s[e0 + t];
    else if (t < 2 * R) sdst[t - R] = dst_s[e0 + (t - R)];
    __syncthreads();

    int cg = t & 31, rg = t >> 5;
    int c0 = cg * 4;
    float acc[4][4];
#pragma unroll
    for (int i = 0; i < 4; ++i)
#pragma unroll
        for (int c = 0; c < 4; ++c) acc[i][c] = 0.0f;
    const uint4* W4 = (const uint4*)cWe16_l;  // [64 kp][32 uint4]
    for (int kc = 0; kc < 16; ++kc) {         // 8 k's per chunk = 4 kpairs
        uint4 w0 = W4[(kc * 4 + 0) * 32 + cg];
        uint4 w1 = W4[(kc * 4 + 1) * 32 + cg];
        uint4 w2 = W4[(kc * 4 + 2) * 32 + cg];
        uint4 w3 = W4[(kc * 4 + 3) * 32 + cg];
        const unsigned int* wp0 = (const unsigned int*)&w0;
        const unsigned int* wp1 = (const unsigned int*)&w1;
        const unsigned int* wp2 = (const unsigned int*)&w2;
        const unsigned int* wp3 = (const unsigned int*)&w3;
#pragma unroll
        for (int i = 0; i < 4; ++i) {
            uint4 a = *(const uint4*)&sh[(rg * 4 + i) * SHH_STRIDE + kc * 8];
#pragma unroll
            for (int c = 0; c < 4; ++c) {
                float v = acc[i][c];
                v = fdot2_u(a.x, wp0[c], v);
                v = fdot2_u(a.y, wp1[c], v);
                v = fdot2_u(a.z, wp2[c], v);
                v = fdot2_u(a.w, wp3[c], v);
                acc[i][c] = v;
            }
        }
    }

    float4 cat4 = *(const float4*)&catt_l[c0];
    int head = cg >> 2;
#pragma unroll
    for (int i = 0; i < 4; ++i) {
        int r = rg * 4 + i;
        long e = e0 + r;
        int s = ssrc[r], d = sdst[r];
        float4 xlv = *(const float4*)&xl[(long)s * HID + c0];
        float4 xrv = *(const float4*)&xr[(long)d * HID + c0];
        float m0 = xlv.x + xrv.x + acc[i][0]; m0 = (m0 > 0.0f) ? m0 : 0.2f * m0;
        float m1 = xlv.y + xrv.y + acc[i][1]; m1 = (m1 > 0.0f) ? m1 : 0.2f * m1;
        float m2 = xlv.z + xrv.z + acc[i][2]; m2 = (m2 > 0.0f) ? m2 : 0.2f * m2;
        float m3 = xlv.w + xrv.w + acc[i][3]; m3 = (m3 > 0.0f) ? m3 : 0.2f * m3;
        float p = m0 * cat4.x + m1 * cat4.y + m2 * cat4.z + m3 * cat4.w;
        p += __shfl_xor(p, 1);
        p += __shfl_xor(p, 2);
        if ((cg & 3) == 0) logit[e * HEADS + head] = p;
    }
}

// ---------- CSR fused softmax + aggregate + residual (mode 1) ----------
__global__ __launch_bounds__(128) void csr_smax_agg_kernel(
        const int* __restrict__ ibase, const int* __restrict__ src_s,
        const float* __restrict__ logit, const float* __restrict__ xl,
        const float* __restrict__ cbias_l, float* __restrict__ h) {
    int w = threadIdx.x >> 6, lane = threadIdx.x & 63;
    int d = blockIdx.x * 2 + w;
    if (d >= N_NODES) return;
    int b0 = ibase[d], b1 = ibase[d + 1];
    int hh = lane & 7, g = lane >> 3;
    float m = -INFINITY;
    for (int i = b0 + g; i < b1; i += 8) m = fmaxf(m, logit[(long)i * 8 + hh]);
    m = fmaxf(m, __shfl_xor(m, 8));
    m = fmaxf(m, __shfl_xor(m, 16));
    m = fmaxf(m, __shfl_xor(m, 32));
    float den = 0.0f;
    for (int i = b0 + g; i < b1; i += 8) den += expf(logit[(long)i * 8 + hh] - m);
    den += __shfl_xor(den, 8);
    den += __shfl_xor(den, 16);
    den += __shfl_xor(den, 32);
    int h1 = lane >> 4, h2 = 4 + (lane >> 4);
    float mx1 = __shfl(m, h1), mx2 = __shfl(m, h2);
    float dn1 = __shfl(den, h1) + 1e-16f, dn2 = __shfl(den, h2) + 1e-16f;
    float acc0 = 0.0f, acc1 = 0.0f;
    for (int i = b0; i < b1; ++i) {
        int s = src_s[i];
        float a0 = expf(logit[(long)i * 8 + h1] - mx1) / dn1;
        float a1 = expf(logit[(long)i * 8 + h2] - mx2) / dn2;
        acc0 += a0 * xl[(long)s * HID + lane];
        acc1 += a1 * xl[(long)s * HID + lane + 64];
    }
    long o = (long)d * HID + lane;
    h[o]      = gelu_f(acc0 + cbias_l[lane])      + h[o];
    h[o + 64] = gelu_f(acc1 + cbias_l[lane + 64]) + h[o + 64];
}

// ---------- fallback chain kernels (modes 0/2) ----------
__global__ void softmax_norm_kernel(const int* __restrict__ ei_dst, const float* __restrict__ mx,
                                    float* __restrict__ logit, float* __restrict__ den) {
    long idx = (long)blockIdx.x * blockDim.x + threadIdx.x;
    if (idx >= (long)EF * HEADS) return;
    long e = idx >> 3;
    int hh = (int)(idx & 7);
    int d = (e < N_EDGES) ? ei_dst[e] : (int)(e - N_EDGES);
    float ex = expf(logit[idx] - mx[(long)d * HEADS + hh]);
    logit[idx] = ex;
    atomicAdd(&den[(long)d * HEADS + hh], ex);
}

__global__ void aggregate_kernel(const float* __restrict__ logit, const float* __restrict__ den,
                                 const float* __restrict__ xl,
                                 const int* __restrict__ ei_src, const int* __restrict__ ei_dst,
                                 float* __restrict__ aggout) {
    long idx = (long)blockIdx.x * blockDim.x + threadIdx.x;
    if (idx >= (long)EF * HID) return;
    long e = idx >> 7;
    int j = (int)(idx & 127);
    int s, d;
    if (e < N_EDGES) { s = ei_src[e]; d = ei_dst[e]; }
    else             { s = d = (int)(e - N_EDGES); }
    int head = j >> 4;
    float alpha = logit[e * HEADS + head] / (den[(long)d * HEADS + head] + 1e-16f);
    atomicAdd(&aggout[(long)d * HID + j], alpha * xl[(long)s * HID + j]);
}

__global__ void residual_kernel(const float* __restrict__ aggout, const float* __restrict__ cbias_l,
                                float* __restrict__ h) {
    int idx = blockIdx.x * blockDim.x + threadIdx.x;
    if (idx >= N_NODES * HID) return;
    int j = idx & 127;
    h[idx] = gelu_f(aggout[idx] + cbias_l[j]) + h[idx];
}

// ---------- pooling ----------
#define POOL_NODES 64
__global__ void pool_kernel(const float* __restrict__ h, const int* __restrict__ batch,
                            float* __restrict__ gsum, float* __restrict__ gcnt) {
    __shared__ float acc[N_GRAPHS][HID];
    __shared__ float cnt_sh[N_GRAPHS];
    int j = threadIdx.x;
    for (int g = 0; g < N_GRAPHS; ++g) acc[g][j] = 0.0f;
    if (j < N_GRAPHS) cnt_sh[j] = 0.0f;
    __syncthreads();
    int n0 = blockIdx.x * POOL_NODES;
    for (int i = 0; i < POOL_NODES; ++i) {
        int n = n0 + i;
        if (n >= N_NODES) break;
        int g = batch[n];
        acc[g][j] += h[(long)n * HID + j];
        if (j == 0) cnt_sh[g] += 1.0f;
    }
    __syncthreads();
    for (int g = 0; g < N_GRAPHS; ++g) atomicAdd(&gsum[g * HID + j], acc[g][j]);
    if (j < N_GRAPHS) atomicAdd(&gcnt[j], cnt_sh[j]);
}

// ---------- props head ----------
__global__ void props_kernel(const float* __restrict__ gsum, const float* __restrict__ gcnt,
                             const float* __restrict__ pW1, const float* __restrict__ pb1,
                             const float* __restrict__ pg, const float* __restrict__ pbe,
                             const float* __restrict__ pW2, const float* __restrict__ pb2,
                             float* __restrict__ out_props) {
    int g = blockIdx.x, j = threadIdx.x;
    __shared__ float feat[HID], red[HID], t2[HID];
    float c = fmaxf(gcnt[g], 1.0f);
    feat[j] = gsum[g * HID + j] / c;
    __syncthreads();
    float acc = pb1[j];
    for (int k = 0; k < HID; ++k) acc += feat[k] * pW1[k * HID + j];
    red[j] = acc;
    __syncthreads();
    for (int s = 64; s > 0; s >>= 1) { if (j < s) red[j] += red[j + s]; __syncthreads(); }
    float mean = red[0] * (1.0f / HID);
    __syncthreads();
    float dd = acc - mean;
    red[j] = dd * dd;
    __syncthreads();
    for (int s = 64; s > 0; s >>= 1) { if (j < s) red[j] += red[j + s]; __syncthreads(); }
    float var = red[0] * (1.0f / HID);
    t2[j] = gelu_f(dd * rsqrtf(var + LN_EPS) * pg[j] + pbe[j]);
    __syncthreads();
    if (j < COND) {
        float a = pb2[j];
        for (int k = 0; k < HID; ++k) a += t2[k] * pW2[k * COND + j];
        out_props[g * COND + j] = a;
    }
}

extern "C" void kernel_launch(void* const* d_in, const int* in_sizes, int n_in,
                              void* d_out, int out_size, void* d_ws, size_t ws_size,
                              hipStream_t stream) {
    const float* x        = (const float*)d_in[0];
    const float* edge_attr= (const float*)d_in[1];
    const float* t        = (const float*)d_in[2];
    const float* conds    = (const float*)d_in[3];
    const float* tW1      = (const float*)d_in[4];
    const float* tb1      = (const float*)d_in[5];
    const float* tW2      = (const float*)d_in[6];
    const float* tb2      = (const float*)d_in[7];
    const float* encW     = (const float*)d_in[8];
    const float* encb     = (const float*)d_in[9];
    const float* encg     = (const float*)d_in[10];
    const float* encbe    = (const float*)d_in[11];
    const float* eW       = (const float*)d_in[12];
    const float* eb       = (const float*)d_in[13];
    const float* eg       = (const float*)d_in[14];
    const float* ebe      = (const float*)d_in[15];
    const float* cWl      = (const float*)d_in[16];
    const float* cbl      = (const float*)d_in[17];
    const float* cWr      = (const float*)d_in[18];
    const float* cbr      = (const float*)d_in[19];
    const float* cWe      = (const float*)d_in[20];
    const float* catt     = (const float*)d_in[21];
    const float* cbias    = (const float*)d_in[22];
    const float* nW1      = (const float*)d_in[23];
    const float* nb1      = (const float*)d_in[24];
    const float* ng       = (const float*)d_in[25];
    const float* nbe      = (const float*)d_in[26];
    const float* nW2      = (const float*)d_in[27];
    const float* nb2      = (const float*)d_in[28];
    const float* pW1      = (const float*)d_in[29];
    const float* pb1      = (const float*)d_in[30];
    const float* pg       = (const float*)d_in[31];
    const float* pbe      = (const float*)d_in[32];
    const float* pW2      = (const float*)d_in[33];
    const float* pb2      = (const float*)d_in[34];
    const int* edge_index = (const int*)d_in[35];
    const int* batch      = (const int*)d_in[36];
    const int* ei_src = edge_index;
    const int* ei_dst = edge_index + N_EDGES;

    // workspace: common + union(mode1 sort ints + cWe16 | mode0/2 stat+mx+den+aggout) + ea
    float* ws = (float*)d_ws;
    size_t off = 0;
    auto alloc = [&](size_t n) { float* p = ws + off; off += n; return p; };
    float* t_emb     = alloc((size_t)N_GRAPHS * HID);
    float* h         = alloc((size_t)N_NODES * HID);
    float* loop_attr = alloc((size_t)N_NODES * HID);
    float* cnt       = alloc((size_t)N_NODES);
    float* xl        = alloc((size_t)N_NODES * HID);
    float* xr        = alloc((size_t)N_NODES * HID);
    float* logit     = alloc((size_t)EF * HEADS);      // 4.08M floats
    float* gsum      = alloc((size_t)N_GRAPHS * HID);
    float* gcnt      = alloc((size_t)N_GRAPHS);
    // union region (5.28M float slots):
    float* uni = alloc((size_t)(960000 + 240000 + 240000 + (size_t)N_NODES * HID));
    // mode-0/2 view:
    float* stat   = uni;                  // [N_EDGES*2]
    float* mx     = uni + 960000;         // [N*8]
    float* den    = uni + 960000 + 240000;
    float* aggout = uni + 960000 + 480000; // [N*128]
    // mode-1 view (ints + packed fp16 weights):
    int* ibase   = (int*)uni;                         // [N_NODES+1]
    int* icursor = ibase + (N_NODES + 1);             // [N_NODES]
    int* src_s   = icursor + N_NODES;                 // [EF]
    int* dst_s   = src_s + EF;                        // [EF]
    int* inv     = dst_s + EF;                        // [EF]
    unsigned int* cWe16 = (unsigned int*)(inv + EF);  // [NLAYERS][64][128] (32768 uints)
    size_t base_bytes = off * sizeof(float);
    float*  ea32 = ws + off;
    __half* ea16 = (__half*)(ws + off);
    int mode = 0;
    if (ws_size >= base_bytes + (size_t)EF * HID * sizeof(float)) mode = 2;
    else if (ws_size >= base_bytes + (size_t)EF * HID * sizeof(__half)) mode = 1;
    // aliases (disjoint lifetimes):
    float* xc   = logit;  // [N,72] used only pre-layers
    float* tmp1 = xl;     // used only post-layers
    (void)in_sizes; (void)n_in; (void)out_size;

    float* pred_noise = (float*)d_out;                              // [N,64]
    float* pred_props = (float*)d_out + (size_t)N_NODES * NODE_OUT; // [16,8]

    // 0. (mode 1) CSR sort of edges by dst + fp16 weight packing
    if (mode == 1) {
        hipLaunchKernelGGL(zero_kernel, dim3(64), dim3(256), 0, stream,
                           (float*)ibase, (long)(2 * N_NODES + 1));  // ibase + icursor
        hipLaunchKernelGGL(hist_kernel, dim3((EF + 255) / 256), dim3(256), 0, stream,
                           ei_dst, ibase);
        hipLaunchKernelGGL(scan_kernel, dim3(1), dim3(1024), 0, stream, ibase);
        hipLaunchKernelGGL(scatter_kernel, dim3((EF + 255) / 256), dim3(256), 0, stream,
                           ei_src, ei_dst, ibase, icursor, src_s, dst_s, inv);
        hipLaunchKernelGGL(prep_cwe16_kernel, dim3((NLAYERS * 64 * HID + 255) / 256), dim3(256),
                           0, stream, cWe, cWe16);
    }
    // 1. time MLP
    hipLaunchKernelGGL(time_mlp_kernel, dim3(N_GRAPHS), dim3(HID), 0, stream,
                       t, tW1, tb1, tW2, tb2, t_emb);
    // 2. concat
    hipLaunchKernelGGL(concat_kernel, dim3((N_NODES * 72 + 255) / 256), dim3(256), 0, stream,
                       x, conds, batch, xc);
    // 3. node encoder gemm + LN/GELU (+t_emb[batch])
    hipLaunchKernelGGL((gemm_kernel<HID, 8>), dim3(N_NODES / 8), dim3(HID), 0, stream,
                       xc, encW, encb, h, N_NODES, 72);
    hipLaunchKernelGGL(ln_gelu_kernel, dim3(N_NODES), dim3(HID), 0, stream,
                       h, encg, encbe, t_emb, batch);
    // 4. edge encode + self-loop mean
    if (mode == 1) {
        hipLaunchKernelGGL(edge_enc_loop_w_kernel, dim3(N_EDGES / 8), dim3(128), 0, stream,
                           edge_attr, eW, eb, eg, ebe, inv, ea16);
        hipLaunchKernelGGL(csr_loop_mean_kernel, dim3((N_NODES + 1) / 2), dim3(128), 0, stream,
                           ibase, inv, ea16);
    } else {
        hipLaunchKernelGGL(zero_kernel, dim3(1024), dim3(256), 0, stream,
                           loop_attr, (long)N_NODES * HID);
        hipLaunchKernelGGL(zero_kernel, dim3(64), dim3(256), 0, stream, cnt, (long)N_NODES);
        if (mode == 2) {
            hipLaunchKernelGGL((edge_enc_loop_kernel<8, 2>), dim3(N_EDGES / 8), dim3(HID), 0,
                               stream, edge_attr, eW, eb, eg, ebe, ei_dst, loop_attr, cnt, stat,
                               ea32, ea16);
        } else {
            hipLaunchKernelGGL((edge_enc_loop_kernel<8, 0>), dim3(N_EDGES / 8), dim3(HID), 0,
                               stream, edge_attr, eW, eb, eg, ebe, ei_dst, loop_attr, cnt, stat,
                               ea32, ea16);
        }
        hipLaunchKernelGGL(loop_div_kernel, dim3((N_NODES * HID + 255) / 256), dim3(256), 0,
                           stream, loop_attr, cnt);
    }

    // 5. layers
    for (int l = 0; l < NLAYERS; ++l) {
        const float* cWl_l = cWl + (size_t)l * HID * HID;
        const float* cWr_l = cWr + (size_t)l * HID * HID;
        const float* cWe_l = cWe + (size_t)l * HID * HID;
        const unsigned int* cWe16_l = cWe16 + (size_t)l * 64 * HID;
        const float* cbl_l = cbl + (size_t)l * HID;
        const float* cbr_l = cbr + (size_t)l * HID;
        const float* catt_l = catt + (size_t)l * HID;
        const float* cbias_l = cbias + (size_t)l * HID;

        hipLaunchKernelGGL((gemm2_kernel<8>), dim3(N_NODES / 8), dim3(HID), 0, stream,
                           h, cWl_l, cbl_l, cWr_l, cbr_l, xl, xr, N_NODES);
        if (mode == 1) {
            hipLaunchKernelGGL(att_logit11h_kernel, dim3(EF / 16), dim3(128), 0, stream,
                               ea16, src_s, dst_s, cWe16_l, catt_l, xl, xr, logit);
            hipLaunchKernelGGL(csr_smax_agg_kernel, dim3((N_NODES + 1) / 2), dim3(128), 0, stream,
                               ibase, src_s, logit, xl, cbias_l, h);
        } else {
            hipLaunchKernelGGL(init_mx_den_kernel, dim3((N_NODES * HEADS + 255) / 256), dim3(256),
                               0, stream, mx, den);
            if (mode == 2) {
                hipLaunchKernelGGL((att_logit6_kernel<8>), dim3(EF / 8), dim3(HID), 0, stream,
                                   ea32, loop_attr, cWe_l, catt_l, xl, xr, ei_src, ei_dst,
                                   logit, mx);
            } else {
                hipLaunchKernelGGL((att_logit7_kernel<8>), dim3(EF / 8), dim3(HID), 0, stream,
                                   edge_attr, eW, eb, eg, ebe, stat, loop_attr,
                                   cWe_l, catt_l, xl, xr, ei_src, ei_dst, logit, mx);
            }
            hipLaunchKernelGGL(softmax_norm_kernel,
                               dim3((int)(((long)EF * HEADS + 255) / 256)), dim3(256), 0, stream,
                               ei_dst, mx, logit, den);
            hipLaunchKernelGGL(zero_kernel, dim3(1024), dim3(256), 0, stream,
                               aggout, (long)N_NODES * HID);
            hipLaunchKernelGGL(aggregate_kernel,
                               dim3((int)(((long)EF * HID + 255) / 256)), dim3(256), 0, stream,
                               logit, den, xl, ei_src, ei_dst, aggout);
            hipLaunchKernelGGL(residual_kernel, dim3((N_NODES * HID + 255) / 256), dim3(256), 0,
                               stream, aggout, cbias_l, h);
        }
    }

    // 6. noise head
    hipLaunchKernelGGL((gemm_kernel<HID, 8>), dim3(N_NODES / 8), dim3(HID), 0, stream,
                       h, nW1, nb1, tmp1, N_NODES, HID);
    hipLaunchKernelGGL(ln_gelu_kernel, dim3(N_NODES), dim3(HID), 0, stream,
                       tmp1, ng, nbe, (const float*)nullptr, (const int*)nullptr);
    hipLaunchKernelGGL((gemm_kernel<NODE_OUT, 8>), dim3(N_NODES / 8), dim3(NODE_OUT), 0, stream,
                       tmp1, nW2, nb2, pred_noise, N_NODES, HID);

    // 7. pooling + props head
    hipLaunchKernelGGL(zero_kernel, dim3(4), dim3(256), 0, stream,
                       gsum, (long)N_GRAPHS * HID);
    hipLaunchKernelGGL(zero_kernel, dim3(1), dim3(64), 0, stream, gcnt, (long)N_GRAPHS);
    hipLaunchKernelGGL(pool_kernel, dim3((N_NODES + POOL_NODES - 1) / POOL_NODES), dim3(HID), 0,
                       stream, h, batch, gsum, gcnt);
    hipLaunchKernelGGL(props_kernel, dim3(N_GRAPHS), dim3(HID), 0, stream,
                       gsum, gcnt, pW1, pb1, pg, pbe, pW2, pb2, pred_props);
}

// Round 14
// 1636.516 us; speedup vs baseline: 1.9844x; 1.1314x over previous
//
#include <hip/hip_runtime.h>
#include <hip/hip_fp16.h>
#include <math.h>

#define N_NODES 30000
#define N_EDGES 480000
#define N_GRAPHS 16
#define HID 128
#define HEADS 8
#define HEAD_DIM 16
#define NODE_IN 64
#define EDGE_IN 32
#define COND 8
#define NODE_OUT 64
#define NLAYERS 4
#define EF (N_EDGES + N_NODES) /* 510000 */
#define LN_EPS 1e-5f

typedef _Float16 v8hf __attribute__((ext_vector_type(8)));
typedef float v4f __attribute__((ext_vector_type(4)));

__device__ __forceinline__ float gelu_f(float x) {
    return 0.5f * x * (1.0f + erff(x * 0.70710678118654752440f));
}

__device__ __forceinline__ void atomicMaxF(float* addr, float val) {
    if (val >= 0.0f) {
        atomicMax((int*)addr, __float_as_int(val));
    } else {
        atomicMin((unsigned int*)addr, __float_as_uint(val));
    }
}

// ---------- generic zero ----------
__global__ void zero_kernel(float* __restrict__ p, long n) {
    long i = (long)blockIdx.x * blockDim.x + threadIdx.x;
    long stride = (long)gridDim.x * blockDim.x;
    for (; i < n; i += stride) p[i] = 0.0f;
}

// ---------- time MLP ----------
__global__ void time_mlp_kernel(const float* __restrict__ t,
                                const float* __restrict__ tW1, const float* __restrict__ tb1,
                                const float* __restrict__ tW2, const float* __restrict__ tb2,
                                float* __restrict__ t_emb) {
    __shared__ float hsh[HID];
    int b = blockIdx.x, j = threadIdx.x;
    float tv = t[b];
    hsh[j] = gelu_f(tv * tW1[j] + tb1[j]);
    __syncthreads();
    float acc = tb2[j];
    for (int k = 0; k < HID; ++k) acc += hsh[k] * tW2[k * HID + j];
    t_emb[b * HID + j] = acc;
}

// ---------- concat ----------
__global__ void concat_kernel(const float* __restrict__ x, const float* __restrict__ cond,
                              const int* __restrict__ batch, float* __restrict__ xc) {
    int idx = blockIdx.x * blockDim.x + threadIdx.x;
    if (idx >= N_NODES * 72) return;
    int n = idx / 72, c = idx % 72;
    xc[idx] = (c < NODE_IN) ? x[n * NODE_IN + c] : cond[batch[n] * COND + (c - NODE_IN)];
}

// ---------- generic GEMM ----------
template <int NCOL, int R>
__global__ void gemm_kernel(const float* __restrict__ A, const float* __restrict__ B,
                            const float* __restrict__ bias, float* __restrict__ C,
                            int M, int K) {
    __shared__ __align__(16) float sh[R * HID];
    int j = threadIdx.x;
    int row0 = blockIdx.x * R;
    int total = R * K;
    for (int i = j; i < total; i += NCOL) {
        int r = i / K, k = i - r * K;
        int row = row0 + r;
        sh[r * K + k] = (row < M) ? A[(long)row * K + k] : 0.0f;
    }
    __syncthreads();
    float acc[R];
    float bv = bias ? bias[j] : 0.0f;
#pragma unroll
    for (int r = 0; r < R; ++r) acc[r] = bv;
    int KB = K >> 2;
    for (int kb = 0; kb < KB; ++kb) {
        float w0 = B[(kb * 4 + 0) * NCOL + j];
        float w1 = B[(kb * 4 + 1) * NCOL + j];
        float w2 = B[(kb * 4 + 2) * NCOL + j];
        float w3 = B[(kb * 4 + 3) * NCOL + j];
#pragma unroll
        for (int r = 0; r < R; ++r) {
            float4 a = *(const float4*)&sh[r * K + kb * 4];
            acc[r] += a.x * w0 + a.y * w1 + a.z * w2 + a.w * w3;
        }
    }
#pragma unroll
    for (int r = 0; r < R; ++r) {
        int row = row0 + r;
        if (row < M) C[(long)row * NCOL + j] = acc[r];
    }
}

// ---------- fused dual GEMM ----------
template <int R>
__global__ void gemm2_kernel(const float* __restrict__ A,
                             const float* __restrict__ Bl, const float* __restrict__ bl,
                             const float* __restrict__ Br, const float* __restrict__ br,
                             float* __restrict__ Cl, float* __restrict__ Cr, int M) {
    __shared__ __align__(16) float sh[R * HID];
    int j = threadIdx.x;
    int row0 = blockIdx.x * R;
    for (int i = j; i < R * HID; i += HID) {
        int r = i >> 7, k = i & 127;
        int row = row0 + r;
        sh[i] = (row < M) ? A[(long)row * HID + k] : 0.0f;
    }
    __syncthreads();
    float accl[R], accr[R];
    float blv = bl[j], brv = br[j];
#pragma unroll
    for (int r = 0; r < R; ++r) { accl[r] = blv; accr[r] = brv; }
    for (int kb = 0; kb < HID / 4; ++kb) {
        float l0 = Bl[(kb * 4 + 0) * HID + j];
        float l1 = Bl[(kb * 4 + 1) * HID + j];
        float l2 = Bl[(kb * 4 + 2) * HID + j];
        float l3 = Bl[(kb * 4 + 3) * HID + j];
        float r0 = Br[(kb * 4 + 0) * HID + j];
        float r1 = Br[(kb * 4 + 1) * HID + j];
        float r2 = Br[(kb * 4 + 2) * HID + j];
        float r3 = Br[(kb * 4 + 3) * HID + j];
#pragma unroll
        for (int r = 0; r < R; ++r) {
            float4 a = *(const float4*)&sh[r * HID + kb * 4];
            accl[r] += a.x * l0 + a.y * l1 + a.z * l2 + a.w * l3;
            accr[r] += a.x * r0 + a.y * r1 + a.z * r2 + a.w * r3;
        }
    }
#pragma unroll
    for (int r = 0; r < R; ++r) {
        int row = row0 + r;
        if (row < M) {
            Cl[(long)row * HID + j] = accl[r];
            Cr[(long)row * HID + j] = accr[r];
        }
    }
}

// ---------- in-place LayerNorm + GELU ----------
__global__ void ln_gelu_kernel(float* __restrict__ X, const float* __restrict__ g,
                               const float* __restrict__ bta,
                               const float* __restrict__ t_emb, const int* __restrict__ batch) {
    int row = blockIdx.x, j = threadIdx.x;
    __shared__ float red[HID];
    float v = X[(long)row * HID + j];
    red[j] = v;
    __syncthreads();
    for (int s = 64; s > 0; s >>= 1) { if (j < s) red[j] += red[j + s]; __syncthreads(); }
    float mean = red[0] * (1.0f / HID);
    __syncthreads();
    float d = v - mean;
    red[j] = d * d;
    __syncthreads();
    for (int s = 64; s > 0; s >>= 1) { if (j < s) red[j] += red[j + s]; __syncthreads(); }
    float var = red[0] * (1.0f / HID);
    float y = gelu_f(d * rsqrtf(var + LN_EPS) * g[j] + bta[j]);
    if (t_emb) y += t_emb[batch[row] * HID + j];
    X[(long)row * HID + j] = y;
}

// ================= CSR sort setup (mode 1) =================
__global__ void hist_kernel(const int* __restrict__ ei_dst, int* __restrict__ ibase) {
    int idx = blockIdx.x * blockDim.x + threadIdx.x;
    if (idx >= EF) return;
    int d = (idx < N_EDGES) ? ei_dst[idx] : (idx - N_EDGES);
    atomicAdd(&ibase[d + 1], 1);
}

__global__ __launch_bounds__(1024) void scan_kernel(int* __restrict__ ibase) {
    __shared__ int wsums[16];
    __shared__ int s_carry;
    int t = threadIdx.x, lane = t & 63, w = t >> 6;
    if (t == 0) s_carry = 0;
    __syncthreads();
    for (int start = 0; start < N_NODES; start += 1024) {
        int i = start + t;
        int v = (i < N_NODES) ? ibase[i + 1] : 0;
        int x = v;
#pragma unroll
        for (int m = 1; m < 64; m <<= 1) {
            int y = __shfl_up(x, m);
            if (lane >= m) x += y;
        }
        if (lane == 63) wsums[w] = x;
        __syncthreads();
        if (w == 0 && lane < 16) {
            int ws = wsums[lane];
#pragma unroll
            for (int m = 1; m < 16; m <<= 1) {
                int y = __shfl_up(ws, m);
                if (lane >= m) ws += y;
            }
            wsums[lane] = ws;
        }
        __syncthreads();
        int waveoff = (w == 0) ? 0 : wsums[w - 1];
        int incl = x + waveoff + s_carry;
        if (i < N_NODES) ibase[i + 1] = incl;
        __syncthreads();
        if (t == 1023) s_carry = incl;
        __syncthreads();
    }
}

__global__ void scatter_kernel(const int* __restrict__ ei_src, const int* __restrict__ ei_dst,
                               const int* __restrict__ ibase, int* __restrict__ icursor,
                               int* __restrict__ src_s, int* __restrict__ dst_s,
                               int* __restrict__ inv) {
    int idx = blockIdx.x * blockDim.x + threadIdx.x;
    if (idx >= EF) return;
    int s, d;
    if (idx < N_EDGES) { s = ei_src[idx]; d = ei_dst[idx]; }
    else               { s = d = idx - N_EDGES; }
    int pos = ibase[d] + atomicAdd(&icursor[d], 1);
    src_s[pos] = s;
    dst_s[pos] = d;
    inv[idx] = pos;
}

// ---------- prep: pack cWe into MFMA B-fragment layout ----------
// Bp[l][cg][kt][lane] (uint4 = 8 halves): j-th half = cWe[l][kt*32 + (lane>>4)*8 + j][cg*16 + (lane&15)]
__global__ void prep_bp_kernel(const float* __restrict__ cWe, uint4* __restrict__ Bp) {
    int idx = blockIdx.x * blockDim.x + threadIdx.x;
    if (idx >= NLAYERS * 8 * 4 * 64) return;
    int l = idx >> 11;
    int rem = idx & 2047;
    int cg = rem >> 8;
    int kt = (rem >> 6) & 3;
    int lane = rem & 63;
    int c = cg * 16 + (lane & 15);
    int kbase = kt * 32 + (lane >> 4) * 8;
    __half hh[8];
#pragma unroll
    for (int j = 0; j < 8; ++j)
        hh[j] = __float2half(cWe[(size_t)l * HID * HID + (size_t)(kbase + j) * HID + c]);
    Bp[idx] = *(const uint4*)hh;
}

// ---------- CSR loop-mean ----------
__global__ __launch_bounds__(128) void csr_loop_mean_kernel(
        const int* __restrict__ ibase, const int* __restrict__ inv,
        __half* __restrict__ ea16) {
    int w = threadIdx.x >> 6, lane = threadIdx.x & 63;
    int d = blockIdx.x * 2 + w;
    if (d >= N_NODES) return;
    int b0 = ibase[d], b1 = ibase[d + 1];
    int selfpos = inv[N_EDGES + d];
    float a0 = 0.0f, a1 = 0.0f;
    for (int i = b0; i < b1; ++i) {
        if (i == selfpos) continue;
        a0 += __half2float(ea16[(long)i * HID + lane]);
        a1 += __half2float(ea16[(long)i * HID + lane + 64]);
    }
    float c = fmaxf((float)(b1 - b0 - 1), 1.0f);
    ea16[(long)selfpos * HID + lane]      = __float2half(a0 / c);
    ea16[(long)selfpos * HID + lane + 64] = __float2half(a1 / c);
}

// ---------- fallback (modes 0/2): edge-encode + segment-sum, LDS-tree LN ----------
template <int R, int MODE>
__global__ void edge_enc_loop_kernel(const float* __restrict__ edge_attr,
                                     const float* __restrict__ eW, const float* __restrict__ eb,
                                     const float* __restrict__ eg, const float* __restrict__ ebe,
                                     const int* __restrict__ ei_dst,
                                     float* __restrict__ loop_sum, float* __restrict__ cnt,
                                     float* __restrict__ stat,
                                     float* __restrict__ ea32, __half* __restrict__ ea16) {
    __shared__ float red[R * HID];
    __shared__ __align__(16) float sattr[R * EDGE_IN];
    __shared__ int sdst[R];
    int j = threadIdx.x;
    long e0 = (long)blockIdx.x * R;
    if (j < R * EDGE_IN / 4)
        ((float4*)sattr)[j] = ((const float4*)(edge_attr + e0 * EDGE_IN))[j];
    if (j < R) sdst[j] = ei_dst[e0 + j];
    __syncthreads();
    float val[R];
    float ebv = eb[j];
#pragma unroll
    for (int r = 0; r < R; ++r) val[r] = ebv;
#pragma unroll
    for (int kb = 0; kb < EDGE_IN / 4; ++kb) {
        float w0 = eW[(kb * 4 + 0) * HID + j];
        float w1 = eW[(kb * 4 + 1) * HID + j];
        float w2 = eW[(kb * 4 + 2) * HID + j];
        float w3 = eW[(kb * 4 + 3) * HID + j];
#pragma unroll
        for (int r = 0; r < R; ++r) {
            float4 a = *(const float4*)&sattr[r * EDGE_IN + kb * 4];
            val[r] += a.x * w0 + a.y * w1 + a.z * w2 + a.w * w3;
        }
    }
#pragma unroll
    for (int r = 0; r < R; ++r) red[r * HID + j] = val[r];
    __syncthreads();
    for (int s = 64; s > 0; s >>= 1) {
        if (j < s) {
#pragma unroll
            for (int r = 0; r < R; ++r) red[r * HID + j] += red[r * HID + j + s];
        }
        __syncthreads();
    }
    float mean[R];
#pragma unroll
    for (int r = 0; r < R; ++r) mean[r] = red[r * HID] * (1.0f / HID);
    __syncthreads();
#pragma unroll
    for (int r = 0; r < R; ++r) { float d = val[r] - mean[r]; red[r * HID + j] = d * d; }
    __syncthreads();
    for (int s = 64; s > 0; s >>= 1) {
        if (j < s) {
#pragma unroll
            for (int r = 0; r < R; ++r) red[r * HID + j] += red[r * HID + j + s];
        }
        __syncthreads();
    }
    float egv = eg[j], bev = ebe[j];
#pragma unroll
    for (int r = 0; r < R; ++r) {
        float var = red[r * HID] * (1.0f / HID);
        float rstd = rsqrtf(var + LN_EPS);
        float y = gelu_f((val[r] - mean[r]) * rstd * egv + bev);
        int d = sdst[r];
        long e = e0 + r;
        if (j == 0) { stat[e * 2] = mean[r]; stat[e * 2 + 1] = rstd; }
        if (MODE == 2) ea32[e * HID + j] = y;
        if (MODE == 1) ea16[e * HID + j] = __float2half(y);
        atomicAdd(&loop_sum[(long)d * HID + j], y);
        if (j == 0) atomicAdd(&cnt[d], 1.0f);
    }
}

// ---------- mode-1 MAIN enc: wave-owns-rows, shfl LN, fp16 ea to sorted pos, NO atomics ----------
__global__ __launch_bounds__(128) void edge_enc_loop_w_kernel(
        const float* __restrict__ edge_attr,
        const float* __restrict__ eW, const float* __restrict__ eb,
        const float* __restrict__ eg, const float* __restrict__ ebe,
        const int* __restrict__ inv,
        __half* __restrict__ ea16) {
    const int R = 8;
    __shared__ __align__(16) float sattr[R * EDGE_IN];
    __shared__ int spos[R];
    int t = threadIdx.x;
    long e0 = (long)blockIdx.x * R;
    if (t < R * EDGE_IN / 4)
        ((float4*)sattr)[t] = ((const float4*)(edge_attr + e0 * EDGE_IN))[t];
    if (t < R) spos[t] = inv[e0 + t];
    __syncthreads();
    int lane = t & 63, w = t >> 6;
    int r0 = w * 4;
    int j1 = lane, j2 = lane + 64;
    float eb1 = eb[j1], eb2 = eb[j2];
    float v0[4], v1[4];
#pragma unroll
    for (int q = 0; q < 4; ++q) { v0[q] = eb1; v1[q] = eb2; }
#pragma unroll
    for (int kb = 0; kb < EDGE_IN / 4; ++kb) {
        float w10 = eW[(kb * 4 + 0) * HID + j1];
        float w11 = eW[(kb * 4 + 1) * HID + j1];
        float w12 = eW[(kb * 4 + 2) * HID + j1];
        float w13 = eW[(kb * 4 + 3) * HID + j1];
        float w20 = eW[(kb * 4 + 0) * HID + j2];
        float w21 = eW[(kb * 4 + 1) * HID + j2];
        float w22 = eW[(kb * 4 + 2) * HID + j2];
        float w23 = eW[(kb * 4 + 3) * HID + j2];
#pragma unroll
        for (int q = 0; q < 4; ++q) {
            float4 a = *(const float4*)&sattr[(r0 + q) * EDGE_IN + kb * 4];
            v0[q] += a.x * w10 + a.y * w11 + a.z * w12 + a.w * w13;
            v1[q] += a.x * w20 + a.y * w21 + a.z * w22 + a.w * w23;
        }
    }
    float eg1 = eg[j1], eg2 = eg[j2];
    float be1 = ebe[j1], be2 = ebe[j2];
#pragma unroll
    for (int q = 0; q < 4; ++q) {
        float s1 = v0[q] + v1[q];
        float s2 = v0[q] * v0[q] + v1[q] * v1[q];
#pragma unroll
        for (int m = 1; m < 64; m <<= 1) {
            s1 += __shfl_xor(s1, m);
            s2 += __shfl_xor(s2, m);
        }
        float mean = s1 * (1.0f / 128.0f);
        float var = s2 * (1.0f / 128.0f) - mean * mean;
        float rstd = rsqrtf(var + LN_EPS);
        float y0 = gelu_f((v0[q] - mean) * rstd * eg1 + be1);
        float y1 = gelu_f((v1[q] - mean) * rstd * eg2 + be2);
        long pos = spos[r0 + q];
        ea16[pos * HID + j1] = __float2half(y0);
        ea16[pos * HID + j2] = __float2half(y1);
    }
}

__global__ void loop_div_kernel(float* __restrict__ loop_attr, const float* __restrict__ cnt) {
    int idx = blockIdx.x * blockDim.x + threadIdx.x;
    if (idx >= N_NODES * HID) return;
    int n = idx >> 7;
    loop_attr[idx] = loop_attr[idx] / fmaxf(cnt[n], 1.0f);
}

// ---------- init mx=-inf, den=0 (modes 0/2) ----------
__global__ void init_mx_den_kernel(float* __restrict__ mx, float* __restrict__ den) {
    int idx = blockIdx.x * blockDim.x + threadIdx.x;
    if (idx >= N_NODES * HEADS) return;
    mx[idx] = -INFINITY;
    den[idx] = 0.0f;
}

// ---------- shared epilogue (fallback variants) ----------
template <int R>
__device__ __forceinline__ void em_logit_body(
        const float* __restrict__ sh, const int* __restrict__ ssrc, const int* __restrict__ sdst,
        const float* __restrict__ cWe_l, const float* __restrict__ catt_l,
        const float* __restrict__ xl, const float* __restrict__ xr,
        float* __restrict__ logit, float* __restrict__ mx, long e0, int j) {
    float acc[R];
#pragma unroll
    for (int r = 0; r < R; ++r) acc[r] = 0.0f;
    for (int kb = 0; kb < HID / 4; ++kb) {
        float w0 = cWe_l[(kb * 4 + 0) * HID + j];
        float w1 = cWe_l[(kb * 4 + 1) * HID + j];
        float w2 = cWe_l[(kb * 4 + 2) * HID + j];
        float w3 = cWe_l[(kb * 4 + 3) * HID + j];
#pragma unroll
        for (int r = 0; r < R; ++r) {
            float4 a = *(const float4*)&sh[r * HID + kb * 4];
            acc[r] += a.x * w0 + a.y * w1 + a.z * w2 + a.w * w3;
        }
    }
    float cj = catt_l[j];
    int head = j >> 4;
#pragma unroll
    for (int r = 0; r < R; ++r) {
        long e = e0 + r;
        int s = ssrc[r], d = sdst[r];
        float m = xl[(long)s * HID + j] + xr[(long)d * HID + j] + acc[r];
        m = (m > 0.0f) ? m : 0.2f * m;
        float p = m * cj;
        p += __shfl_down(p, 8, 16);
        p += __shfl_down(p, 4, 16);
        p += __shfl_down(p, 2, 16);
        p += __shfl_down(p, 1, 16);
        if ((j & 15) == 0) {
            logit[e * HEADS + head] = p;
            atomicMaxF(&mx[(long)d * HEADS + head], p);
        }
    }
}

// ---------- att kernel, mode 0 fallback ----------
template <int R>
__global__ void att_logit7_kernel(const float* __restrict__ edge_attr,
                                  const float* __restrict__ eW, const float* __restrict__ eb,
                                  const float* __restrict__ eg, const float* __restrict__ ebe,
                                  const float* __restrict__ stat,
                                  const float* __restrict__ loop_attr,
                                  const float* __restrict__ cWe_l, const float* __restrict__ catt_l,
                                  const float* __restrict__ xl, const float* __restrict__ xr,
                                  const int* __restrict__ ei_src, const int* __restrict__ ei_dst,
                                  float* __restrict__ logit, float* __restrict__ mx) {
    __shared__ __align__(16) float sh[R * HID];
    __shared__ __align__(16) float sattr[R * EDGE_IN];
    __shared__ float sstat[R * 2];
    __shared__ int ssrc[R], sdst[R];
    int j = threadIdx.x;
    long e0 = (long)blockIdx.x * R;
    bool realblk = (e0 < N_EDGES);

    if (realblk) {
        if (j < R * EDGE_IN / 4)
            ((float4*)sattr)[j] = ((const float4*)(edge_attr + e0 * EDGE_IN))[j];
        if (j < R * 2) sstat[j] = stat[e0 * 2 + j];
        if (j < R) { ssrc[j] = ei_src[e0 + j]; sdst[j] = ei_dst[e0 + j]; }
    } else {
        if (j < R) ssrc[j] = sdst[j] = (int)(e0 + j - N_EDGES);
    }
    __syncthreads();

    if (realblk) {
        float val[R];
        float ebv = eb[j];
#pragma unroll
        for (int r = 0; r < R; ++r) val[r] = ebv;
#pragma unroll
        for (int kb = 0; kb < EDGE_IN / 4; ++kb) {
            float w0 = eW[(kb * 4 + 0) * HID + j];
            float w1 = eW[(kb * 4 + 1) * HID + j];
            float w2 = eW[(kb * 4 + 2) * HID + j];
            float w3 = eW[(kb * 4 + 3) * HID + j];
#pragma unroll
            for (int r = 0; r < R; ++r) {
                float4 a = *(const float4*)&sattr[r * EDGE_IN + kb * 4];
                val[r] += a.x * w0 + a.y * w1 + a.z * w2 + a.w * w3;
            }
        }
        float egv = eg[j], bev = ebe[j];
#pragma unroll
        for (int r = 0; r < R; ++r) {
            float mean = sstat[r * 2], rstd = sstat[r * 2 + 1];
            sh[r * HID + j] = gelu_f((val[r] - mean) * rstd * egv + bev);
        }
    } else {
#pragma unroll
        for (int r = 0; r < R; ++r)
            sh[r * HID + j] = loop_attr[(long)(e0 + r - N_EDGES) * HID + j];
    }
    __syncthreads();
    em_logit_body<R>(sh, ssrc, sdst, cWe_l, catt_l, xl, xr, logit, mx, e0, j);
}

// ---------- att kernel, mode 2 fallback ----------
template <int R>
__global__ void att_logit6_kernel(const float* __restrict__ ea,
                                  const float* __restrict__ loop_attr,
                                  const float* __restrict__ cWe_l, const float* __restrict__ catt_l,
                                  const float* __restrict__ xl, const float* __restrict__ xr,
                                  const int* __restrict__ ei_src, const int* __restrict__ ei_dst,
                                  float* __restrict__ logit, float* __restrict__ mx) {
    __shared__ __align__(16) float sh[R * HID];
    __shared__ int ssrc[R], sdst[R];
    int j = threadIdx.x;
    long e0 = (long)blockIdx.x * R;
    bool realblk = (e0 < N_EDGES);
    const float* srcp = realblk ? (ea + e0 * HID) : (loop_attr + (e0 - N_EDGES) * HID);
    const float4* s4 = (const float4*)srcp;
    ((float4*)sh)[j]       = s4[j];
    ((float4*)sh)[j + HID] = s4[j + HID];
    if (j < R) {
        long e = e0 + j;
        if (realblk) { ssrc[j] = ei_src[e]; sdst[j] = ei_dst[e]; }
        else         { ssrc[j] = sdst[j] = (int)(e - N_EDGES); }
    }
    __syncthreads();
    em_logit_body<R>(sh, ssrc, sdst, cWe_l, catt_l, xl, xr, logit, mx, e0, j);
}

// ---------- att kernel, mode 1 MAIN: MFMA 16x16x32_f16 on sorted fp16 ea ----------
// Block: 256 threads = 4 waves; wave w handles edges e0+16w..+15 (16-edge x 128-col tile).
// A-frag: lane l holds ea[row=e0w+(l&15)][k=(l>>4)*8..+8) per k-tile -> one uint4 global load.
// B-frag: prepacked Bp[cg][kt][lane] (8 halves along k, col = cg*16+(l&15)).
// C/D: col=lane&15, row=(lane>>4)*4+reg (HW-verified) -> head reduce = 4 shfl_xor in 16 lanes;
// col-group cg == head (HEAD_DIM=16).
__global__ __launch_bounds__(256) void att_logit12m_kernel(
        const __half* __restrict__ ea,          /* sorted [EF,128] */
        const int* __restrict__ src_s, const int* __restrict__ dst_s,
        const uint4* __restrict__ Bp_l,         /* [8][4][64] uint4 */
        const float* __restrict__ catt_l,
        const float* __restrict__ xl, const float* __restrict__ xr,
        float* __restrict__ logit) {
    int t = threadIdx.x;
    int w = t >> 6, lane = t & 63;
    long e0 = (long)blockIdx.x * 64 + (long)w * 16;
    if (e0 >= (long)EF) return;
    int row = lane & 15, ks = lane >> 4;

    uint4 A[4];
#pragma unroll
    for (int kt = 0; kt < 4; ++kt)
        A[kt] = *(const uint4*)&ea[(e0 + row) * HID + kt * 32 + ks * 8];

#pragma unroll
    for (int cg = 0; cg < 8; ++cg) {
        v4f acc = {0.0f, 0.0f, 0.0f, 0.0f};
#pragma unroll
        for (int kt = 0; kt < 4; ++kt) {
            uint4 B = Bp_l[(cg * 4 + kt) * 64 + lane];
            acc = __builtin_amdgcn_mfma_f32_16x16x32_f16(
                __builtin_bit_cast(v8hf, A[kt]), __builtin_bit_cast(v8hf, B), acc, 0, 0, 0);
        }
        int c = cg * 16 + row;
        float cj = catt_l[c];
#pragma unroll
        for (int q = 0; q < 4; ++q) {
            int r = ks * 4 + q;
            long e = e0 + r;
            int s = src_s[e], d = dst_s[e];
            float m = xl[(long)s * HID + c] + xr[(long)d * HID + c] + acc[q];
            m = (m > 0.0f) ? m : 0.2f * m;
            float p = m * cj;
            p += __shfl_xor(p, 1);
            p += __shfl_xor(p, 2);
            p += __shfl_xor(p, 4);
            p += __shfl_xor(p, 8);
            if (row == 0) logit[e * HEADS + cg] = p;
        }
    }
}

// ---------- CSR fused softmax + aggregate + residual (mode 1) ----------
__global__ __launch_bounds__(128) void csr_smax_agg_kernel(
        const int* __restrict__ ibase, const int* __restrict__ src_s,
        const float* __restrict__ logit, const float* __restrict__ xl,
        const float* __restrict__ cbias_l, float* __restrict__ h) {
    int w = threadIdx.x >> 6, lane = threadIdx.x & 63;
    int d = blockIdx.x * 2 + w;
    if (d >= N_NODES) return;
    int b0 = ibase[d], b1 = ibase[d + 1];
    int hh = lane & 7, g = lane >> 3;
    float m = -INFINITY;
    for (int i = b0 + g; i < b1; i += 8) m = fmaxf(m, logit[(long)i * 8 + hh]);
    m = fmaxf(m, __shfl_xor(m, 8));
    m = fmaxf(m, __shfl_xor(m, 16));
    m = fmaxf(m, __shfl_xor(m, 32));
    float den = 0.0f;
    for (int i = b0 + g; i < b1; i += 8) den += expf(logit[(long)i * 8 + hh] - m);
    den += __shfl_xor(den, 8);
    den += __shfl_xor(den, 16);
    den += __shfl_xor(den, 32);
    int h1 = lane >> 4, h2 = 4 + (lane >> 4);
    float mx1 = __shfl(m, h1), mx2 = __shfl(m, h2);
    float dn1 = __shfl(den, h1) + 1e-16f, dn2 = __shfl(den, h2) + 1e-16f;
    float acc0 = 0.0f, acc1 = 0.0f;
    for (int i = b0; i < b1; ++i) {
        int s = src_s[i];
        float a0 = expf(logit[(long)i * 8 + h1] - mx1) / dn1;
        float a1 = expf(logit[(long)i * 8 + h2] - mx2) / dn2;
        acc0 += a0 * xl[(long)s * HID + lane];
        acc1 += a1 * xl[(long)s * HID + lane + 64];
    }
    long o = (long)d * HID + lane;
    h[o]      = gelu_f(acc0 + cbias_l[lane])      + h[o];
    h[o + 64] = gelu_f(acc1 + cbias_l[lane + 64]) + h[o + 64];
}

// ---------- fallback chain kernels (modes 0/2) ----------
__global__ void softmax_norm_kernel(const int* __restrict__ ei_dst, const float* __restrict__ mx,
                                    float* __restrict__ logit, float* __restrict__ den) {
    long idx = (long)blockIdx.x * blockDim.x + threadIdx.x;
    if (idx >= (long)EF * HEADS) return;
    long e = idx >> 3;
    int hh = (int)(idx & 7);
    int d = (e < N_EDGES) ? ei_dst[e] : (int)(e - N_EDGES);
    float ex = expf(logit[idx] - mx[(long)d * HEADS + hh]);
    logit[idx] = ex;
    atomicAdd(&den[(long)d * HEADS + hh], ex);
}

__global__ void aggregate_kernel(const float* __restrict__ logit, const float* __restrict__ den,
                                 const float* __restrict__ xl,
                                 const int* __restrict__ ei_src, const int* __restrict__ ei_dst,
                                 float* __restrict__ aggout) {
    long idx = (long)blockIdx.x * blockDim.x + threadIdx.x;
    if (idx >= (long)EF * HID) return;
    long e = idx >> 7;
    int j = (int)(idx & 127);
    int s, d;
    if (e < N_EDGES) { s = ei_src[e]; d = ei_dst[e]; }
    else             { s = d = (int)(e - N_EDGES); }
    int head = j >> 4;
    float alpha = logit[e * HEADS + head] / (den[(long)d * HEADS + head] + 1e-16f);
    atomicAdd(&aggout[(long)d * HID + j], alpha * xl[(long)s * HID + j]);
}

__global__ void residual_kernel(const float* __restrict__ aggout, const float* __restrict__ cbias_l,
                                float* __restrict__ h) {
    int idx = blockIdx.x * blockDim.x + threadIdx.x;
    if (idx >= N_NODES * HID) return;
    int j = idx & 127;
    h[idx] = gelu_f(aggout[idx] + cbias_l[j]) + h[idx];
}

// ---------- pooling ----------
#define POOL_NODES 64
__global__ void pool_kernel(const float* __restrict__ h, const int* __restrict__ batch,
                            float* __restrict__ gsum, float* __restrict__ gcnt) {
    __shared__ float acc[N_GRAPHS][HID];
    __shared__ float cnt_sh[N_GRAPHS];
    int j = threadIdx.x;
    for (int g = 0; g < N_GRAPHS; ++g) acc[g][j] = 0.0f;
    if (j < N_GRAPHS) cnt_sh[j] = 0.0f;
    __syncthreads();
    int n0 = blockIdx.x * POOL_NODES;
    for (int i = 0; i < POOL_NODES; ++i) {
        int n = n0 + i;
        if (n >= N_NODES) break;
        int g = batch[n];
        acc[g][j] += h[(long)n * HID + j];
        if (j == 0) cnt_sh[g] += 1.0f;
    }
    __syncthreads();
    for (int g = 0; g < N_GRAPHS; ++g) atomicAdd(&gsum[g * HID + j], acc[g][j]);
    if (j < N_GRAPHS) atomicAdd(&gcnt[j], cnt_sh[j]);
}

// ---------- props head ----------
__global__ void props_kernel(const float* __restrict__ gsum, const float* __restrict__ gcnt,
                             const float* __restrict__ pW1, const float* __restrict__ pb1,
                             const float* __restrict__ pg, const float* __restrict__ pbe,
                             const float* __restrict__ pW2, const float* __restrict__ pb2,
                             float* __restrict__ out_props) {
    int g = blockIdx.x, j = threadIdx.x;
    __shared__ float feat[HID], red[HID], t2[HID];
    float c = fmaxf(gcnt[g], 1.0f);
    feat[j] = gsum[g * HID + j] / c;
    __syncthreads();
    float acc = pb1[j];
    for (int k = 0; k < HID; ++k) acc += feat[k] * pW1[k * HID + j];
    red[j] = acc;
    __syncthreads();
    for (int s = 64; s > 0; s >>= 1) { if (j < s) red[j] += red[j + s]; __syncthreads(); }
    float mean = red[0] * (1.0f / HID);
    __syncthreads();
    float dd = acc - mean;
    red[j] = dd * dd;
    __syncthreads();
    for (int s = 64; s > 0; s >>= 1) { if (j < s) red[j] += red[j + s]; __syncthreads(); }
    float var = red[0] * (1.0f / HID);
    t2[j] = gelu_f(dd * rsqrtf(var + LN_EPS) * pg[j] + pbe[j]);
    __syncthreads();
    if (j < COND) {
        float a = pb2[j];
        for (int k = 0; k < HID; ++k) a += t2[k] * pW2[k * COND + j];
        out_props[g * COND + j] = a;
    }
}

extern "C" void kernel_launch(void* const* d_in, const int* in_sizes, int n_in,
                              void* d_out, int out_size, void* d_ws, size_t ws_size,
                              hipStream_t stream) {
    const float* x        = (const float*)d_in[0];
    const float* edge_attr= (const float*)d_in[1];
    const float* t        = (const float*)d_in[2];
    const float* conds    = (const float*)d_in[3];
    const float* tW1      = (const float*)d_in[4];
    const float* tb1      = (const float*)d_in[5];
    const float* tW2      = (const float*)d_in[6];
    const float* tb2      = (const float*)d_in[7];
    const float* encW     = (const float*)d_in[8];
    const float* encb     = (const float*)d_in[9];
    const float* encg     = (const float*)d_in[10];
    const float* encbe    = (const float*)d_in[11];
    const float* eW       = (const float*)d_in[12];
    const float* eb       = (const float*)d_in[13];
    const float* eg       = (const float*)d_in[14];
    const float* ebe      = (const float*)d_in[15];
    const float* cWl      = (const float*)d_in[16];
    const float* cbl      = (const float*)d_in[17];
    const float* cWr      = (const float*)d_in[18];
    const float* cbr      = (const float*)d_in[19];
    const float* cWe      = (const float*)d_in[20];
    const float* catt     = (const float*)d_in[21];
    const float* cbias    = (const float*)d_in[22];
    const float* nW1      = (const float*)d_in[23];
    const float* nb1      = (const float*)d_in[24];
    const float* ng       = (const float*)d_in[25];
    const float* nbe      = (const float*)d_in[26];
    const float* nW2      = (const float*)d_in[27];
    const float* nb2      = (const float*)d_in[28];
    const float* pW1      = (const float*)d_in[29];
    const float* pb1      = (const float*)d_in[30];
    const float* pg       = (const float*)d_in[31];
    const float* pbe      = (const float*)d_in[32];
    const float* pW2      = (const float*)d_in[33];
    const float* pb2      = (const float*)d_in[34];
    const int* edge_index = (const int*)d_in[35];
    const int* batch      = (const int*)d_in[36];
    const int* ei_src = edge_index;
    const int* ei_dst = edge_index + N_EDGES;

    // workspace: common + union(mode1 sort ints + Bp | mode0/2 stat+mx+den+aggout) + ea
    float* ws = (float*)d_ws;
    size_t off = 0;
    auto alloc = [&](size_t n) { float* p = ws + off; off += n; return p; };
    float* t_emb     = alloc((size_t)N_GRAPHS * HID);
    float* h         = alloc((size_t)N_NODES * HID);
    float* loop_attr = alloc((size_t)N_NODES * HID);
    float* cnt       = alloc((size_t)N_NODES);
    float* xl        = alloc((size_t)N_NODES * HID);
    float* xr        = alloc((size_t)N_NODES * HID);
    float* logit     = alloc((size_t)EF * HEADS);      // 4.08M floats
    float* gsum      = alloc((size_t)N_GRAPHS * HID);
    float* gcnt      = alloc((size_t)N_GRAPHS);
    // union region (5.28M float slots):
    float* uni = alloc((size_t)(960000 + 240000 + 240000 + (size_t)N_NODES * HID));
    // mode-0/2 view:
    float* stat   = uni;                  // [N_EDGES*2]
    float* mx     = uni + 960000;         // [N*8]
    float* den    = uni + 960000 + 240000;
    float* aggout = uni + 960000 + 480000; // [N*128]
    // mode-1 view (ints + MFMA-packed fp16 weights):
    int* ibase   = (int*)uni;                         // [N_NODES+1]
    int* icursor = ibase + (N_NODES + 1);             // [N_NODES]
    int* src_s   = icursor + N_NODES;                 // [EF]
    int* dst_s   = src_s + EF;                        // [EF]
    int* inv     = dst_s + EF;                        // [EF]
    uintptr_t bp_addr = (((uintptr_t)(inv + EF)) + 15) & ~(uintptr_t)15;
    uint4* Bp = (uint4*)bp_addr;                      // [NLAYERS][8][4][64] uint4 = 128KB
    size_t base_bytes = off * sizeof(float);
    float*  ea32 = ws + off;
    __half* ea16 = (__half*)(ws + off);
    int mode = 0;
    if (ws_size >= base_bytes + (size_t)EF * HID * sizeof(float)) mode = 2;
    else if (ws_size >= base_bytes + (size_t)EF * HID * sizeof(__half)) mode = 1;
    // aliases (disjoint lifetimes):
    float* xc   = logit;  // [N,72] used only pre-layers
    float* tmp1 = xl;     // used only post-layers
    (void)in_sizes; (void)n_in; (void)out_size;

    float* pred_noise = (float*)d_out;                              // [N,64]
    float* pred_props = (float*)d_out + (size_t)N_NODES * NODE_OUT; // [16,8]

    // 0. (mode 1) CSR sort of edges by dst + MFMA weight packing
    if (mode == 1) {
        hipLaunchKernelGGL(zero_kernel, dim3(64), dim3(256), 0, stream,
                           (float*)ibase, (long)(2 * N_NODES + 1));  // ibase + icursor
        hipLaunchKernelGGL(hist_kernel, dim3((EF + 255) / 256), dim3(256), 0, stream,
                           ei_dst, ibase);
        hipLaunchKernelGGL(scan_kernel, dim3(1), dim3(1024), 0, stream, ibase);
        hipLaunchKernelGGL(scatter_kernel, dim3((EF + 255) / 256), dim3(256), 0, stream,
                           ei_src, ei_dst, ibase, icursor, src_s, dst_s, inv);
        hipLaunchKernelGGL(prep_bp_kernel, dim3((NLAYERS * 8 * 4 * 64 + 255) / 256), dim3(256),
                           0, stream, cWe, Bp);
    }
    // 1. time MLP
    hipLaunchKernelGGL(time_mlp_kernel, dim3(N_GRAPHS), dim3(HID), 0, stream,
                       t, tW1, tb1, tW2, tb2, t_emb);
    // 2. concat
    hipLaunchKernelGGL(concat_kernel, dim3((N_NODES * 72 + 255) / 256), dim3(256), 0, stream,
                       x, conds, batch, xc);
    // 3. node encoder gemm + LN/GELU (+t_emb[batch])
    hipLaunchKernelGGL((gemm_kernel<HID, 8>), dim3(N_NODES / 8), dim3(HID), 0, stream,
                       xc, encW, encb, h, N_NODES, 72);
    hipLaunchKernelGGL(ln_gelu_kernel, dim3(N_NODES), dim3(HID), 0, stream,
                       h, encg, encbe, t_emb, batch);
    // 4. edge encode + self-loop mean
    if (mode == 1) {
        hipLaunchKernelGGL(edge_enc_loop_w_kernel, dim3(N_EDGES / 8), dim3(128), 0, stream,
                           edge_attr, eW, eb, eg, ebe, inv, ea16);
        hipLaunchKernelGGL(csr_loop_mean_kernel, dim3((N_NODES + 1) / 2), dim3(128), 0, stream,
                           ibase, inv, ea16);
    } else {
        hipLaunchKernelGGL(zero_kernel, dim3(1024), dim3(256), 0, stream,
                           loop_attr, (long)N_NODES * HID);
        hipLaunchKernelGGL(zero_kernel, dim3(64), dim3(256), 0, stream, cnt, (long)N_NODES);
        if (mode == 2) {
            hipLaunchKernelGGL((edge_enc_loop_kernel<8, 2>), dim3(N_EDGES / 8), dim3(HID), 0,
                               stream, edge_attr, eW, eb, eg, ebe, ei_dst, loop_attr, cnt, stat,
                               ea32, ea16);
        } else {
            hipLaunchKernelGGL((edge_enc_loop_kernel<8, 0>), dim3(N_EDGES / 8), dim3(HID), 0,
                               stream, edge_attr, eW, eb, eg, ebe, ei_dst, loop_attr, cnt, stat,
                               ea32, ea16);
        }
        hipLaunchKernelGGL(loop_div_kernel, dim3((N_NODES * HID + 255) / 256), dim3(256), 0,
                           stream, loop_attr, cnt);
    }

    // 5. layers
    for (int l = 0; l < NLAYERS; ++l) {
        const float* cWl_l = cWl + (size_t)l * HID * HID;
        const float* cWr_l = cWr + (size_t)l * HID * HID;
        const float* cWe_l = cWe + (size_t)l * HID * HID;
        const uint4* Bp_l  = Bp + (size_t)l * 8 * 4 * 64;
        const float* cbl_l = cbl + (size_t)l * HID;
        const float* cbr_l = cbr + (size_t)l * HID;
        const float* catt_l = catt + (size_t)l * HID;
        const float* cbias_l = cbias + (size_t)l * HID;

        hipLaunchKernelGGL((gemm2_kernel<8>), dim3(N_NODES / 8), dim3(HID), 0, stream,
                           h, cWl_l, cbl_l, cWr_l, cbr_l, xl, xr, N_NODES);
        if (mode == 1) {
            hipLaunchKernelGGL(att_logit12m_kernel, dim3((EF + 63) / 64), dim3(256), 0, stream,
                               ea16, src_s, dst_s, Bp_l, catt_l, xl, xr, logit);
            hipLaunchKernelGGL(csr_smax_agg_kernel, dim3((N_NODES + 1) / 2), dim3(128), 0, stream,
                               ibase, src_s, logit, xl, cbias_l, h);
        } else {
            hipLaunchKernelGGL(init_mx_den_kernel, dim3((N_NODES * HEADS + 255) / 256), dim3(256),
                               0, stream, mx, den);
            if (mode == 2) {
                hipLaunchKernelGGL((att_logit6_kernel<8>), dim3(EF / 8), dim3(HID), 0, stream,
                                   ea32, loop_attr, cWe_l, catt_l, xl, xr, ei_src, ei_dst,
                                   logit, mx);
            } else {
                hipLaunchKernelGGL((att_logit7_kernel<8>), dim3(EF / 8), dim3(HID), 0, stream,
                                   edge_attr, eW, eb, eg, ebe, stat, loop_attr,
                                   cWe_l, catt_l, xl, xr, ei_src, ei_dst, logit, mx);
            }
            hipLaunchKernelGGL(softmax_norm_kernel,
                               dim3((int)(((long)EF * HEADS + 255) / 256)), dim3(256), 0, stream,
                               ei_dst, mx, logit, den);
            hipLaunchKernelGGL(zero_kernel, dim3(1024), dim3(256), 0, stream,
                               aggout, (long)N_NODES * HID);
            hipLaunchKernelGGL(aggregate_kernel,
                               dim3((int)(((long)EF * HID + 255) / 256)), dim3(256), 0, stream,
                               logit, den, xl, ei_src, ei_dst, aggout);
            hipLaunchKernelGGL(residual_kernel, dim3((N_NODES * HID + 255) / 256), dim3(256), 0,
                               stream, aggout, cbias_l, h);
        }
    }

    // 6. noise head
    hipLaunchKernelGGL((gemm_kernel<HID, 8>), dim3(N_NODES / 8), dim3(HID), 0, stream,
                       h, nW1, nb1, tmp1, N_NODES, HID);
    hipLaunchKernelGGL(ln_gelu_kernel, dim3(N_NODES), dim3(HID), 0, stream,
                       tmp1, ng, nbe, (const float*)nullptr, (const int*)nullptr);
    hipLaunchKernelGGL((gemm_kernel<NODE_OUT, 8>), dim3(N_NODES / 8), dim3(NODE_OUT), 0, stream,
                       tmp1, nW2, nb2, pred_noise, N_NODES, HID);

    // 7. pooling + props head
    hipLaunchKernelGGL(zero_kernel, dim3(4), dim3(256), 0, stream,
                       gsum, (long)N_GRAPHS * HID);
    hipLaunchKernelGGL(zero_kernel, dim3(1), dim3(64), 0, stream, gcnt, (long)N_GRAPHS);
    hipLaunchKernelGGL(pool_kernel, dim3((N_NODES + POOL_NODES - 1) / POOL_NODES), dim3(HID), 0,
                       stream, h, batch, gsum, gcnt);
    hipLaunchKernelGGL(props_kernel, dim3(N_GRAPHS), dim3(HID), 0, stream,
                       gsum, gcnt, pW1, pb1, pg, pbe, pW2, pb2, pred_props);
}

// Round 15
// 1468.102 us; speedup vs baseline: 2.2121x; 1.1147x over previous
//
#include <hip/hip_runtime.h>
#include <hip/hip_fp16.h>
#include <math.h>

#define N_NODES 30000
#define N_EDGES 480000
#define N_GRAPHS 16
#define HID 128
#define HEADS 8
#define HEAD_DIM 16
#define NODE_IN 64
#define EDGE_IN 32
#define COND 8
#define NODE_OUT 64
#define NLAYERS 4
#define EF (N_EDGES + N_NODES) /* 510000 */
#define LN_EPS 1e-5f

typedef _Float16 v8hf __attribute__((ext_vector_type(8)));
typedef float v4f __attribute__((ext_vector_type(4)));

__device__ __forceinline__ float gelu_f(float x) {
    return 0.5f * x * (1.0f + erff(x * 0.70710678118654752440f));
}

__device__ __forceinline__ void atomicMaxF(float* addr, float val) {
    if (val >= 0.0f) {
        atomicMax((int*)addr, __float_as_int(val));
    } else {
        atomicMin((unsigned int*)addr, __float_as_uint(val));
    }
}

// ---------- generic zero ----------
__global__ void zero_kernel(float* __restrict__ p, long n) {
    long i = (long)blockIdx.x * blockDim.x + threadIdx.x;
    long stride = (long)gridDim.x * blockDim.x;
    for (; i < n; i += stride) p[i] = 0.0f;
}

// ---------- time MLP ----------
__global__ void time_mlp_kernel(const float* __restrict__ t,
                                const float* __restrict__ tW1, const float* __restrict__ tb1,
                                const float* __restrict__ tW2, const float* __restrict__ tb2,
                                float* __restrict__ t_emb) {
    __shared__ float hsh[HID];
    int b = blockIdx.x, j = threadIdx.x;
    float tv = t[b];
    hsh[j] = gelu_f(tv * tW1[j] + tb1[j]);
    __syncthreads();
    float acc = tb2[j];
    for (int k = 0; k < HID; ++k) acc += hsh[k] * tW2[k * HID + j];
    t_emb[b * HID + j] = acc;
}

// ---------- concat ----------
__global__ void concat_kernel(const float* __restrict__ x, const float* __restrict__ cond,
                              const int* __restrict__ batch, float* __restrict__ xc) {
    int idx = blockIdx.x * blockDim.x + threadIdx.x;
    if (idx >= N_NODES * 72) return;
    int n = idx / 72, c = idx % 72;
    xc[idx] = (c < NODE_IN) ? x[n * NODE_IN + c] : cond[batch[n] * COND + (c - NODE_IN)];
}

// ---------- generic GEMM ----------
template <int NCOL, int R>
__global__ void gemm_kernel(const float* __restrict__ A, const float* __restrict__ B,
                            const float* __restrict__ bias, float* __restrict__ C,
                            int M, int K) {
    __shared__ __align__(16) float sh[R * HID];
    int j = threadIdx.x;
    int row0 = blockIdx.x * R;
    int total = R * K;
    for (int i = j; i < total; i += NCOL) {
        int r = i / K, k = i - r * K;
        int row = row0 + r;
        sh[r * K + k] = (row < M) ? A[(long)row * K + k] : 0.0f;
    }
    __syncthreads();
    float acc[R];
    float bv = bias ? bias[j] : 0.0f;
#pragma unroll
    for (int r = 0; r < R; ++r) acc[r] = bv;
    int KB = K >> 2;
    for (int kb = 0; kb < KB; ++kb) {
        float w0 = B[(kb * 4 + 0) * NCOL + j];
        float w1 = B[(kb * 4 + 1) * NCOL + j];
        float w2 = B[(kb * 4 + 2) * NCOL + j];
        float w3 = B[(kb * 4 + 3) * NCOL + j];
#pragma unroll
        for (int r = 0; r < R; ++r) {
            float4 a = *(const float4*)&sh[r * K + kb * 4];
            acc[r] += a.x * w0 + a.y * w1 + a.z * w2 + a.w * w3;
        }
    }
#pragma unroll
    for (int r = 0; r < R; ++r) {
        int row = row0 + r;
        if (row < M) C[(long)row * NCOL + j] = acc[r];
    }
}

// ---------- fused dual GEMM ----------
template <int R>
__global__ void gemm2_kernel(const float* __restrict__ A,
                             const float* __restrict__ Bl, const float* __restrict__ bl,
                             const float* __restrict__ Br, const float* __restrict__ br,
                             float* __restrict__ Cl, float* __restrict__ Cr, int M) {
    __shared__ __align__(16) float sh[R * HID];
    int j = threadIdx.x;
    int row0 = blockIdx.x * R;
    for (int i = j; i < R * HID; i += HID) {
        int r = i >> 7, k = i & 127;
        int row = row0 + r;
        sh[i] = (row < M) ? A[(long)row * HID + k] : 0.0f;
    }
    __syncthreads();
    float accl[R], accr[R];
    float blv = bl[j], brv = br[j];
#pragma unroll
    for (int r = 0; r < R; ++r) { accl[r] = blv; accr[r] = brv; }
    for (int kb = 0; kb < HID / 4; ++kb) {
        float l0 = Bl[(kb * 4 + 0) * HID + j];
        float l1 = Bl[(kb * 4 + 1) * HID + j];
        float l2 = Bl[(kb * 4 + 2) * HID + j];
        float l3 = Bl[(kb * 4 + 3) * HID + j];
        float r0 = Br[(kb * 4 + 0) * HID + j];
        float r1 = Br[(kb * 4 + 1) * HID + j];
        float r2 = Br[(kb * 4 + 2) * HID + j];
        float r3 = Br[(kb * 4 + 3) * HID + j];
#pragma unroll
        for (int r = 0; r < R; ++r) {
            float4 a = *(const float4*)&sh[r * HID + kb * 4];
            accl[r] += a.x * l0 + a.y * l1 + a.z * l2 + a.w * l3;
            accr[r] += a.x * r0 + a.y * r1 + a.z * r2 + a.w * r3;
        }
    }
#pragma unroll
    for (int r = 0; r < R; ++r) {
        int row = row0 + r;
        if (row < M) {
            Cl[(long)row * HID + j] = accl[r];
            Cr[(long)row * HID + j] = accr[r];
        }
    }
}

// ---------- in-place LayerNorm + GELU ----------
__global__ void ln_gelu_kernel(float* __restrict__ X, const float* __restrict__ g,
                               const float* __restrict__ bta,
                               const float* __restrict__ t_emb, const int* __restrict__ batch) {
    int row = blockIdx.x, j = threadIdx.x;
    __shared__ float red[HID];
    float v = X[(long)row * HID + j];
    red[j] = v;
    __syncthreads();
    for (int s = 64; s > 0; s >>= 1) { if (j < s) red[j] += red[j + s]; __syncthreads(); }
    float mean = red[0] * (1.0f / HID);
    __syncthreads();
    float d = v - mean;
    red[j] = d * d;
    __syncthreads();
    for (int s = 64; s > 0; s >>= 1) { if (j < s) red[j] += red[j + s]; __syncthreads(); }
    float var = red[0] * (1.0f / HID);
    float y = gelu_f(d * rsqrtf(var + LN_EPS) * g[j] + bta[j]);
    if (t_emb) y += t_emb[batch[row] * HID + j];
    X[(long)row * HID + j] = y;
}

// ================= CSR sort setup (mode 1) =================
__global__ void hist_kernel(const int* __restrict__ ei_dst, int* __restrict__ ibase) {
    int idx = blockIdx.x * blockDim.x + threadIdx.x;
    if (idx >= EF) return;
    int d = (idx < N_EDGES) ? ei_dst[idx] : (idx - N_EDGES);
    atomicAdd(&ibase[d + 1], 1);
}

__global__ __launch_bounds__(1024) void scan_kernel(int* __restrict__ ibase) {
    __shared__ int wsums[16];
    __shared__ int s_carry;
    int t = threadIdx.x, lane = t & 63, w = t >> 6;
    if (t == 0) s_carry = 0;
    __syncthreads();
    for (int start = 0; start < N_NODES; start += 1024) {
        int i = start + t;
        int v = (i < N_NODES) ? ibase[i + 1] : 0;
        int x = v;
#pragma unroll
        for (int m = 1; m < 64; m <<= 1) {
            int y = __shfl_up(x, m);
            if (lane >= m) x += y;
        }
        if (lane == 63) wsums[w] = x;
        __syncthreads();
        if (w == 0 && lane < 16) {
            int ws = wsums[lane];
#pragma unroll
            for (int m = 1; m < 16; m <<= 1) {
                int y = __shfl_up(ws, m);
                if (lane >= m) ws += y;
            }
            wsums[lane] = ws;
        }
        __syncthreads();
        int waveoff = (w == 0) ? 0 : wsums[w - 1];
        int incl = x + waveoff + s_carry;
        if (i < N_NODES) ibase[i + 1] = incl;
        __syncthreads();
        if (t == 1023) s_carry = incl;
        __syncthreads();
    }
}

__global__ void scatter_kernel(const int* __restrict__ ei_src, const int* __restrict__ ei_dst,
                               const int* __restrict__ ibase, int* __restrict__ icursor,
                               int* __restrict__ src_s, int* __restrict__ dst_s,
                               int* __restrict__ inv) {
    int idx = blockIdx.x * blockDim.x + threadIdx.x;
    if (idx >= EF) return;
    int s, d;
    if (idx < N_EDGES) { s = ei_src[idx]; d = ei_dst[idx]; }
    else               { s = d = idx - N_EDGES; }
    int pos = ibase[d] + atomicAdd(&icursor[d], 1);
    src_s[pos] = s;
    dst_s[pos] = d;
    inv[idx] = pos;
}

// ---------- prep: pack cWe into MFMA B-fragment layout ----------
__global__ void prep_bp_kernel(const float* __restrict__ cWe, uint4* __restrict__ Bp) {
    int idx = blockIdx.x * blockDim.x + threadIdx.x;
    if (idx >= NLAYERS * 8 * 4 * 64) return;
    int l = idx >> 11;
    int rem = idx & 2047;
    int cg = rem >> 8;
    int kt = (rem >> 6) & 3;
    int lane = rem & 63;
    int c = cg * 16 + (lane & 15);
    int kbase = kt * 32 + (lane >> 4) * 8;
    __half hh[8];
#pragma unroll
    for (int j = 0; j < 8; ++j)
        hh[j] = __float2half(cWe[(size_t)l * HID * HID + (size_t)(kbase + j) * HID + c]);
    Bp[idx] = *(const uint4*)hh;
}

// ---------- prep: pack eW [32][128] into MFMA B-fragment layout (K=32, one k-tile) ----------
// Bpe[cg][lane]: j-th half = eW[(lane>>4)*8 + j][cg*16 + (lane&15)]
__global__ void prep_bpe_kernel(const float* __restrict__ eW, uint4* __restrict__ Bpe) {
    int idx = blockIdx.x * blockDim.x + threadIdx.x;
    if (idx >= 8 * 64) return;
    int cg = idx >> 6, lane = idx & 63;
    int c = cg * 16 + (lane & 15);
    int kbase = (lane >> 4) * 8;
    __half hh[8];
#pragma unroll
    for (int j = 0; j < 8; ++j)
        hh[j] = __float2half(eW[(size_t)(kbase + j) * HID + c]);
    Bpe[idx] = *(const uint4*)hh;
}

// ---------- CSR loop-mean ----------
__global__ __launch_bounds__(128) void csr_loop_mean_kernel(
        const int* __restrict__ ibase, const int* __restrict__ inv,
        __half* __restrict__ ea16) {
    int w = threadIdx.x >> 6, lane = threadIdx.x & 63;
    int d = blockIdx.x * 2 + w;
    if (d >= N_NODES) return;
    int b0 = ibase[d], b1 = ibase[d + 1];
    int selfpos = inv[N_EDGES + d];
    float a0 = 0.0f, a1 = 0.0f;
    for (int i = b0; i < b1; ++i) {
        if (i == selfpos) continue;
        a0 += __half2float(ea16[(long)i * HID + lane]);
        a1 += __half2float(ea16[(long)i * HID + lane + 64]);
    }
    float c = fmaxf((float)(b1 - b0 - 1), 1.0f);
    ea16[(long)selfpos * HID + lane]      = __float2half(a0 / c);
    ea16[(long)selfpos * HID + lane + 64] = __float2half(a1 / c);
}

// ---------- fallback (modes 0/2): edge-encode + segment-sum, LDS-tree LN ----------
template <int R, int MODE>
__global__ void edge_enc_loop_kernel(const float* __restrict__ edge_attr,
                                     const float* __restrict__ eW, const float* __restrict__ eb,
                                     const float* __restrict__ eg, const float* __restrict__ ebe,
                                     const int* __restrict__ ei_dst,
                                     float* __restrict__ loop_sum, float* __restrict__ cnt,
                                     float* __restrict__ stat,
                                     float* __restrict__ ea32, __half* __restrict__ ea16) {
    __shared__ float red[R * HID];
    __shared__ __align__(16) float sattr[R * EDGE_IN];
    __shared__ int sdst[R];
    int j = threadIdx.x;
    long e0 = (long)blockIdx.x * R;
    if (j < R * EDGE_IN / 4)
        ((float4*)sattr)[j] = ((const float4*)(edge_attr + e0 * EDGE_IN))[j];
    if (j < R) sdst[j] = ei_dst[e0 + j];
    __syncthreads();
    float val[R];
    float ebv = eb[j];
#pragma unroll
    for (int r = 0; r < R; ++r) val[r] = ebv;
#pragma unroll
    for (int kb = 0; kb < EDGE_IN / 4; ++kb) {
        float w0 = eW[(kb * 4 + 0) * HID + j];
        float w1 = eW[(kb * 4 + 1) * HID + j];
        float w2 = eW[(kb * 4 + 2) * HID + j];
        float w3 = eW[(kb * 4 + 3) * HID + j];
#pragma unroll
        for (int r = 0; r < R; ++r) {
            float4 a = *(const float4*)&sattr[r * EDGE_IN + kb * 4];
            val[r] += a.x * w0 + a.y * w1 + a.z * w2 + a.w * w3;
        }
    }
#pragma unroll
    for (int r = 0; r < R; ++r) red[r * HID + j] = val[r];
    __syncthreads();
    for (int s = 64; s > 0; s >>= 1) {
        if (j < s) {
#pragma unroll
            for (int r = 0; r < R; ++r) red[r * HID + j] += red[r * HID + j + s];
        }
        __syncthreads();
    }
    float mean[R];
#pragma unroll
    for (int r = 0; r < R; ++r) mean[r] = red[r * HID] * (1.0f / HID);
    __syncthreads();
#pragma unroll
    for (int r = 0; r < R; ++r) { float d = val[r] - mean[r]; red[r * HID + j] = d * d; }
    __syncthreads();
    for (int s = 64; s > 0; s >>= 1) {
        if (j < s) {
#pragma unroll
            for (int r = 0; r < R; ++r) red[r * HID + j] += red[r * HID + j + s];
        }
        __syncthreads();
    }
    float egv = eg[j], bev = ebe[j];
#pragma unroll
    for (int r = 0; r < R; ++r) {
        float var = red[r * HID] * (1.0f / HID);
        float rstd = rsqrtf(var + LN_EPS);
        float y = gelu_f((val[r] - mean[r]) * rstd * egv + bev);
        int d = sdst[r];
        long e = e0 + r;
        if (j == 0) { stat[e * 2] = mean[r]; stat[e * 2 + 1] = rstd; }
        if (MODE == 2) ea32[e * HID + j] = y;
        if (MODE == 1) ea16[e * HID + j] = __float2half(y);
        atomicAdd(&loop_sum[(long)d * HID + j], y);
        if (j == 0) atomicAdd(&cnt[d], 1.0f);
    }
}

// ---------- mode-1 MAIN enc: MFMA 16x16x32_f16 encode + shfl-LN, fp16 ea to sorted pos ----------
// Block 256 = 4 waves; wave w -> edges e0+16w..+15. A-frag: lane l holds
// edge_attr[row=l&15][k=(l>>4)*8..+8) cvt fp16 (layout validated by att12m).
// One MFMA per col-group (K=32). LN: s1/s2 partials over 8 cg + 4-step 16-lane butterfly.
__global__ __launch_bounds__(256) void edge_enc_mfma_kernel(
        const float* __restrict__ edge_attr,
        const uint4* __restrict__ Bpe,          /* [8][64] */
        const float* __restrict__ eb, const float* __restrict__ eg, const float* __restrict__ ebe,
        const int* __restrict__ inv,
        __half* __restrict__ ea16) {
    int t = threadIdx.x;
    int w = t >> 6, lane = t & 63;
    long e0 = (long)blockIdx.x * 64 + (long)w * 16;   /* 480000/64 = 7500 blocks exact */
    int row = lane & 15, ks = lane >> 4;

    const float* ap = &edge_attr[(e0 + row) * EDGE_IN + ks * 8];
    float4 a0 = *(const float4*)ap;
    float4 a1 = *(const float4*)(ap + 4);
    __half ah[8];
    ah[0] = __float2half(a0.x); ah[1] = __float2half(a0.y);
    ah[2] = __float2half(a0.z); ah[3] = __float2half(a0.w);
    ah[4] = __float2half(a1.x); ah[5] = __float2half(a1.y);
    ah[6] = __float2half(a1.z); ah[7] = __float2half(a1.w);
    v8hf A = *(v8hf*)ah;

    v4f acc[8];
    float ebv[8], egv[8], bev[8];
#pragma unroll
    for (int cg = 0; cg < 8; ++cg) {
        v4f z = {0.0f, 0.0f, 0.0f, 0.0f};
        acc[cg] = __builtin_amdgcn_mfma_f32_16x16x32_f16(
            A, __builtin_bit_cast(v8hf, Bpe[cg * 64 + lane]), z, 0, 0, 0);
        int c = cg * 16 + row;
        ebv[cg] = eb[c]; egv[cg] = eg[c]; bev[cg] = ebe[c];
    }

#pragma unroll
    for (int q = 0; q < 4; ++q) {
        float s1 = 0.0f, s2 = 0.0f;
#pragma unroll
        for (int cg = 0; cg < 8; ++cg) {
            float v = acc[cg][q] + ebv[cg];
            s1 += v;
            s2 += v * v;
        }
        s1 += __shfl_xor(s1, 1); s2 += __shfl_xor(s2, 1);
        s1 += __shfl_xor(s1, 2); s2 += __shfl_xor(s2, 2);
        s1 += __shfl_xor(s1, 4); s2 += __shfl_xor(s2, 4);
        s1 += __shfl_xor(s1, 8); s2 += __shfl_xor(s2, 8);
        float mean = s1 * (1.0f / 128.0f);
        float var = s2 * (1.0f / 128.0f) - mean * mean;
        float rstd = rsqrtf(var + LN_EPS);
        long pos = inv[e0 + ks * 4 + q];
#pragma unroll
        for (int cg = 0; cg < 8; ++cg) {
            float v = acc[cg][q] + ebv[cg];
            float y = gelu_f((v - mean) * rstd * egv[cg] + bev[cg]);
            ea16[pos * HID + cg * 16 + row] = __float2half(y);
        }
    }
}

__global__ void loop_div_kernel(float* __restrict__ loop_attr, const float* __restrict__ cnt) {
    int idx = blockIdx.x * blockDim.x + threadIdx.x;
    if (idx >= N_NODES * HID) return;
    int n = idx >> 7;
    loop_attr[idx] = loop_attr[idx] / fmaxf(cnt[n], 1.0f);
}

// ---------- init mx=-inf, den=0 (modes 0/2) ----------
__global__ void init_mx_den_kernel(float* __restrict__ mx, float* __restrict__ den) {
    int idx = blockIdx.x * blockDim.x + threadIdx.x;
    if (idx >= N_NODES * HEADS) return;
    mx[idx] = -INFINITY;
    den[idx] = 0.0f;
}

// ---------- shared epilogue (fallback variants) ----------
template <int R>
__device__ __forceinline__ void em_logit_body(
        const float* __restrict__ sh, const int* __restrict__ ssrc, const int* __restrict__ sdst,
        const float* __restrict__ cWe_l, const float* __restrict__ catt_l,
        const float* __restrict__ xl, const float* __restrict__ xr,
        float* __restrict__ logit, float* __restrict__ mx, long e0, int j) {
    float acc[R];
#pragma unroll
    for (int r = 0; r < R; ++r) acc[r] = 0.0f;
    for (int kb = 0; kb < HID / 4; ++kb) {
        float w0 = cWe_l[(kb * 4 + 0) * HID + j];
        float w1 = cWe_l[(kb * 4 + 1) * HID + j];
        float w2 = cWe_l[(kb * 4 + 2) * HID + j];
        float w3 = cWe_l[(kb * 4 + 3) * HID + j];
#pragma unroll
        for (int r = 0; r < R; ++r) {
            float4 a = *(const float4*)&sh[r * HID + kb * 4];
            acc[r] += a.x * w0 + a.y * w1 + a.z * w2 + a.w * w3;
        }
    }
    float cj = catt_l[j];
    int head = j >> 4;
#pragma unroll
    for (int r = 0; r < R; ++r) {
        long e = e0 + r;
        int s = ssrc[r], d = sdst[r];
        float m = xl[(long)s * HID + j] + xr[(long)d * HID + j] + acc[r];
        m = (m > 0.0f) ? m : 0.2f * m;
        float p = m * cj;
        p += __shfl_down(p, 8, 16);
        p += __shfl_down(p, 4, 16);
        p += __shfl_down(p, 2, 16);
        p += __shfl_down(p, 1, 16);
        if ((j & 15) == 0) {
            logit[e * HEADS + head] = p;
            atomicMaxF(&mx[(long)d * HEADS + head], p);
        }
    }
}

// ---------- att kernel, mode 0 fallback ----------
template <int R>
__global__ void att_logit7_kernel(const float* __restrict__ edge_attr,
                                  const float* __restrict__ eW, const float* __restrict__ eb,
                                  const float* __restrict__ eg, const float* __restrict__ ebe,
                                  const float* __restrict__ stat,
                                  const float* __restrict__ loop_attr,
                                  const float* __restrict__ cWe_l, const float* __restrict__ catt_l,
                                  const float* __restrict__ xl, const float* __restrict__ xr,
                                  const int* __restrict__ ei_src, const int* __restrict__ ei_dst,
                                  float* __restrict__ logit, float* __restrict__ mx) {
    __shared__ __align__(16) float sh[R * HID];
    __shared__ __align__(16) float sattr[R * EDGE_IN];
    __shared__ float sstat[R * 2];
    __shared__ int ssrc[R], sdst[R];
    int j = threadIdx.x;
    long e0 = (long)blockIdx.x * R;
    bool realblk = (e0 < N_EDGES);

    if (realblk) {
        if (j < R * EDGE_IN / 4)
            ((float4*)sattr)[j] = ((const float4*)(edge_attr + e0 * EDGE_IN))[j];
        if (j < R * 2) sstat[j] = stat[e0 * 2 + j];
        if (j < R) { ssrc[j] = ei_src[e0 + j]; sdst[j] = ei_dst[e0 + j]; }
    } else {
        if (j < R) ssrc[j] = sdst[j] = (int)(e0 + j - N_EDGES);
    }
    __syncthreads();

    if (realblk) {
        float val[R];
        float ebv = eb[j];
#pragma unroll
        for (int r = 0; r < R; ++r) val[r] = ebv;
#pragma unroll
        for (int kb = 0; kb < EDGE_IN / 4; ++kb) {
            float w0 = eW[(kb * 4 + 0) * HID + j];
            float w1 = eW[(kb * 4 + 1) * HID + j];
            float w2 = eW[(kb * 4 + 2) * HID + j];
            float w3 = eW[(kb * 4 + 3) * HID + j];
#pragma unroll
            for (int r = 0; r < R; ++r) {
                float4 a = *(const float4*)&sattr[r * EDGE_IN + kb * 4];
                val[r] += a.x * w0 + a.y * w1 + a.z * w2 + a.w * w3;
            }
        }
        float egv = eg[j], bev = ebe[j];
#pragma unroll
        for (int r = 0; r < R; ++r) {
            float mean = sstat[r * 2], rstd = sstat[r * 2 + 1];
            sh[r * HID + j] = gelu_f((val[r] - mean) * rstd * egv + bev);
        }
    } else {
#pragma unroll
        for (int r = 0; r < R; ++r)
            sh[r * HID + j] = loop_attr[(long)(e0 + r - N_EDGES) * HID + j];
    }
    __syncthreads();
    em_logit_body<R>(sh, ssrc, sdst, cWe_l, catt_l, xl, xr, logit, mx, e0, j);
}

// ---------- att kernel, mode 2 fallback ----------
template <int R>
__global__ void att_logit6_kernel(const float* __restrict__ ea,
                                  const float* __restrict__ loop_attr,
                                  const float* __restrict__ cWe_l, const float* __restrict__ catt_l,
                                  const float* __restrict__ xl, const float* __restrict__ xr,
                                  const int* __restrict__ ei_src, const int* __restrict__ ei_dst,
                                  float* __restrict__ logit, float* __restrict__ mx) {
    __shared__ __align__(16) float sh[R * HID];
    __shared__ int ssrc[R], sdst[R];
    int j = threadIdx.x;
    long e0 = (long)blockIdx.x * R;
    bool realblk = (e0 < N_EDGES);
    const float* srcp = realblk ? (ea + e0 * HID) : (loop_attr + (e0 - N_EDGES) * HID);
    const float4* s4 = (const float4*)srcp;
    ((float4*)sh)[j]       = s4[j];
    ((float4*)sh)[j + HID] = s4[j + HID];
    if (j < R) {
        long e = e0 + j;
        if (realblk) { ssrc[j] = ei_src[e]; sdst[j] = ei_dst[e]; }
        else         { ssrc[j] = sdst[j] = (int)(e - N_EDGES); }
    }
    __syncthreads();
    em_logit_body<R>(sh, ssrc, sdst, cWe_l, catt_l, xl, xr, logit, mx, e0, j);
}

// ---------- att kernel, mode 1 MAIN: MFMA 16x16x32_f16 on sorted fp16 ea ----------
__global__ __launch_bounds__(256) void att_logit12m_kernel(
        const __half* __restrict__ ea,          /* sorted [EF,128] */
        const int* __restrict__ src_s, const int* __restrict__ dst_s,
        const uint4* __restrict__ Bp_l,         /* [8][4][64] uint4 */
        const float* __restrict__ catt_l,
        const float* __restrict__ xl, const float* __restrict__ xr,
        float* __restrict__ logit) {
    int t = threadIdx.x;
    int w = t >> 6, lane = t & 63;
    long e0 = (long)blockIdx.x * 64 + (long)w * 16;
    if (e0 >= (long)EF) return;
    int row = lane & 15, ks = lane >> 4;

    uint4 A[4];
#pragma unroll
    for (int kt = 0; kt < 4; ++kt)
        A[kt] = *(const uint4*)&ea[(e0 + row) * HID + kt * 32 + ks * 8];

#pragma unroll
    for (int cg = 0; cg < 8; ++cg) {
        v4f acc = {0.0f, 0.0f, 0.0f, 0.0f};
#pragma unroll
        for (int kt = 0; kt < 4; ++kt) {
            uint4 B = Bp_l[(cg * 4 + kt) * 64 + lane];
            acc = __builtin_amdgcn_mfma_f32_16x16x32_f16(
                __builtin_bit_cast(v8hf, A[kt]), __builtin_bit_cast(v8hf, B), acc, 0, 0, 0);
        }
        int c = cg * 16 + row;
        float cj = catt_l[c];
#pragma unroll
        for (int q = 0; q < 4; ++q) {
            int r = ks * 4 + q;
            long e = e0 + r;
            int s = src_s[e], d = dst_s[e];
            float m = xl[(long)s * HID + c] + xr[(long)d * HID + c] + acc[q];
            m = (m > 0.0f) ? m : 0.2f * m;
            float p = m * cj;
            p += __shfl_xor(p, 1);
            p += __shfl_xor(p, 2);
            p += __shfl_xor(p, 4);
            p += __shfl_xor(p, 8);
            if (row == 0) logit[e * HEADS + cg] = p;
        }
    }
}

// ---------- CSR fused softmax + aggregate + residual (mode 1) ----------
__global__ __launch_bounds__(128) void csr_smax_agg_kernel(
        const int* __restrict__ ibase, const int* __restrict__ src_s,
        const float* __restrict__ logit, const float* __restrict__ xl,
        const float* __restrict__ cbias_l, float* __restrict__ h) {
    int w = threadIdx.x >> 6, lane = threadIdx.x & 63;
    int d = blockIdx.x * 2 + w;
    if (d >= N_NODES) return;
    int b0 = ibase[d], b1 = ibase[d + 1];
    int hh = lane & 7, g = lane >> 3;
    float m = -INFINITY;
    for (int i = b0 + g; i < b1; i += 8) m = fmaxf(m, logit[(long)i * 8 + hh]);
    m = fmaxf(m, __shfl_xor(m, 8));
    m = fmaxf(m, __shfl_xor(m, 16));
    m = fmaxf(m, __shfl_xor(m, 32));
    float den = 0.0f;
    for (int i = b0 + g; i < b1; i += 8) den += expf(logit[(long)i * 8 + hh] - m);
    den += __shfl_xor(den, 8);
    den += __shfl_xor(den, 16);
    den += __shfl_xor(den, 32);
    int h1 = lane >> 4, h2 = 4 + (lane >> 4);
    float mx1 = __shfl(m, h1), mx2 = __shfl(m, h2);
    float dn1 = __shfl(den, h1) + 1e-16f, dn2 = __shfl(den, h2) + 1e-16f;
    float acc0 = 0.0f, acc1 = 0.0f;
    for (int i = b0; i < b1; ++i) {
        int s = src_s[i];
        float a0 = expf(logit[(long)i * 8 + h1] - mx1) / dn1;
        float a1 = expf(logit[(long)i * 8 + h2] - mx2) / dn2;
        acc0 += a0 * xl[(long)s * HID + lane];
        acc1 += a1 * xl[(long)s * HID + lane + 64];
    }
    long o = (long)d * HID + lane;
    h[o]      = gelu_f(acc0 + cbias_l[lane])      + h[o];
    h[o + 64] = gelu_f(acc1 + cbias_l[lane + 64]) + h[o + 64];
}

// ---------- fallback chain kernels (modes 0/2) ----------
__global__ void softmax_norm_kernel(const int* __restrict__ ei_dst, const float* __restrict__ mx,
                                    float* __restrict__ logit, float* __restrict__ den) {
    long idx = (long)blockIdx.x * blockDim.x + threadIdx.x;
    if (idx >= (long)EF * HEADS) return;
    long e = idx >> 3;
    int hh = (int)(idx & 7);
    int d = (e < N_EDGES) ? ei_dst[e] : (int)(e - N_EDGES);
    float ex = expf(logit[idx] - mx[(long)d * HEADS + hh]);
    logit[idx] = ex;
    atomicAdd(&den[(long)d * HEADS + hh], ex);
}

__global__ void aggregate_kernel(const float* __restrict__ logit, const float* __restrict__ den,
                                 const float* __restrict__ xl,
                                 const int* __restrict__ ei_src, const int* __restrict__ ei_dst,
                                 float* __restrict__ aggout) {
    long idx = (long)blockIdx.x * blockDim.x + threadIdx.x;
    if (idx >= (long)EF * HID) return;
    long e = idx >> 7;
    int j = (int)(idx & 127);
    int s, d;
    if (e < N_EDGES) { s = ei_src[e]; d = ei_dst[e]; }
    else             { s = d = (int)(e - N_EDGES); }
    int head = j >> 4;
    float alpha = logit[e * HEADS + head] / (den[(long)d * HEADS + head] + 1e-16f);
    atomicAdd(&aggout[(long)d * HID + j], alpha * xl[(long)s * HID + j]);
}

__global__ void residual_kernel(const float* __restrict__ aggout, const float* __restrict__ cbias_l,
                                float* __restrict__ h) {
    int idx = blockIdx.x * blockDim.x + threadIdx.x;
    if (idx >= N_NODES * HID) return;
    int j = idx & 127;
    h[idx] = gelu_f(aggout[idx] + cbias_l[j]) + h[idx];
}

// ---------- pooling ----------
#define POOL_NODES 64
__global__ void pool_kernel(const float* __restrict__ h, const int* __restrict__ batch,
                            float* __restrict__ gsum, float* __restrict__ gcnt) {
    __shared__ float acc[N_GRAPHS][HID];
    __shared__ float cnt_sh[N_GRAPHS];
    int j = threadIdx.x;
    for (int g = 0; g < N_GRAPHS; ++g) acc[g][j] = 0.0f;
    if (j < N_GRAPHS) cnt_sh[j] = 0.0f;
    __syncthreads();
    int n0 = blockIdx.x * POOL_NODES;
    for (int i = 0; i < POOL_NODES; ++i) {
        int n = n0 + i;
        if (n >= N_NODES) break;
        int g = batch[n];
        acc[g][j] += h[(long)n * HID + j];
        if (j == 0) cnt_sh[g] += 1.0f;
    }
    __syncthreads();
    for (int g = 0; g < N_GRAPHS; ++g) atomicAdd(&gsum[g * HID + j], acc[g][j]);
    if (j < N_GRAPHS) atomicAdd(&gcnt[j], cnt_sh[j]);
}

// ---------- props head ----------
__global__ void props_kernel(const float* __restrict__ gsum, const float* __restrict__ gcnt,
                             const float* __restrict__ pW1, const float* __restrict__ pb1,
                             const float* __restrict__ pg, const float* __restrict__ pbe,
                             const float* __restrict__ pW2, const float* __restrict__ pb2,
                             float* __restrict__ out_props) {
    int g = blockIdx.x, j = threadIdx.x;
    __shared__ float feat[HID], red[HID], t2[HID];
    float c = fmaxf(gcnt[g], 1.0f);
    feat[j] = gsum[g * HID + j] / c;
    __syncthreads();
    float acc = pb1[j];
    for (int k = 0; k < HID; ++k) acc += feat[k] * pW1[k * HID + j];
    red[j] = acc;
    __syncthreads();
    for (int s = 64; s > 0; s >>= 1) { if (j < s) red[j] += red[j + s]; __syncthreads(); }
    float mean = red[0] * (1.0f / HID);
    __syncthreads();
    float dd = acc - mean;
    red[j] = dd * dd;
    __syncthreads();
    for (int s = 64; s > 0; s >>= 1) { if (j < s) red[j] += red[j + s]; __syncthreads(); }
    float var = red[0] * (1.0f / HID);
    t2[j] = gelu_f(dd * rsqrtf(var + LN_EPS) * pg[j] + pbe[j]);
    __syncthreads();
    if (j < COND) {
        float a = pb2[j];
        for (int k = 0; k < HID; ++k) a += t2[k] * pW2[k * COND + j];
        out_props[g * COND + j] = a;
    }
}

extern "C" void kernel_launch(void* const* d_in, const int* in_sizes, int n_in,
                              void* d_out, int out_size, void* d_ws, size_t ws_size,
                              hipStream_t stream) {
    const float* x        = (const float*)d_in[0];
    const float* edge_attr= (const float*)d_in[1];
    const float* t        = (const float*)d_in[2];
    const float* conds    = (const float*)d_in[3];
    const float* tW1      = (const float*)d_in[4];
    const float* tb1      = (const float*)d_in[5];
    const float* tW2      = (const float*)d_in[6];
    const float* tb2      = (const float*)d_in[7];
    const float* encW     = (const float*)d_in[8];
    const float* encb     = (const float*)d_in[9];
    const float* encg     = (const float*)d_in[10];
    const float* encbe    = (const float*)d_in[11];
    const float* eW       = (const float*)d_in[12];
    const float* eb       = (const float*)d_in[13];
    const float* eg       = (const float*)d_in[14];
    const float* ebe      = (const float*)d_in[15];
    const float* cWl      = (const float*)d_in[16];
    const float* cbl      = (const float*)d_in[17];
    const float* cWr      = (const float*)d_in[18];
    const float* cbr      = (const float*)d_in[19];
    const float* cWe      = (const float*)d_in[20];
    const float* catt     = (const float*)d_in[21];
    const float* cbias    = (const float*)d_in[22];
    const float* nW1      = (const float*)d_in[23];
    const float* nb1      = (const float*)d_in[24];
    const float* ng       = (const float*)d_in[25];
    const float* nbe      = (const float*)d_in[26];
    const float* nW2      = (const float*)d_in[27];
    const float* nb2      = (const float*)d_in[28];
    const float* pW1      = (const float*)d_in[29];
    const float* pb1      = (const float*)d_in[30];
    const float* pg       = (const float*)d_in[31];
    const float* pbe      = (const float*)d_in[32];
    const float* pW2      = (const float*)d_in[33];
    const float* pb2      = (const float*)d_in[34];
    const int* edge_index = (const int*)d_in[35];
    const int* batch      = (const int*)d_in[36];
    const int* ei_src = edge_index;
    const int* ei_dst = edge_index + N_EDGES;

    // workspace: common + union(mode1 sort ints + Bp + Bpe | mode0/2 stat+mx+den+aggout) + ea
    float* ws = (float*)d_ws;
    size_t off = 0;
    auto alloc = [&](size_t n) { float* p = ws + off; off += n; return p; };
    float* t_emb     = alloc((size_t)N_GRAPHS * HID);
    float* h         = alloc((size_t)N_NODES * HID);
    float* loop_attr = alloc((size_t)N_NODES * HID);
    float* cnt       = alloc((size_t)N_NODES);
    float* xl        = alloc((size_t)N_NODES * HID);
    float* xr        = alloc((size_t)N_NODES * HID);
    float* logit     = alloc((size_t)EF * HEADS);      // 4.08M floats
    float* gsum      = alloc((size_t)N_GRAPHS * HID);
    float* gcnt      = alloc((size_t)N_GRAPHS);
    // union region (5.28M float slots):
    float* uni = alloc((size_t)(960000 + 240000 + 240000 + (size_t)N_NODES * HID));
    // mode-0/2 view:
    float* stat   = uni;                  // [N_EDGES*2]
    float* mx     = uni + 960000;         // [N*8]
    float* den    = uni + 960000 + 240000;
    float* aggout = uni + 960000 + 480000; // [N*128]
    // mode-1 view (ints + MFMA-packed fp16 weights):
    int* ibase   = (int*)uni;                         // [N_NODES+1]
    int* icursor = ibase + (N_NODES + 1);             // [N_NODES]
    int* src_s   = icursor + N_NODES;                 // [EF]
    int* dst_s   = src_s + EF;                        // [EF]
    int* inv     = dst_s + EF;                        // [EF]
    uintptr_t bp_addr = (((uintptr_t)(inv + EF)) + 15) & ~(uintptr_t)15;
    uint4* Bp  = (uint4*)bp_addr;                     // [NLAYERS][8][4][64] uint4 = 128KB
    uint4* Bpe = Bp + (size_t)NLAYERS * 8 * 4 * 64;   // [8][64] uint4 = 8KB
    size_t base_bytes = off * sizeof(float);
    float*  ea32 = ws + off;
    __half* ea16 = (__half*)(ws + off);
    int mode = 0;
    if (ws_size >= base_bytes + (size_t)EF * HID * sizeof(float)) mode = 2;
    else if (ws_size >= base_bytes + (size_t)EF * HID * sizeof(__half)) mode = 1;
    // aliases (disjoint lifetimes):
    float* xc   = logit;  // [N,72] used only pre-layers
    float* tmp1 = xl;     // used only post-layers
    (void)in_sizes; (void)n_in; (void)out_size;

    float* pred_noise = (float*)d_out;                              // [N,64]
    float* pred_props = (float*)d_out + (size_t)N_NODES * NODE_OUT; // [16,8]

    // 0. (mode 1) CSR sort of edges by dst + MFMA weight packing
    if (mode == 1) {
        hipLaunchKernelGGL(zero_kernel, dim3(64), dim3(256), 0, stream,
                           (float*)ibase, (long)(2 * N_NODES + 1));  // ibase + icursor
        hipLaunchKernelGGL(hist_kernel, dim3((EF + 255) / 256), dim3(256), 0, stream,
                           ei_dst, ibase);
        hipLaunchKernelGGL(scan_kernel, dim3(1), dim3(1024), 0, stream, ibase);
        hipLaunchKernelGGL(scatter_kernel, dim3((EF + 255) / 256), dim3(256), 0, stream,
                           ei_src, ei_dst, ibase, icursor, src_s, dst_s, inv);
        hipLaunchKernelGGL(prep_bp_kernel, dim3((NLAYERS * 8 * 4 * 64 + 255) / 256), dim3(256),
                           0, stream, cWe, Bp);
        hipLaunchKernelGGL(prep_bpe_kernel, dim3(2), dim3(256), 0, stream, eW, Bpe);
    }
    // 1. time MLP
    hipLaunchKernelGGL(time_mlp_kernel, dim3(N_GRAPHS), dim3(HID), 0, stream,
                       t, tW1, tb1, tW2, tb2, t_emb);
    // 2. concat
    hipLaunchKernelGGL(concat_kernel, dim3((N_NODES * 72 + 255) / 256), dim3(256), 0, stream,
                       x, conds, batch, xc);
    // 3. node encoder gemm + LN/GELU (+t_emb[batch])
    hipLaunchKernelGGL((gemm_kernel<HID, 8>), dim3(N_NODES / 8), dim3(HID), 0, stream,
                       xc, encW, encb, h, N_NODES, 72);
    hipLaunchKernelGGL(ln_gelu_kernel, dim3(N_NODES), dim3(HID), 0, stream,
                       h, encg, encbe, t_emb, batch);
    // 4. edge encode + self-loop mean
    if (mode == 1) {
        hipLaunchKernelGGL(edge_enc_mfma_kernel, dim3(N_EDGES / 64), dim3(256), 0, stream,
                           edge_attr, Bpe, eb, eg, ebe, inv, ea16);
        hipLaunchKernelGGL(csr_loop_mean_kernel, dim3((N_NODES + 1) / 2), dim3(128), 0, stream,
                           ibase, inv, ea16);
    } else {
        hipLaunchKernelGGL(zero_kernel, dim3(1024), dim3(256), 0, stream,
                           loop_attr, (long)N_NODES * HID);
        hipLaunchKernelGGL(zero_kernel, dim3(64), dim3(256), 0, stream, cnt, (long)N_NODES);
        if (mode == 2) {
            hipLaunchKernelGGL((edge_enc_loop_kernel<8, 2>), dim3(N_EDGES / 8), dim3(HID), 0,
                               stream, edge_attr, eW, eb, eg, ebe, ei_dst, loop_attr, cnt, stat,
                               ea32, ea16);
        } else {
            hipLaunchKernelGGL((edge_enc_loop_kernel<8, 0>), dim3(N_EDGES / 8), dim3(HID), 0,
                               stream, edge_attr, eW, eb, eg, ebe, ei_dst, loop_attr, cnt, stat,
                               ea32, ea16);
        }
        hipLaunchKernelGGL(loop_div_kernel, dim3((N_NODES * HID + 255) / 256), dim3(256), 0,
                           stream, loop_attr, cnt);
    }

    // 5. layers
    for (int l = 0; l < NLAYERS; ++l) {
        const float* cWl_l = cWl + (size_t)l * HID * HID;
        const float* cWr_l = cWr + (size_t)l * HID * HID;
        const float* cWe_l = cWe + (size_t)l * HID * HID;
        const uint4* Bp_l  = Bp + (size_t)l * 8 * 4 * 64;
        const float* cbl_l = cbl + (size_t)l * HID;
        const float* cbr_l = cbr + (size_t)l * HID;
        const float* catt_l = catt + (size_t)l * HID;
        const float* cbias_l = cbias + (size_t)l * HID;

        hipLaunchKernelGGL((gemm2_kernel<8>), dim3(N_NODES / 8), dim3(HID), 0, stream,
                           h, cWl_l, cbl_l, cWr_l, cbr_l, xl, xr, N_NODES);
        if (mode == 1) {
            hipLaunchKernelGGL(att_logit12m_kernel, dim3((EF + 63) / 64), dim3(256), 0, stream,
                               ea16, src_s, dst_s, Bp_l, catt_l, xl, xr, logit);
            hipLaunchKernelGGL(csr_smax_agg_kernel, dim3((N_NODES + 1) / 2), dim3(128), 0, stream,
                               ibase, src_s, logit, xl, cbias_l, h);
        } else {
            hipLaunchKernelGGL(init_mx_den_kernel, dim3((N_NODES * HEADS + 255) / 256), dim3(256),
                               0, stream, mx, den);
            if (mode == 2) {
                hipLaunchKernelGGL((att_logit6_kernel<8>), dim3(EF / 8), dim3(HID), 0, stream,
                                   ea32, loop_attr, cWe_l, catt_l, xl, xr, ei_src, ei_dst,
                                   logit, mx);
            } else {
                hipLaunchKernelGGL((att_logit7_kernel<8>), dim3(EF / 8), dim3(HID), 0, stream,
                                   edge_attr, eW, eb, eg, ebe, stat, loop_attr,
                                   cWe_l, catt_l, xl, xr, ei_src, ei_dst, logit, mx);
            }
            hipLaunchKernelGGL(softmax_norm_kernel,
                               dim3((int)(((long)EF * HEADS + 255) / 256)), dim3(256), 0, stream,
                               ei_dst, mx, logit, den);
            hipLaunchKernelGGL(zero_kernel, dim3(1024), dim3(256), 0, stream,
                               aggout, (long)N_NODES * HID);
            hipLaunchKernelGGL(aggregate_kernel,
                               dim3((int)(((long)EF * HID + 255) / 256)), dim3(256), 0, stream,
                               logit, den, xl, ei_src, ei_dst, aggout);
            hipLaunchKernelGGL(residual_kernel, dim3((N_NODES * HID + 255) / 256), dim3(256), 0,
                               stream, aggout, cbias_l, h);
        }
    }

    // 6. noise head
    hipLaunchKernelGGL((gemm_kernel<HID, 8>), dim3(N_NODES / 8), dim3(HID), 0, stream,
                       h, nW1, nb1, tmp1, N_NODES, HID);
    hipLaunchKernelGGL(ln_gelu_kernel, dim3(N_NODES), dim3(HID), 0, stream,
                       tmp1, ng, nbe, (const float*)nullptr, (const int*)nullptr);
    hipLaunchKernelGGL((gemm_kernel<NODE_OUT, 8>), dim3(N_NODES / 8), dim3(NODE_OUT), 0, stream,
                       tmp1, nW2, nb2, pred_noise, N_NODES, HID);

    // 7. pooling + props head
    hipLaunchKernelGGL(zero_kernel, dim3(4), dim3(256), 0, stream,
                       gsum, (long)N_GRAPHS * HID);
    hipLaunchKernelGGL(zero_kernel, dim3(1), dim3(64), 0, stream, gcnt, (long)N_GRAPHS);
    hipLaunchKernelGGL(pool_kernel, dim3((N_NODES + POOL_NODES - 1) / POOL_NODES), dim3(HID), 0,
                       stream, h, batch, gsum, gcnt);
    hipLaunchKernelGGL(props_kernel, dim3(N_GRAPHS), dim3(HID), 0, stream,
                       gsum, gcnt, pW1, pb1, pg, pbe, pW2, pb2, pred_props);
}